// Round 7
// baseline (411.001 us; speedup 1.0000x reference)
//
#include <hip/hip_runtime.h>
#include <hip/hip_bf16.h>
#include <stdint.h>

#define NN 30000
#define MPAD 30080
#define FI 16
#define EE 300000
#define ETOT (EE + NN)
#define HD 256
#define NH 8
#define CH 32
#define NL 3
#define SS 256
#define KS 128
#define NHC 4
#define HC 64
#define GSB 256
#define RPB 118
#define SCB 118

typedef _Float16 half8 __attribute__((ext_vector_type(8)));
typedef _Float16 half4v __attribute__((ext_vector_type(4)));
typedef _Float16 half2v __attribute__((ext_vector_type(2)));
typedef float f32x4 __attribute__((ext_vector_type(4)));

// ---------------- wave helpers ----------------
__device__ __forceinline__ float wsum(float v) {
#pragma unroll
  for (int d = 1; d < 64; d <<= 1) v += __shfl_xor(v, d);
  return v;
}

__device__ __forceinline__ half2v h2max(half2v a, half2v b) {
#if __has_builtin(__builtin_elementwise_max)
  return __builtin_elementwise_max(a, b);
#else
  half2v r; r[0] = a[0] > b[0] ? a[0] : b[0]; r[1] = a[1] > b[1] ? a[1] : b[1];
  return r;
#endif
}

__device__ __forceinline__ float h2dot(half2v a, half2v b, float c) {
#if __has_builtin(__builtin_amdgcn_fdot2)
  return __builtin_amdgcn_fdot2(a, b, c, false);
#else
  return c + (float)a[0] * (float)b[0] + (float)a[1] * (float)b[1];
#endif
}

// LN over n channels, 256 threads, t<n holds a. 2 barriers.
__device__ __forceinline__ float ln_fast(float a, int t, int n, float* red16,
    const float* __restrict__ G, const float* __restrict__ Be, bool relu)
{
  float av = (t < n) ? a : 0.f;
  float s = wsum(av), s2 = wsum(av * av);
  if ((t & 63) == 0) { red16[t >> 6] = s; red16[8 + (t >> 6)] = s2; }
  __syncthreads();
  float sum = red16[0] + red16[1] + red16[2] + red16[3];
  float sq  = red16[8] + red16[9] + red16[10] + red16[11];
  float mu = sum / n;
  float var = sq / n - mu * mu;
  float o = 0.f;
  if (t < n) {
    o = (a - mu) * rsqrtf(var + 1e-5f) * G[t] + Be[t];
    if (relu) o = fmaxf(o, 0.f);
  }
  __syncthreads();
  return o;
}

// ---------------- init (zero cnt, gcnt, h16 pad) ----------------
__global__ __launch_bounds__(256) void k_init(int* __restrict__ cnt,
    int* __restrict__ gcnt, _Float16* __restrict__ h16pad)
{
  int i = blockIdx.x * 256 + threadIdx.x;
  if (i < NN) cnt[i] = 0;
  if (i == 0) gcnt[0] = 0;
  if (i < (MPAD - NN) * HD) h16pad[i] = (_Float16)0.f;
}

// ---------------- GAT weight transpose+convert ----------------
__global__ __launch_bounds__(256) void k_wconv(const float* __restrict__ Wl,
    const float* __restrict__ Wr, _Float16* __restrict__ WT)
{
  int m = blockIdx.x >> 8;
  int n = blockIdx.x & 255;
  int k = threadIdx.x;
  int l = m >> 1;
  const float* W = (m & 1) ? (Wr + (size_t)l * HD * HD) : (Wl + (size_t)l * HD * HD);
  WT[((size_t)m * HD + n) * HD + k] = (_Float16)W[k * HD + n];
}

// ---------------- tail weight transpose+convert ----------------
__global__ __launch_bounds__(256) void k_wconvT(
    const float* __restrict__ geo_W2, const float* __restrict__ ca_Wq,
    const float* __restrict__ ca_Wk, const float* __restrict__ ca_Wv,
    const float* __restrict__ ca_Wo, const float* __restrict__ q_W1,
    const float* __restrict__ q_W2,
    _Float16* __restrict__ Tgeo2, _Float16* __restrict__ Tq,
    _Float16* __restrict__ Tk, _Float16* __restrict__ Tv,
    _Float16* __restrict__ To, _Float16* __restrict__ Tq1,
    _Float16* __restrict__ Tq2)
{
  int b = blockIdx.x, t = threadIdx.x;
  if (b < 1280) {
    int seg = b >> 8;
    int n = b & 255;
    const float* src = (seg == 0) ? geo_W2 : (seg == 1) ? ca_Wq : (seg == 2) ? ca_Wk
                     : (seg == 3) ? ca_Wv : ca_Wo;
    _Float16* dst = (seg == 0) ? Tgeo2 : (seg == 1) ? Tq : (seg == 2) ? Tk
                  : (seg == 3) ? Tv : To;
    dst[(size_t)n * 256 + t] = (_Float16)src[(size_t)t * 256 + n];
  } else if (b < 1536) {
    int n = b - 1280;
    Tq1[(size_t)n * 512 + t]       = (_Float16)q_W1[(size_t)t * 256 + n];
    Tq1[(size_t)n * 512 + 256 + t] = (_Float16)q_W1[(size_t)(256 + t) * 256 + n];
  } else {
    int n = b - 1536;
    Tq2[(size_t)n * 256 + t] = (_Float16)q_W2[(size_t)t * 128 + n];
  }
}

// ---------------- pre-transform ----------------
__global__ __launch_bounds__(256) void k_pre(const float* __restrict__ x,
    const float* __restrict__ W, const float* __restrict__ b,
    _Float16* __restrict__ H16)
{
  __shared__ float Ws[FI][HD];
  __shared__ float xs[8][FI];
  int r0 = blockIdx.x * 8;
  int t = threadIdx.x;
  for (int i = t; i < FI * HD; i += 256) Ws[i >> 8][i & 255] = W[i];
  if (t < 8 * FI) xs[t >> 4][t & 15] = x[(size_t)(r0 + (t >> 4)) * FI + (t & 15)];
  __syncthreads();
  float bj = b[t];
  for (int r = 0; r < 8; ++r) {
    float acc = bj;
#pragma unroll
    for (int k = 0; k < FI; ++k) acc += xs[r][k] * Ws[k][t];
    H16[(size_t)(r0 + r) * HD + t] = (_Float16)acc;
  }
}

// ---------------- CSR build ----------------
__global__ __launch_bounds__(256) void k_count(const int* __restrict__ ei, int* __restrict__ cnt)
{
  int i = blockIdx.x * 256 + threadIdx.x;
  if (i >= ETOT) return;
  int dst = (i < EE) ? ei[EE + i] : (i - EE);
  atomicAdd(&cnt[dst], 1);
}

__global__ __launch_bounds__(256) void k_scanA(const int* __restrict__ cnt,
    int* __restrict__ rowptr, int* __restrict__ btot)
{
  __shared__ int wt[4];
  int b = blockIdx.x, t = threadIdx.x;
  int i = b * 256 + t;
  int v = (i < NN) ? cnt[i] : 0;
  int lane = t & 63, w = t >> 6;
  int s = v;
#pragma unroll
  for (int d = 1; d < 64; d <<= 1) {
    int u = __shfl_up(s, d);
    if (lane >= d) s += u;
  }
  if (lane == 63) wt[w] = s;
  __syncthreads();
  int off = 0;
  for (int k = 0; k < w; ++k) off += wt[k];
  if (i < NN) rowptr[i] = off + s - v;
  if (t == 255) btot[b] = off + s;
}

__global__ __launch_bounds__(128) void k_scanB(const int* __restrict__ btot,
    int* __restrict__ boff, int* __restrict__ rowptr)
{
  __shared__ int wt[2];
  int t = threadIdx.x;
  int v = (t < SCB) ? btot[t] : 0;
  int lane = t & 63, w = t >> 6;
  int s = v;
#pragma unroll
  for (int d = 1; d < 64; d <<= 1) {
    int u = __shfl_up(s, d);
    if (lane >= d) s += u;
  }
  if (lane == 63) wt[w] = s;
  __syncthreads();
  int off = (w == 1) ? wt[0] : 0;
  if (t < SCB) boff[t] = off + s - v;
  if (t == 127) rowptr[NN] = wt[0] + wt[1];
}

__global__ __launch_bounds__(256) void k_scanC(int* __restrict__ rowptr,
    const int* __restrict__ boff, int* __restrict__ wptr)
{
  int b = blockIdx.x, t = threadIdx.x;
  int i = b * 256 + t;
  if (i < NN) {
    int r = rowptr[i] + boff[b];
    rowptr[i] = r;
    wptr[i] = r;
  }
}

__global__ __launch_bounds__(256) void k_scatter(const int* __restrict__ ei,
    int* __restrict__ wptr, int* __restrict__ csr_src)
{
  int i = blockIdx.x * 256 + threadIdx.x;
  if (i >= ETOT) return;
  int src = (i < EE) ? ei[i] : (i - EE);
  int dst = (i < EE) ? ei[EE + i] : (i - EE);
  int pos = atomicAdd(&wptr[dst], 1);
  csr_src[pos] = src;
}

// ---------------- fp16 MFMA GEMM (GAT layers) ----------------
#define BK 64
__global__ __launch_bounds__(256) void k_gemm16(const _Float16* __restrict__ A,
    const _Float16* __restrict__ WT,
    _Float16* __restrict__ Xl, _Float16* __restrict__ Xr)
{
  __shared__ __align__(16) _Float16 As[128 * BK];
  __shared__ __align__(16) _Float16 Bs[128 * BK];
  int t = threadIdx.x;
  int w = t >> 6, lane = t & 63;
  int row0 = blockIdx.x * 128;
  int ct = blockIdx.y;
  const _Float16* Bmat = WT + (size_t)(ct >> 1) * HD * HD + (size_t)(ct & 1) * 128 * HD;
  _Float16* Out = (ct >> 1) ? Xr : Xl;
  int j0 = (ct & 1) * 128;

  f32x4 acc[4][4] = {};
  int wr = w >> 1, wc = w & 1;

  for (int k0 = 0; k0 < HD; k0 += BK) {
#pragma unroll
    for (int i = 0; i < 4; ++i) {
      int p = (i * 4 + w) * 64 + lane;
      int row = p >> 3, s = p & 7;
      int g = s ^ (row & 7);
      const _Float16* srcA = A + (size_t)(row0 + row) * HD + k0 + g * 8;
      __builtin_amdgcn_global_load_lds(
        (const __attribute__((address_space(1))) void*)srcA,
        (__attribute__((address_space(3))) void*)((char*)As + (i * 4 + w) * 1024),
        16, 0, 0);
      const _Float16* srcB = Bmat + (size_t)row * HD + k0 + g * 8;
      __builtin_amdgcn_global_load_lds(
        (const __attribute__((address_space(1))) void*)srcB,
        (__attribute__((address_space(3))) void*)((char*)Bs + (i * 4 + w) * 1024),
        16, 0, 0);
    }
    __syncthreads();
#pragma unroll
    for (int ks = 0; ks < 2; ++ks) {
      half8 af[4], bfr[4];
      int kslot = ks * 4 + (lane >> 4);
#pragma unroll
      for (int mi = 0; mi < 4; ++mi) {
        int rl = wr * 64 + mi * 16 + (lane & 15);
        int ps = kslot ^ (rl & 7);
        af[mi] = *(const half8*)((const char*)As + rl * 128 + ps * 16);
      }
#pragma unroll
      for (int ni = 0; ni < 4; ++ni) {
        int nl = wc * 64 + ni * 16 + (lane & 15);
        int ps = kslot ^ (nl & 7);
        bfr[ni] = *(const half8*)((const char*)Bs + nl * 128 + ps * 16);
      }
#pragma unroll
      for (int mi = 0; mi < 4; ++mi)
#pragma unroll
        for (int ni = 0; ni < 4; ++ni)
          acc[mi][ni] = __builtin_amdgcn_mfma_f32_16x16x32_f16(af[mi], bfr[ni], acc[mi][ni], 0, 0, 0);
    }
    __syncthreads();
  }
  int crow = (lane >> 4) * 4;
  int ccol = lane & 15;
#pragma unroll
  for (int mi = 0; mi < 4; ++mi)
#pragma unroll
    for (int ni = 0; ni < 4; ++ni) {
      size_t base_r = row0 + wr * 64 + mi * 16 + crow;
      int c = j0 + wc * 64 + ni * 16 + ccol;
#pragma unroll
      for (int r = 0; r < 4; ++r)
        Out[(base_r + r) * HD + c] = (_Float16)acc[mi][ni][r];
    }
}

// ---------------- fused edge + online-softmax agg (packed fp16, 4-unroll) ----------------
__global__ __launch_bounds__(256) void k_edgeagg(const _Float16* __restrict__ Xl,
    const _Float16* __restrict__ Xr, const float* __restrict__ attw,
    const float* __restrict__ bias, const int* __restrict__ rowptr,
    const int* __restrict__ csr_src, _Float16* __restrict__ H16)
{
  int node = blockIdx.x * 4 + (threadIdx.x >> 6);
  int lane = threadIdx.x & 63;
  if (node >= NN) return;
  int st = rowptr[node], en = rowptr[node + 1];
  int c = lane * 4;
  half4v xrv = *(const half4v*)(Xr + (size_t)node * HD + c);
  half2v r01; r01[0] = xrv[0]; r01[1] = xrv[1];
  half2v r23; r23[0] = xrv[2]; r23[1] = xrv[3];
  float4 wvf = *(const float4*)(attw + c);
  half2v w01; w01[0] = (_Float16)wvf.x; w01[1] = (_Float16)wvf.y;
  half2v w23; w23[0] = (_Float16)wvf.z; w23[1] = (_Float16)wvf.w;
  half2v c02; c02[0] = (_Float16)0.2f; c02[1] = (_Float16)0.2f;

  float mh = -1e30f, dsum = 0.f;
  float a0 = 0.f, a1 = 0.f, a2 = 0.f, a3 = 0.f;

  half4v vx[4];
#pragma unroll
  for (int k = 0; k < 4; ++k) {
    int ii = st + k; if (ii >= en) ii = en - 1;
    vx[k] = *(const half4v*)(Xl + (size_t)csr_src[ii] * HD + c);
  }

  for (int i = st; i < en; i += 4) {
    half4v nvx[4];
#pragma unroll
    for (int k = 0; k < 4; ++k) {
      int ii = i + 4 + k; ii = (ii < en) ? ii : (en - 1);
      nvx[k] = *(const half4v*)(Xl + (size_t)csr_src[ii] * HD + c);
    }
    float e[4];
#pragma unroll
    for (int k = 0; k < 4; ++k) {
      half2v x01; x01[0] = vx[k][0]; x01[1] = vx[k][1];
      half2v x23; x23[0] = vx[k][2]; x23[1] = vx[k][3];
      half2v s0 = x01 + r01;
      half2v s1 = x23 + r23;
      half2v m0 = h2max(s0, s0 * c02);
      half2v m1 = h2max(s1, s1 * c02);
      float ek = h2dot(m1, w23, h2dot(m0, w01, 0.f));
      ek += __shfl_xor(ek, 1);
      ek += __shfl_xor(ek, 2);
      ek += __shfl_xor(ek, 4);
      e[k] = (i + k < en) ? ek : -1e30f;
    }
    float pmax = fmaxf(fmaxf(e[0], e[1]), fmaxf(e[2], e[3]));
    if (__any(pmax > mh + 8.f)) {
      float nm = fmaxf(mh, pmax);
      float sc = __expf(mh - nm);
      a0 *= sc; a1 *= sc; a2 *= sc; a3 *= sc; dsum *= sc;
      mh = nm;
    }
    float ps = 0.f;
#pragma unroll
    for (int k = 0; k < 4; ++k) {
      float pw = __expf(e[k] - mh);
      a0 += pw * (float)vx[k][0];
      a1 += pw * (float)vx[k][1];
      a2 += pw * (float)vx[k][2];
      a3 += pw * (float)vx[k][3];
      ps += pw;
    }
    dsum += ps;
#pragma unroll
    for (int k = 0; k < 4; ++k) vx[k] = nvx[k];
  }
  float inv = 1.f / (dsum + 1e-16f);
  float4 bb = *(const float4*)(bias + c);
  float o0 = a0 * inv + bb.x, o1 = a1 * inv + bb.y;
  float o2 = a2 * inv + bb.z, o3 = a3 * inv + bb.w;
  o0 = (o0 > 0.f) ? o0 : expm1f(o0);
  o1 = (o1 > 0.f) ? o1 : expm1f(o1);
  o2 = (o2 > 0.f) ? o2 : expm1f(o2);
  o3 = (o3 > 0.f) ? o3 : expm1f(o3);
  half4v h4;
  h4[0] = (_Float16)o0; h4[1] = (_Float16)o1; h4[2] = (_Float16)o2; h4[3] = (_Float16)o3;
  *(half4v*)(H16 + (size_t)node * HD + c) = h4;
}

// ---------------- global sum: per-block partials ----------------
__global__ __launch_bounds__(256) void k_gsum(const _Float16* __restrict__ H,
    const int* __restrict__ batch, float* __restrict__ gpart, int* __restrict__ gcnt)
{
  __shared__ float flagf[RPB];
  __shared__ int scount;
  int b = blockIdx.x, t = threadIdx.x;
  int r0 = b * RPB;
  int nr = NN - r0; if (nr > RPB) nr = RPB; if (nr < 0) nr = 0;
  if (t == 0) scount = 0;
  __syncthreads();
  if (t < nr) {
    int ok = (batch[r0 + t] == 0) ? 1 : 0;
    flagf[t] = (float)ok;
    if (ok) atomicAdd(&scount, 1);
  }
  __syncthreads();
  float a0 = 0.f, a1 = 0.f, a2 = 0.f, a3 = 0.f;
  const _Float16* Hp = H + (size_t)r0 * HD + t;
  int r = 0;
  for (; r + 4 <= nr; r += 4) {
    float v0 = (float)Hp[(size_t)(r + 0) * HD];
    float v1 = (float)Hp[(size_t)(r + 1) * HD];
    float v2 = (float)Hp[(size_t)(r + 2) * HD];
    float v3 = (float)Hp[(size_t)(r + 3) * HD];
    a0 += v0 * flagf[r + 0]; a1 += v1 * flagf[r + 1];
    a2 += v2 * flagf[r + 2]; a3 += v3 * flagf[r + 3];
  }
  for (; r < nr; ++r) a0 += (float)Hp[(size_t)r * HD] * flagf[r];
  gpart[(size_t)b * HD + t] = (a0 + a1) + (a2 + a3);
  if (t == 0 && scount) atomicAdd(gcnt, scount);
}

__global__ __launch_bounds__(256) void k_gfin(const float* __restrict__ gpart,
    const int* __restrict__ gcnt, float* __restrict__ gvec)
{
  int t = threadIdx.x;
  float a0 = 0.f, a1 = 0.f, a2 = 0.f, a3 = 0.f;
  for (int b = 0; b < GSB; b += 4) {
    a0 += gpart[(size_t)b * HD + t];
    a1 += gpart[(size_t)(b + 1) * HD + t];
    a2 += gpart[(size_t)(b + 2) * HD + t];
    a3 += gpart[(size_t)(b + 3) * HD + t];
  }
  gvec[t] = ((a0 + a1) + (a2 + a3)) / (float)(*gcnt);
}

// ---------------- tail head: sheet pool + geo1 ----------------
__global__ __launch_bounds__(256) void k_tail1(const _Float16* __restrict__ h16,
    const int* __restrict__ sheet_idx, const float* __restrict__ sheet_feat,
    const float* __restrict__ geo_W1, const float* __restrict__ geo_b1,
    const float* __restrict__ geo_g1, const float* __restrict__ geo_be1,
    _Float16* __restrict__ sh16, _Float16* __restrict__ g116)
{
  __shared__ float xf[FI];
  __shared__ int sidx[KS];
  __shared__ float red16[16];
  int s = blockIdx.x, t = threadIdx.x;

  if (t < KS) sidx[t] = sheet_idx[s * KS + t];
  if (t >= 240) xf[t - 240] = sheet_feat[s * FI + (t - 240)];
  __syncthreads();

  float pa[8] = {};
#pragma unroll 2
  for (int r = 0; r < KS; r += 8) {
#pragma unroll
    for (int u = 0; u < 8; ++u)
      pa[u] += (float)h16[(size_t)sidx[r + u] * HD + t];
  }
  float shv = ((pa[0] + pa[1]) + (pa[2] + pa[3]) + (pa[4] + pa[5]) + (pa[6] + pa[7])) * (1.f / KS);
  sh16[(size_t)s * HD + t] = (_Float16)shv;

  float a = geo_b1[t];
#pragma unroll
  for (int k = 0; k < FI; ++k) a += xf[k] * geo_W1[k * HD + t];
  float g1 = ln_fast(a, t, 256, red16, geo_g1, geo_be1, true);
  g116[(size_t)s * HD + t] = (_Float16)g1;
}

// ---------------- MFMA tail building blocks (1 wave per 16 rows) ----------------
template <int KD, int NT, bool ALDS>
__device__ __forceinline__ void mt_mfma(int m0, const _Float16* __restrict__ A,
    int xstr, const _Float16* __restrict__ WT, const float* __restrict__ b,
    f32x4* acc)
{
  int lane = threadIdx.x & 63;
  int arow = lane & 15, kg = lane >> 4;
#pragma unroll
  for (int n = 0; n < NT; ++n) { acc[n][0] = 0.f; acc[n][1] = 0.f; acc[n][2] = 0.f; acc[n][3] = 0.f; }
#pragma unroll
  for (int ks = 0; ks < KD / 32; ++ks) {
    half8 af;
    if (ALDS) {
      int slot = (ks * 4 + kg) ^ (arow & 7);
      af = *(const half8*)(A + arow * KD + slot * 8);
    } else {
      af = *(const half8*)(A + (size_t)(m0 + arow) * xstr + ks * 32 + kg * 8);
    }
#pragma unroll
    for (int n = 0; n < NT; ++n) {
      half8 bf = *(const half8*)(WT + (size_t)(n * 16 + arow) * KD + ks * 32 + kg * 8);
      acc[n] = __builtin_amdgcn_mfma_f32_16x16x32_f16(af, bf, acc[n], 0, 0, 0);
    }
  }
#pragma unroll
  for (int n = 0; n < NT; ++n) {
    float bv = b[n * 16 + arow];
#pragma unroll
    for (int r = 0; r < 4; ++r) acc[n][r] += bv;
  }
}

template <int NT>
__device__ __forceinline__ void mt_ln(f32x4* acc, const float* __restrict__ G,
    const float* __restrict__ Be, bool relu)
{
  int lane = threadIdx.x & 63;
  int arow = lane & 15;
  float s[4] = {}, s2[4] = {};
#pragma unroll
  for (int n = 0; n < NT; ++n)
#pragma unroll
    for (int r = 0; r < 4; ++r) { float v = acc[n][r]; s[r] += v; s2[r] += v * v; }
#pragma unroll
  for (int d = 1; d < 16; d <<= 1) {
#pragma unroll
    for (int r = 0; r < 4; ++r) { s[r] += __shfl_xor(s[r], d); s2[r] += __shfl_xor(s2[r], d); }
  }
  const float invN = 1.f / (NT * 16);
#pragma unroll
  for (int r = 0; r < 4; ++r) {
    float mu = s[r] * invN;
    float var = s2[r] * invN - mu * mu;
    s[r] = mu; s2[r] = rsqrtf(var + 1e-5f);
  }
#pragma unroll
  for (int n = 0; n < NT; ++n) {
    float gv = G[n * 16 + arow], bev = Be[n * 16 + arow];
#pragma unroll
    for (int r = 0; r < 4; ++r) {
      float v = (acc[n][r] - s[r]) * s2[r] * gv + bev;
      acc[n][r] = relu ? fmaxf(v, 0.f) : v;
    }
  }
}

template <int NT>
__device__ __forceinline__ void mt_store_g(const f32x4* acc, _Float16* __restrict__ Y,
    int ystr, int m0)
{
  int lane = threadIdx.x & 63;
  int arow = lane & 15, kg = lane >> 4;
#pragma unroll
  for (int n = 0; n < NT; ++n) {
    int col = n * 16 + arow;
#pragma unroll
    for (int r = 0; r < 4; ++r)
      Y[(size_t)(m0 + kg * 4 + r) * ystr + col] = (_Float16)acc[n][r];
  }
}

template <int NT, int LKD>
__device__ __forceinline__ void mt_store_lds(const f32x4* acc, _Float16* lds)
{
  int lane = threadIdx.x & 63;
  int arow = lane & 15, kg = lane >> 4;
#pragma unroll
  for (int n = 0; n < NT; ++n) {
    int col = n * 16 + arow;
#pragma unroll
    for (int r = 0; r < 4; ++r) {
      int row = kg * 4 + r;
      int phys = (((col >> 3) ^ (row & 7)) << 3) | (col & 7);
      lds[row * LKD + phys] = (_Float16)acc[n][r];
    }
  }
}

// ---------------- stage B: geo2 + q/k/v (grid 16, 64 thr) ----------------
__global__ __launch_bounds__(64) void k_stageB(
    const _Float16* __restrict__ g116, const _Float16* __restrict__ sh16,
    const _Float16* __restrict__ Tgeo2, const float* __restrict__ geo_b2,
    const float* __restrict__ geo_g2, const float* __restrict__ geo_be2,
    const _Float16* __restrict__ Tq, const _Float16* __restrict__ Tk,
    const _Float16* __restrict__ Tv,
    const float* __restrict__ bq, const float* __restrict__ bk,
    const float* __restrict__ bv,
    _Float16* __restrict__ qb, _Float16* __restrict__ kb, _Float16* __restrict__ vb)
{
  __shared__ __align__(16) _Float16 lA[16 * 256];
  int m0 = blockIdx.x * 16;
  f32x4 acc[16];
  // geo2
  mt_mfma<256, 16, false>(m0, g116, 256, Tgeo2, geo_b2, acc);
  mt_ln<16>(acc, geo_g2, geo_be2, true);
  mt_store_lds<16, 256>(acc, lA);
  // q from sheet
  mt_mfma<256, 16, false>(m0, sh16, 256, Tq, bq, acc);
  mt_store_g<16>(acc, qb, 256, m0);
  // k, v from geo2 (LDS)
  mt_mfma<256, 16, true>(m0, lA, 256, Tk, bk, acc);
  mt_store_g<16>(acc, kb, 256, m0);
  mt_mfma<256, 16, true>(m0, lA, 256, Tv, bv, acc);
  mt_store_g<16>(acc, vb, 256, m0);
}

// ---------------- cross-attention per query row (1024 thr) ----------------
__global__ __launch_bounds__(1024) void k_attn(const _Float16* __restrict__ qb,
    const _Float16* __restrict__ kb, const _Float16* __restrict__ vb,
    _Float16* __restrict__ pv16)
{
  __shared__ float qv[HD];
  __shared__ float att[1024];
  __shared__ float red4[1024];
  __shared__ float redm[16];
  __shared__ float reds[16];
  int row = blockIdx.x, t = threadIdx.x;
  int w = t >> 6;

  if (t < 256) qv[t] = (float)qb[(size_t)row * HD + t];
  __syncthreads();

  int h = t >> 8, key = t & 255;
  float e = 0.f;
  {
    const half8* kr = (const half8*)(kb + (size_t)key * HD + h * HC);
    const float* qh = qv + h * HC;
#pragma unroll
    for (int d = 0; d < 8; ++d) {
      half8 kk = kr[d];
#pragma unroll
      for (int u = 0; u < 8; ++u) e += qh[d * 8 + u] * (float)kk[u];
    }
    e *= 0.125f;
  }
  float wm = e;
#pragma unroll
  for (int d = 1; d < 64; d <<= 1) wm = fmaxf(wm, __shfl_xor(wm, d));
  if ((t & 63) == 0) redm[w] = wm;
  __syncthreads();
  float mx = fmaxf(fmaxf(redm[4 * h], redm[4 * h + 1]), fmaxf(redm[4 * h + 2], redm[4 * h + 3]));
  float pw = __expf(e - mx);
  float ws = wsum(pw);
  if ((t & 63) == 0) reds[w] = ws;
  att[t] = pw;
  __syncthreads();

  int kq = t >> 8, j = t & 255;
  int hj = j >> 6;
  float p = 0.f;
  const float* arow = att + hj * 256 + kq * 64;
  const _Float16* vcol = vb + (size_t)(kq * 64) * HD + j;
  for (int k = 0; k < 64; ++k)
    p += arow[k] * (float)vcol[(size_t)k * HD];
  red4[t] = p;
  __syncthreads();
  if (t < 256) {
    int hh = t >> 6;
    float dsum = reds[4 * hh] + reds[4 * hh + 1] + reds[4 * hh + 2] + reds[4 * hh + 3];
    float pv = (red4[t] + red4[256 + t] + red4[512 + t] + red4[768 + t]) / dsum;
    pv16[(size_t)row * HD + t] = (_Float16)pv;
  }
}

// ---------------- stage D: Wo + hq1 + hq2 + qval (+done at blk 16), 64 thr ----------------
__global__ __launch_bounds__(64) void k_stageD(
    const _Float16* __restrict__ pv16, const _Float16* __restrict__ To,
    const float* __restrict__ ca_bo, const float* __restrict__ gvec,
    const _Float16* __restrict__ Tq1, const float* __restrict__ q_b1,
    const float* __restrict__ q_g1, const float* __restrict__ q_be1,
    const _Float16* __restrict__ Tq2, const float* __restrict__ q_b2,
    const float* __restrict__ q_g2, const float* __restrict__ q_be2,
    const float* __restrict__ q_W3, const float* __restrict__ q_b3,
    const float* __restrict__ d_W1, const float* __restrict__ d_b1,
    const float* __restrict__ d_g1, const float* __restrict__ d_be1,
    const float* __restrict__ d_W2, const float* __restrict__ d_b2,
    float* __restrict__ out_q, float* __restrict__ out_d)
{
  __shared__ __align__(16) _Float16 lFu[16 * 256];
  __shared__ __align__(16) _Float16 lH1[16 * 256];
  __shared__ __align__(16) _Float16 lGv[256];
  int lane = threadIdx.x;

  if (blockIdx.x == 16) {
    // ---- done head ----
    float a0 = d_b1[lane], a1 = d_b1[lane + 64];
    for (int k = 0; k < 256; ++k) {
      float g = gvec[k];
      a0 += g * d_W1[(size_t)k * 128 + lane];
      a1 += g * d_W1[(size_t)k * 128 + lane + 64];
    }
    float s = wsum(a0 + a1);
    float s2 = wsum(a0 * a0 + a1 * a1);
    float mu = s * (1.f / 128.f);
    float var = s2 * (1.f / 128.f) - mu * mu;
    float rs = rsqrtf(var + 1e-5f);
    float h0 = fmaxf((a0 - mu) * rs * d_g1[lane] + d_be1[lane], 0.f);
    float h1 = fmaxf((a1 - mu) * rs * d_g1[lane + 64] + d_be1[lane + 64], 0.f);
    float o = wsum(h0 * d_W2[lane] + h1 * d_W2[lane + 64]);
    if (lane == 0) out_d[0] = o + d_b2[0];
    return;
  }

  int m0 = blockIdx.x * 16;
  for (int j = lane; j < 256; j += 64) lGv[j] = (_Float16)gvec[j];

  f32x4 acc[16];
  // Wo
  mt_mfma<256, 16, false>(m0, pv16, 256, To, ca_bo, acc);
  mt_store_lds<16, 256>(acc, lFu);

  // hq1: KD=512, A = [lFu | lGv]
  {
    int arow = lane & 15, kg = lane >> 4;
#pragma unroll
    for (int n = 0; n < 16; ++n) { acc[n][0] = 0.f; acc[n][1] = 0.f; acc[n][2] = 0.f; acc[n][3] = 0.f; }
#pragma unroll
    for (int ks = 0; ks < 16; ++ks) {
      half8 af;
      if (ks < 8) {
        int slot = (ks * 4 + kg) ^ (arow & 7);
        af = *(const half8*)(lFu + arow * 256 + slot * 8);
      } else {
        af = *(const half8*)(lGv + (ks - 8) * 32 + kg * 8);
      }
#pragma unroll
      for (int n = 0; n < 16; ++n) {
        half8 bf = *(const half8*)(Tq1 + (size_t)(n * 16 + arow) * 512 + ks * 32 + kg * 8);
        acc[n] = __builtin_amdgcn_mfma_f32_16x16x32_f16(af, bf, acc[n], 0, 0, 0);
      }
    }
    int a2row = lane & 15;
#pragma unroll
    for (int n = 0; n < 16; ++n) {
      float bv = q_b1[n * 16 + a2row];
#pragma unroll
      for (int r = 0; r < 4; ++r) acc[n][r] += bv;
    }
  }
  mt_ln<16>(acc, q_g1, q_be1, true);
  mt_store_lds<16, 256>(acc, lH1);

  // hq2 (128 out) + qval
  f32x4 acc2[8];
  mt_mfma<256, 8, true>(m0, lH1, 256, Tq2, q_b2, acc2);
  mt_ln<8>(acc2, q_g2, q_be2, true);
  {
    int arow = lane & 15, kg = lane >> 4;
    float p[4] = {};
#pragma unroll
    for (int n = 0; n < 8; ++n) {
      float w3 = q_W3[n * 16 + arow];
#pragma unroll
      for (int r = 0; r < 4; ++r) p[r] += acc2[n][r] * w3;
    }
#pragma unroll
    for (int d = 1; d < 16; d <<= 1)
#pragma unroll
      for (int r = 0; r < 4; ++r) p[r] += __shfl_xor(p[r], d);
    if (arow == 0) {
      float bb = q_b3[0];
#pragma unroll
      for (int r = 0; r < 4; ++r) out_q[m0 + kg * 4 + r] = p[r] + bb;
    }
  }
}

// =====================================================================
extern "C" void kernel_launch(void* const* d_in, const int* in_sizes, int n_in,
                              void* d_out, int out_size, void* d_ws, size_t ws_size,
                              hipStream_t stream) {
  const float* x      = (const float*)d_in[0];
  const int*   ei     = (const int*)d_in[1];
  const int*   batch  = (const int*)d_in[2];
  const int*   sheet_idx = (const int*)d_in[3];
  const float* sheet_feat = (const float*)d_in[4];
  const float* pre_W  = (const float*)d_in[5];
  const float* pre_b  = (const float*)d_in[6];
  const float* gat_Wl = (const float*)d_in[7];
  const float* gat_Wr = (const float*)d_in[8];
  const float* gat_att = (const float*)d_in[9];
  const float* gat_b  = (const float*)d_in[10];
  const float* geo_W1 = (const float*)d_in[11];
  const float* geo_b1 = (const float*)d_in[12];
  const float* geo_g1 = (const float*)d_in[13];
  const float* geo_be1 = (const float*)d_in[14];
  const float* geo_W2 = (const float*)d_in[15];
  const float* geo_b2 = (const float*)d_in[16];
  const float* geo_g2 = (const float*)d_in[17];
  const float* geo_be2 = (const float*)d_in[18];
  const float* ca_Wq = (const float*)d_in[19];
  const float* ca_bq = (const float*)d_in[20];
  const float* ca_Wk = (const float*)d_in[21];
  const float* ca_bk = (const float*)d_in[22];
  const float* ca_Wv = (const float*)d_in[23];
  const float* ca_bv = (const float*)d_in[24];
  const float* ca_Wo = (const float*)d_in[25];
  const float* ca_bo = (const float*)d_in[26];
  const float* q_W1 = (const float*)d_in[27];
  const float* q_b1 = (const float*)d_in[28];
  const float* q_g1 = (const float*)d_in[29];
  const float* q_be1 = (const float*)d_in[30];
  const float* q_W2 = (const float*)d_in[31];
  const float* q_b2 = (const float*)d_in[32];
  const float* q_g2 = (const float*)d_in[33];
  const float* q_be2 = (const float*)d_in[34];
  const float* q_W3 = (const float*)d_in[35];
  const float* q_b3 = (const float*)d_in[36];
  const float* d_W1 = (const float*)d_in[37];
  const float* d_b1 = (const float*)d_in[38];
  const float* d_g1 = (const float*)d_in[39];
  const float* d_be1 = (const float*)d_in[40];
  const float* d_W2 = (const float*)d_in[41];
  const float* d_b2 = (const float*)d_in[42];

  char* wsb = (char*)d_ws;
  auto alloc = [&](size_t bytes) { char* p = wsb; wsb += (bytes + 255) & ~(size_t)255; return p; };

  _Float16* h16  = (_Float16*)alloc((size_t)MPAD * HD * 2);
  _Float16* Xl16 = (_Float16*)alloc((size_t)MPAD * HD * 2);
  _Float16* Xr16 = (_Float16*)alloc((size_t)MPAD * HD * 2);
  _Float16* WT   = (_Float16*)alloc((size_t)6 * HD * HD * 2);
  _Float16* Tgeo2 = (_Float16*)alloc((size_t)HD * HD * 2);
  _Float16* Tq   = (_Float16*)alloc((size_t)HD * HD * 2);
  _Float16* Tk   = (_Float16*)alloc((size_t)HD * HD * 2);
  _Float16* Tv   = (_Float16*)alloc((size_t)HD * HD * 2);
  _Float16* To   = (_Float16*)alloc((size_t)HD * HD * 2);
  _Float16* Tq1  = (_Float16*)alloc((size_t)HD * 512 * 2);
  _Float16* Tq2  = (_Float16*)alloc((size_t)128 * HD * 2);
  _Float16* sh16 = (_Float16*)alloc((size_t)SS * HD * 2);
  _Float16* g116 = (_Float16*)alloc((size_t)SS * HD * 2);
  _Float16* qb16 = (_Float16*)alloc((size_t)SS * HD * 2);
  _Float16* kb16 = (_Float16*)alloc((size_t)SS * HD * 2);
  _Float16* vb16 = (_Float16*)alloc((size_t)SS * HD * 2);
  _Float16* pv16 = (_Float16*)alloc((size_t)SS * HD * 2);
  float* gpart   = (float*)alloc((size_t)GSB * HD * 4);
  float* gvec    = (float*)alloc(256 * 4);
  int* cnt       = (int*)alloc((size_t)NN * 4);
  int* rowptr    = (int*)alloc((size_t)(NN + 1) * 4);
  int* wptr      = (int*)alloc((size_t)NN * 4);
  int* csr_src   = (int*)alloc((size_t)ETOT * 4);
  int* btot      = (int*)alloc((size_t)SCB * 4);
  int* boff      = (int*)alloc((size_t)SCB * 4);
  int* gcnt      = (int*)alloc(4);

  float* out_q = (float*)d_out;        // [256]
  float* out_d = out_q + SS;           // [1]

  // init (zero cnt, gcnt, h16 pad)
  k_init<<<118, 256, 0, stream>>>(cnt, gcnt, h16 + (size_t)NN * HD);

  // CSR build
  k_count<<<(ETOT + 255) / 256, 256, 0, stream>>>(ei, cnt);
  k_scanA<<<SCB, 256, 0, stream>>>(cnt, rowptr, btot);
  k_scanB<<<1, 128, 0, stream>>>(btot, boff, rowptr);
  k_scanC<<<SCB, 256, 0, stream>>>(rowptr, boff, wptr);
  k_scatter<<<(ETOT + 255) / 256, 256, 0, stream>>>(ei, wptr, csr_src);

  // weights + pre-transform
  k_wconv<<<6 * 256, 256, 0, stream>>>(gat_Wl, gat_Wr, WT);
  k_wconvT<<<1664, 256, 0, stream>>>(geo_W2, ca_Wq, ca_Wk, ca_Wv, ca_Wo, q_W1, q_W2,
                                     Tgeo2, Tq, Tk, Tv, To, Tq1, Tq2);
  k_pre<<<NN / 8, 256, 0, stream>>>(x, pre_W, pre_b, h16);

  // GAT layers
  dim3 ggrid(MPAD / 128, 4);
  for (int l = 0; l < NL; ++l) {
    k_gemm16<<<ggrid, 256, 0, stream>>>(h16, WT + (size_t)l * 2 * HD * HD, Xl16, Xr16);
    k_edgeagg<<<(NN + 3) / 4, 256, 0, stream>>>(Xl16, Xr16, gat_att + l * NH * CH,
                                                gat_b + l * HD, rowptr, csr_src, h16);
  }

  // global mean
  k_gsum<<<GSB, 256, 0, stream>>>(h16, batch, gpart, gcnt);
  k_gfin<<<1, 256, 0, stream>>>(gpart, gcnt, gvec);

  // tail
  k_tail1<<<SS, 256, 0, stream>>>(h16, sheet_idx, sheet_feat,
      geo_W1, geo_b1, geo_g1, geo_be1, sh16, g116);
  k_stageB<<<16, 64, 0, stream>>>(g116, sh16, Tgeo2, geo_b2, geo_g2, geo_be2,
      Tq, Tk, Tv, ca_bq, ca_bk, ca_bv, qb16, kb16, vb16);
  k_attn<<<SS, 1024, 0, stream>>>(qb16, kb16, vb16, pv16);
  k_stageD<<<17, 64, 0, stream>>>(pv16, To, ca_bo, gvec,
      Tq1, q_b1, q_g1, q_be1, Tq2, q_b2, q_g2, q_be2, q_W3, q_b3,
      d_W1, d_b1, d_g1, d_be1, d_W2, d_b2, out_q, out_d);
}

// Round 8
// 323.345 us; speedup vs baseline: 1.2711x; 1.2711x over previous
//
#include <hip/hip_runtime.h>
#include <hip/hip_bf16.h>
#include <stdint.h>

#define NN 30000
#define MPAD 30080
#define FI 16
#define EE 300000
#define ETOT (EE + NN)
#define HD 256
#define NH 8
#define CH 32
#define NL 3
#define SS 256
#define KS 128
#define NHC 4
#define HC 64
#define GSB 256
#define RPB 118
#define SCB 118

typedef _Float16 half8 __attribute__((ext_vector_type(8)));
typedef _Float16 half4v __attribute__((ext_vector_type(4)));
typedef _Float16 half2v __attribute__((ext_vector_type(2)));
typedef float f32x4 __attribute__((ext_vector_type(4)));

// ---------------- wave helpers ----------------
__device__ __forceinline__ float wsum(float v) {
#pragma unroll
  for (int d = 1; d < 64; d <<= 1) v += __shfl_xor(v, d);
  return v;
}

__device__ __forceinline__ half2v h2max(half2v a, half2v b) {
#if __has_builtin(__builtin_elementwise_max)
  return __builtin_elementwise_max(a, b);
#else
  half2v r; r[0] = a[0] > b[0] ? a[0] : b[0]; r[1] = a[1] > b[1] ? a[1] : b[1];
  return r;
#endif
}

__device__ __forceinline__ float h2dot(half2v a, half2v b, float c) {
#if __has_builtin(__builtin_amdgcn_fdot2)
  return __builtin_amdgcn_fdot2(a, b, c, false);
#else
  return c + (float)a[0] * (float)b[0] + (float)a[1] * (float)b[1];
#endif
}

// LN over n channels, 256 threads, t<n holds a. 2 barriers.
__device__ __forceinline__ float ln_fast(float a, int t, int n, float* red16,
    const float* __restrict__ G, const float* __restrict__ Be, bool relu)
{
  float av = (t < n) ? a : 0.f;
  float s = wsum(av), s2 = wsum(av * av);
  if ((t & 63) == 0) { red16[t >> 6] = s; red16[8 + (t >> 6)] = s2; }
  __syncthreads();
  float sum = red16[0] + red16[1] + red16[2] + red16[3];
  float sq  = red16[8] + red16[9] + red16[10] + red16[11];
  float mu = sum / n;
  float var = sq / n - mu * mu;
  float o = 0.f;
  if (t < n) {
    o = (a - mu) * rsqrtf(var + 1e-5f) * G[t] + Be[t];
    if (relu) o = fmaxf(o, 0.f);
  }
  __syncthreads();
  return o;
}

// ---------------- init ----------------
__global__ __launch_bounds__(256) void k_init(int* __restrict__ cnt,
    int* __restrict__ gcnt, _Float16* __restrict__ h16pad)
{
  int i = blockIdx.x * 256 + threadIdx.x;
  if (i < NN) cnt[i] = 0;
  if (i == 0) gcnt[0] = 0;
  if (i < (MPAD - NN) * HD) h16pad[i] = (_Float16)0.f;
}

// ---------------- GAT weight transpose+convert ----------------
__global__ __launch_bounds__(256) void k_wconv(const float* __restrict__ Wl,
    const float* __restrict__ Wr, _Float16* __restrict__ WT)
{
  int m = blockIdx.x >> 8;
  int n = blockIdx.x & 255;
  int k = threadIdx.x;
  int l = m >> 1;
  const float* W = (m & 1) ? (Wr + (size_t)l * HD * HD) : (Wl + (size_t)l * HD * HD);
  WT[((size_t)m * HD + n) * HD + k] = (_Float16)W[k * HD + n];
}

// ---------------- tail weight transpose+convert ----------------
__global__ __launch_bounds__(256) void k_wconvT(
    const float* __restrict__ geo_W2, const float* __restrict__ ca_Wq,
    const float* __restrict__ ca_Wk, const float* __restrict__ ca_Wv,
    const float* __restrict__ ca_Wo, const float* __restrict__ q_W1,
    const float* __restrict__ q_W2,
    _Float16* __restrict__ Tgeo2, _Float16* __restrict__ Tq,
    _Float16* __restrict__ Tk, _Float16* __restrict__ Tv,
    _Float16* __restrict__ To, _Float16* __restrict__ Tq1,
    _Float16* __restrict__ Tq2)
{
  int b = blockIdx.x, t = threadIdx.x;
  if (b < 1280) {
    int seg = b >> 8;
    int n = b & 255;
    const float* src = (seg == 0) ? geo_W2 : (seg == 1) ? ca_Wq : (seg == 2) ? ca_Wk
                     : (seg == 3) ? ca_Wv : ca_Wo;
    _Float16* dst = (seg == 0) ? Tgeo2 : (seg == 1) ? Tq : (seg == 2) ? Tk
                  : (seg == 3) ? Tv : To;
    dst[(size_t)n * 256 + t] = (_Float16)src[(size_t)t * 256 + n];
  } else if (b < 1536) {
    int n = b - 1280;
    Tq1[(size_t)n * 512 + t]       = (_Float16)q_W1[(size_t)t * 256 + n];
    Tq1[(size_t)n * 512 + 256 + t] = (_Float16)q_W1[(size_t)(256 + t) * 256 + n];
  } else {
    int n = b - 1536;
    Tq2[(size_t)n * 256 + t] = (_Float16)q_W2[(size_t)t * 128 + n];
  }
}

// ---------------- pre-transform ----------------
__global__ __launch_bounds__(256) void k_pre(const float* __restrict__ x,
    const float* __restrict__ W, const float* __restrict__ b,
    _Float16* __restrict__ H16)
{
  __shared__ float Ws[FI][HD];
  __shared__ float xs[8][FI];
  int r0 = blockIdx.x * 8;
  int t = threadIdx.x;
  for (int i = t; i < FI * HD; i += 256) Ws[i >> 8][i & 255] = W[i];
  if (t < 8 * FI) xs[t >> 4][t & 15] = x[(size_t)(r0 + (t >> 4)) * FI + (t & 15)];
  __syncthreads();
  float bj = b[t];
  for (int r = 0; r < 8; ++r) {
    float acc = bj;
#pragma unroll
    for (int k = 0; k < FI; ++k) acc += xs[r][k] * Ws[k][t];
    H16[(size_t)(r0 + r) * HD + t] = (_Float16)acc;
  }
}

// ---------------- CSR build ----------------
__global__ __launch_bounds__(256) void k_count(const int* __restrict__ ei, int* __restrict__ cnt)
{
  int i = blockIdx.x * 256 + threadIdx.x;
  if (i >= ETOT) return;
  int dst = (i < EE) ? ei[EE + i] : (i - EE);
  atomicAdd(&cnt[dst], 1);
}

__global__ __launch_bounds__(256) void k_scanA(const int* __restrict__ cnt,
    int* __restrict__ rowptr, int* __restrict__ btot)
{
  __shared__ int wt[4];
  int b = blockIdx.x, t = threadIdx.x;
  int i = b * 256 + t;
  int v = (i < NN) ? cnt[i] : 0;
  int lane = t & 63, w = t >> 6;
  int s = v;
#pragma unroll
  for (int d = 1; d < 64; d <<= 1) {
    int u = __shfl_up(s, d);
    if (lane >= d) s += u;
  }
  if (lane == 63) wt[w] = s;
  __syncthreads();
  int off = 0;
  for (int k = 0; k < w; ++k) off += wt[k];
  if (i < NN) rowptr[i] = off + s - v;
  if (t == 255) btot[b] = off + s;
}

__global__ __launch_bounds__(128) void k_scanB(const int* __restrict__ btot,
    int* __restrict__ boff, int* __restrict__ rowptr)
{
  __shared__ int wt[2];
  int t = threadIdx.x;
  int v = (t < SCB) ? btot[t] : 0;
  int lane = t & 63, w = t >> 6;
  int s = v;
#pragma unroll
  for (int d = 1; d < 64; d <<= 1) {
    int u = __shfl_up(s, d);
    if (lane >= d) s += u;
  }
  if (lane == 63) wt[w] = s;
  __syncthreads();
  int off = (w == 1) ? wt[0] : 0;
  if (t < SCB) boff[t] = off + s - v;
  if (t == 127) rowptr[NN] = wt[0] + wt[1];
}

__global__ __launch_bounds__(256) void k_scanC(int* __restrict__ rowptr,
    const int* __restrict__ boff, int* __restrict__ wptr)
{
  int b = blockIdx.x, t = threadIdx.x;
  int i = b * 256 + t;
  if (i < NN) {
    int r = rowptr[i] + boff[b];
    rowptr[i] = r;
    wptr[i] = r;
  }
}

__global__ __launch_bounds__(256) void k_scatter(const int* __restrict__ ei,
    int* __restrict__ wptr, int* __restrict__ csr_src)
{
  int i = blockIdx.x * 256 + threadIdx.x;
  if (i >= ETOT) return;
  int src = (i < EE) ? ei[i] : (i - EE);
  int dst = (i < EE) ? ei[EE + i] : (i - EE);
  int pos = atomicAdd(&wptr[dst], 1);
  csr_src[pos] = src;
}

// ---------------- fp16 MFMA GEMM (GAT layers) ----------------
#define BK 64
__global__ __launch_bounds__(256) void k_gemm16(const _Float16* __restrict__ A,
    const _Float16* __restrict__ WT,
    _Float16* __restrict__ Xl, _Float16* __restrict__ Xr)
{
  __shared__ __align__(16) _Float16 As[128 * BK];
  __shared__ __align__(16) _Float16 Bs[128 * BK];
  int t = threadIdx.x;
  int w = t >> 6, lane = t & 63;
  int row0 = blockIdx.x * 128;
  int ct = blockIdx.y;
  const _Float16* Bmat = WT + (size_t)(ct >> 1) * HD * HD + (size_t)(ct & 1) * 128 * HD;
  _Float16* Out = (ct >> 1) ? Xr : Xl;
  int j0 = (ct & 1) * 128;

  f32x4 acc[4][4] = {};
  int wr = w >> 1, wc = w & 1;

  for (int k0 = 0; k0 < HD; k0 += BK) {
#pragma unroll
    for (int i = 0; i < 4; ++i) {
      int p = (i * 4 + w) * 64 + lane;
      int row = p >> 3, s = p & 7;
      int g = s ^ (row & 7);
      const _Float16* srcA = A + (size_t)(row0 + row) * HD + k0 + g * 8;
      __builtin_amdgcn_global_load_lds(
        (const __attribute__((address_space(1))) void*)srcA,
        (__attribute__((address_space(3))) void*)((char*)As + (i * 4 + w) * 1024),
        16, 0, 0);
      const _Float16* srcB = Bmat + (size_t)row * HD + k0 + g * 8;
      __builtin_amdgcn_global_load_lds(
        (const __attribute__((address_space(1))) void*)srcB,
        (__attribute__((address_space(3))) void*)((char*)Bs + (i * 4 + w) * 1024),
        16, 0, 0);
    }
    __syncthreads();
#pragma unroll
    for (int ks = 0; ks < 2; ++ks) {
      half8 af[4], bfr[4];
      int kslot = ks * 4 + (lane >> 4);
#pragma unroll
      for (int mi = 0; mi < 4; ++mi) {
        int rl = wr * 64 + mi * 16 + (lane & 15);
        int ps = kslot ^ (rl & 7);
        af[mi] = *(const half8*)((const char*)As + rl * 128 + ps * 16);
      }
#pragma unroll
      for (int ni = 0; ni < 4; ++ni) {
        int nl = wc * 64 + ni * 16 + (lane & 15);
        int ps = kslot ^ (nl & 7);
        bfr[ni] = *(const half8*)((const char*)Bs + nl * 128 + ps * 16);
      }
#pragma unroll
      for (int mi = 0; mi < 4; ++mi)
#pragma unroll
        for (int ni = 0; ni < 4; ++ni)
          acc[mi][ni] = __builtin_amdgcn_mfma_f32_16x16x32_f16(af[mi], bfr[ni], acc[mi][ni], 0, 0, 0);
    }
    __syncthreads();
  }
  int crow = (lane >> 4) * 4;
  int ccol = lane & 15;
#pragma unroll
  for (int mi = 0; mi < 4; ++mi)
#pragma unroll
    for (int ni = 0; ni < 4; ++ni) {
      size_t base_r = row0 + wr * 64 + mi * 16 + crow;
      int c = j0 + wc * 64 + ni * 16 + ccol;
#pragma unroll
      for (int r = 0; r < 4; ++r)
        Out[(base_r + r) * HD + c] = (_Float16)acc[mi][ni][r];
    }
}

// ---------------- fused edge + online-softmax agg (packed fp16, 4-unroll) ----------------
__global__ __launch_bounds__(256) void k_edgeagg(const _Float16* __restrict__ Xl,
    const _Float16* __restrict__ Xr, const float* __restrict__ attw,
    const float* __restrict__ bias, const int* __restrict__ rowptr,
    const int* __restrict__ csr_src, _Float16* __restrict__ H16)
{
  int node = blockIdx.x * 4 + (threadIdx.x >> 6);
  int lane = threadIdx.x & 63;
  if (node >= NN) return;
  int st = rowptr[node], en = rowptr[node + 1];
  int c = lane * 4;
  half4v xrv = *(const half4v*)(Xr + (size_t)node * HD + c);
  half2v r01; r01[0] = xrv[0]; r01[1] = xrv[1];
  half2v r23; r23[0] = xrv[2]; r23[1] = xrv[3];
  float4 wvf = *(const float4*)(attw + c);
  half2v w01; w01[0] = (_Float16)wvf.x; w01[1] = (_Float16)wvf.y;
  half2v w23; w23[0] = (_Float16)wvf.z; w23[1] = (_Float16)wvf.w;
  half2v c02; c02[0] = (_Float16)0.2f; c02[1] = (_Float16)0.2f;

  float mh = -1e30f, dsum = 0.f;
  float a0 = 0.f, a1 = 0.f, a2 = 0.f, a3 = 0.f;

  half4v vx[4];
#pragma unroll
  for (int k = 0; k < 4; ++k) {
    int ii = st + k; if (ii >= en) ii = en - 1;
    vx[k] = *(const half4v*)(Xl + (size_t)csr_src[ii] * HD + c);
  }

  for (int i = st; i < en; i += 4) {
    half4v nvx[4];
#pragma unroll
    for (int k = 0; k < 4; ++k) {
      int ii = i + 4 + k; ii = (ii < en) ? ii : (en - 1);
      nvx[k] = *(const half4v*)(Xl + (size_t)csr_src[ii] * HD + c);
    }
    float e[4];
#pragma unroll
    for (int k = 0; k < 4; ++k) {
      half2v x01; x01[0] = vx[k][0]; x01[1] = vx[k][1];
      half2v x23; x23[0] = vx[k][2]; x23[1] = vx[k][3];
      half2v s0 = x01 + r01;
      half2v s1 = x23 + r23;
      half2v m0 = h2max(s0, s0 * c02);
      half2v m1 = h2max(s1, s1 * c02);
      float ek = h2dot(m1, w23, h2dot(m0, w01, 0.f));
      ek += __shfl_xor(ek, 1);
      ek += __shfl_xor(ek, 2);
      ek += __shfl_xor(ek, 4);
      e[k] = (i + k < en) ? ek : -1e30f;
    }
    float pmax = fmaxf(fmaxf(e[0], e[1]), fmaxf(e[2], e[3]));
    if (__any(pmax > mh + 8.f)) {
      float nm = fmaxf(mh, pmax);
      float sc = __expf(mh - nm);
      a0 *= sc; a1 *= sc; a2 *= sc; a3 *= sc; dsum *= sc;
      mh = nm;
    }
    float ps = 0.f;
#pragma unroll
    for (int k = 0; k < 4; ++k) {
      float pw = __expf(e[k] - mh);
      a0 += pw * (float)vx[k][0];
      a1 += pw * (float)vx[k][1];
      a2 += pw * (float)vx[k][2];
      a3 += pw * (float)vx[k][3];
      ps += pw;
    }
    dsum += ps;
#pragma unroll
    for (int k = 0; k < 4; ++k) vx[k] = nvx[k];
  }
  float inv = 1.f / (dsum + 1e-16f);
  float4 bb = *(const float4*)(bias + c);
  float o0 = a0 * inv + bb.x, o1 = a1 * inv + bb.y;
  float o2 = a2 * inv + bb.z, o3 = a3 * inv + bb.w;
  o0 = (o0 > 0.f) ? o0 : expm1f(o0);
  o1 = (o1 > 0.f) ? o1 : expm1f(o1);
  o2 = (o2 > 0.f) ? o2 : expm1f(o2);
  o3 = (o3 > 0.f) ? o3 : expm1f(o3);
  half4v h4;
  h4[0] = (_Float16)o0; h4[1] = (_Float16)o1; h4[2] = (_Float16)o2; h4[3] = (_Float16)o3;
  *(half4v*)(H16 + (size_t)node * HD + c) = h4;
}

// ---------------- global sum: per-block partials ----------------
__global__ __launch_bounds__(256) void k_gsum(const _Float16* __restrict__ H,
    const int* __restrict__ batch, float* __restrict__ gpart, int* __restrict__ gcnt)
{
  __shared__ float flagf[RPB];
  __shared__ int scount;
  int b = blockIdx.x, t = threadIdx.x;
  int r0 = b * RPB;
  int nr = NN - r0; if (nr > RPB) nr = RPB; if (nr < 0) nr = 0;
  if (t == 0) scount = 0;
  __syncthreads();
  if (t < nr) {
    int ok = (batch[r0 + t] == 0) ? 1 : 0;
    flagf[t] = (float)ok;
    if (ok) atomicAdd(&scount, 1);
  }
  __syncthreads();
  float a0 = 0.f, a1 = 0.f, a2 = 0.f, a3 = 0.f;
  const _Float16* Hp = H + (size_t)r0 * HD + t;
  int r = 0;
  for (; r + 4 <= nr; r += 4) {
    float v0 = (float)Hp[(size_t)(r + 0) * HD];
    float v1 = (float)Hp[(size_t)(r + 1) * HD];
    float v2 = (float)Hp[(size_t)(r + 2) * HD];
    float v3 = (float)Hp[(size_t)(r + 3) * HD];
    a0 += v0 * flagf[r + 0]; a1 += v1 * flagf[r + 1];
    a2 += v2 * flagf[r + 2]; a3 += v3 * flagf[r + 3];
  }
  for (; r < nr; ++r) a0 += (float)Hp[(size_t)r * HD] * flagf[r];
  gpart[(size_t)b * HD + t] = (a0 + a1) + (a2 + a3);
  if (t == 0 && scount) atomicAdd(gcnt, scount);
}

__global__ __launch_bounds__(256) void k_gfin(const float* __restrict__ gpart,
    const int* __restrict__ gcnt, float* __restrict__ gvec)
{
  int t = threadIdx.x;
  float a0 = 0.f, a1 = 0.f, a2 = 0.f, a3 = 0.f;
  for (int b = 0; b < GSB; b += 4) {
    a0 += gpart[(size_t)b * HD + t];
    a1 += gpart[(size_t)(b + 1) * HD + t];
    a2 += gpart[(size_t)(b + 2) * HD + t];
    a3 += gpart[(size_t)(b + 3) * HD + t];
  }
  gvec[t] = ((a0 + a1) + (a2 + a3)) / (float)(*gcnt);
}

// ---------------- tail head: sheet pool + geo1 ----------------
__global__ __launch_bounds__(256) void k_tail1(const _Float16* __restrict__ h16,
    const int* __restrict__ sheet_idx, const float* __restrict__ sheet_feat,
    const float* __restrict__ geo_W1, const float* __restrict__ geo_b1,
    const float* __restrict__ geo_g1, const float* __restrict__ geo_be1,
    _Float16* __restrict__ sh16, _Float16* __restrict__ g116)
{
  __shared__ float xf[FI];
  __shared__ int sidx[KS];
  __shared__ float red16[16];
  int s = blockIdx.x, t = threadIdx.x;

  if (t < KS) sidx[t] = sheet_idx[s * KS + t];
  if (t >= 240) xf[t - 240] = sheet_feat[s * FI + (t - 240)];
  __syncthreads();

  float pa[8] = {};
#pragma unroll 2
  for (int r = 0; r < KS; r += 8) {
#pragma unroll
    for (int u = 0; u < 8; ++u)
      pa[u] += (float)h16[(size_t)sidx[r + u] * HD + t];
  }
  float shv = ((pa[0] + pa[1]) + (pa[2] + pa[3]) + (pa[4] + pa[5]) + (pa[6] + pa[7])) * (1.f / KS);
  sh16[(size_t)s * HD + t] = (_Float16)shv;

  float a = geo_b1[t];
#pragma unroll
  for (int k = 0; k < FI; ++k) a += xf[k] * geo_W1[k * HD + t];
  float g1 = ln_fast(a, t, 256, red16, geo_g1, geo_be1, true);
  g116[(size_t)s * HD + t] = (_Float16)g1;
}

// ---------------- MFMA tail stage with LN (NW waves, 16 rows/block) ----------------
// each wave owns 64 output cols (NT=4); LN across NW*64 cols via 1 LDS combine
template <int KD, int NW>
__global__ __launch_bounds__(NW * 64) void k_stageLN(
    const _Float16* __restrict__ X, const _Float16* __restrict__ WT,
    const float* __restrict__ b, const float* __restrict__ G,
    const float* __restrict__ Be, _Float16* __restrict__ Y,
    const float* __restrict__ W3, const float* __restrict__ b3,
    float* __restrict__ outq)
{
  __shared__ float ps[NW * 16], ps2[NW * 16], pq[NW * 16];
  const int NCOL = NW * 64;
  int t = threadIdx.x;
  int w = t >> 6, lane = t & 63;
  int arow = lane & 15, kg = lane >> 4;
  int m0 = blockIdx.x * 16;
  int col0 = w * 64;

  f32x4 acc[4] = {};
#pragma unroll
  for (int ks = 0; ks < KD / 32; ++ks) {
    half8 af = *(const half8*)(X + (size_t)(m0 + arow) * KD + ks * 32 + kg * 8);
#pragma unroll
    for (int n = 0; n < 4; ++n) {
      half8 bf = *(const half8*)(WT + (size_t)(col0 + n * 16 + arow) * KD + ks * 32 + kg * 8);
      acc[n] = __builtin_amdgcn_mfma_f32_16x16x32_f16(af, bf, acc[n], 0, 0, 0);
    }
  }
#pragma unroll
  for (int n = 0; n < 4; ++n) {
    float bv = b[col0 + n * 16 + arow];
#pragma unroll
    for (int r = 0; r < 4; ++r) acc[n][r] += bv;
  }
  // per-row partial sums over this wave's 64 cols
  float s[4] = {}, s2[4] = {};
#pragma unroll
  for (int n = 0; n < 4; ++n)
#pragma unroll
    for (int r = 0; r < 4; ++r) { float v = acc[n][r]; s[r] += v; s2[r] += v * v; }
#pragma unroll
  for (int d = 1; d < 16; d <<= 1)
#pragma unroll
    for (int r = 0; r < 4; ++r) { s[r] += __shfl_xor(s[r], d); s2[r] += __shfl_xor(s2[r], d); }
  if (arow == 0) {
#pragma unroll
    for (int r = 0; r < 4; ++r) {
      ps[w * 16 + kg * 4 + r] = s[r];
      ps2[w * 16 + kg * 4 + r] = s2[r];
    }
  }
  __syncthreads();
  float mu[4], rs[4];
#pragma unroll
  for (int r = 0; r < 4; ++r) {
    float S = 0.f, S2 = 0.f;
#pragma unroll
    for (int w2 = 0; w2 < NW; ++w2) { S += ps[w2 * 16 + kg * 4 + r]; S2 += ps2[w2 * 16 + kg * 4 + r]; }
    float m = S / NCOL;
    float var = S2 / NCOL - m * m;
    mu[r] = m; rs[r] = rsqrtf(var + 1e-5f);
  }
#pragma unroll
  for (int n = 0; n < 4; ++n) {
    int col = col0 + n * 16 + arow;
    float gv = G[col], bev = Be[col];
#pragma unroll
    for (int r = 0; r < 4; ++r)
      acc[n][r] = fmaxf((acc[n][r] - mu[r]) * rs[r] * gv + bev, 0.f);
  }
  if (Y) {
#pragma unroll
    for (int n = 0; n < 4; ++n) {
      int col = col0 + n * 16 + arow;
#pragma unroll
      for (int r = 0; r < 4; ++r)
        Y[(size_t)(m0 + kg * 4 + r) * NCOL + col] = (_Float16)acc[n][r];
    }
  }
  if (outq) {
    float p[4] = {};
#pragma unroll
    for (int n = 0; n < 4; ++n) {
      float w3 = W3[col0 + n * 16 + arow];
#pragma unroll
      for (int r = 0; r < 4; ++r) p[r] += acc[n][r] * w3;
    }
#pragma unroll
    for (int d = 1; d < 16; d <<= 1)
#pragma unroll
      for (int r = 0; r < 4; ++r) p[r] += __shfl_xor(p[r], d);
    if (arow == 0)
#pragma unroll
      for (int r = 0; r < 4; ++r) pq[w * 16 + kg * 4 + r] = p[r];
    __syncthreads();
    if (w == 0 && arow == 0) {
#pragma unroll
      for (int r = 0; r < 4; ++r) {
        float o = b3[0];
#pragma unroll
        for (int w2 = 0; w2 < NW; ++w2) o += pq[w2 * 16 + kg * 4 + r];
        outq[m0 + kg * 4 + r] = o;
      }
    }
  }
}

// ---------------- q/k/v stage (no LN): grid (16 rowtiles, 4 colblocks, 3 mats) ----------------
__global__ __launch_bounds__(64) void k_qkv(
    const _Float16* __restrict__ sh16, const _Float16* __restrict__ g216,
    const _Float16* __restrict__ Tq, const _Float16* __restrict__ Tk,
    const _Float16* __restrict__ Tv,
    const float* __restrict__ bq, const float* __restrict__ bk,
    const float* __restrict__ bv,
    _Float16* __restrict__ qb, _Float16* __restrict__ kb, _Float16* __restrict__ vb)
{
  int lane = threadIdx.x;
  int arow = lane & 15, kg = lane >> 4;
  int m0 = blockIdx.x * 16;
  int col0 = blockIdx.y * 64;
  int mat = blockIdx.z;
  const _Float16* X = (mat == 0) ? sh16 : g216;
  const _Float16* WT = (mat == 0) ? Tq : (mat == 1) ? Tk : Tv;
  const float* b = (mat == 0) ? bq : (mat == 1) ? bk : bv;
  _Float16* Y = (mat == 0) ? qb : (mat == 1) ? kb : vb;

  f32x4 acc[4] = {};
#pragma unroll
  for (int ks = 0; ks < 8; ++ks) {
    half8 af = *(const half8*)(X + (size_t)(m0 + arow) * 256 + ks * 32 + kg * 8);
#pragma unroll
    for (int n = 0; n < 4; ++n) {
      half8 bf = *(const half8*)(WT + (size_t)(col0 + n * 16 + arow) * 256 + ks * 32 + kg * 8);
      acc[n] = __builtin_amdgcn_mfma_f32_16x16x32_f16(af, bf, acc[n], 0, 0, 0);
    }
  }
#pragma unroll
  for (int n = 0; n < 4; ++n) {
    int col = col0 + n * 16 + arow;
    float bv2 = b[col];
#pragma unroll
    for (int r = 0; r < 4; ++r)
      Y[(size_t)(m0 + kg * 4 + r) * 256 + col] = (_Float16)(acc[n][r] + bv2);
  }
}

// ---------------- Wo stage + gv concat: grid (16, 4) ----------------
__global__ __launch_bounds__(64) void k_wo(
    const _Float16* __restrict__ pv16, const _Float16* __restrict__ To,
    const float* __restrict__ bo, const float* __restrict__ gvec,
    _Float16* __restrict__ hqin)
{
  int lane = threadIdx.x;
  int arow = lane & 15, kg = lane >> 4;
  int m0 = blockIdx.x * 16;
  int col0 = blockIdx.y * 64;

  f32x4 acc[4] = {};
#pragma unroll
  for (int ks = 0; ks < 8; ++ks) {
    half8 af = *(const half8*)(pv16 + (size_t)(m0 + arow) * 256 + ks * 32 + kg * 8);
#pragma unroll
    for (int n = 0; n < 4; ++n) {
      half8 bf = *(const half8*)(To + (size_t)(col0 + n * 16 + arow) * 256 + ks * 32 + kg * 8);
      acc[n] = __builtin_amdgcn_mfma_f32_16x16x32_f16(af, bf, acc[n], 0, 0, 0);
    }
  }
#pragma unroll
  for (int n = 0; n < 4; ++n) {
    int col = col0 + n * 16 + arow;
    float bv = bo[col];
    _Float16 gg = (_Float16)gvec[col];
#pragma unroll
    for (int r = 0; r < 4; ++r) {
      hqin[(size_t)(m0 + kg * 4 + r) * 512 + col] = (_Float16)(acc[n][r] + bv);
      hqin[(size_t)(m0 + kg * 4 + r) * 512 + 256 + col] = gg;
    }
  }
}

// ---------------- cross-attention per query row (1024 thr) ----------------
__global__ __launch_bounds__(1024) void k_attn(const _Float16* __restrict__ qb,
    const _Float16* __restrict__ kb, const _Float16* __restrict__ vb,
    _Float16* __restrict__ pv16)
{
  __shared__ float qv[HD];
  __shared__ float att[1024];
  __shared__ float red4[1024];
  __shared__ float redm[16];
  __shared__ float reds[16];
  int row = blockIdx.x, t = threadIdx.x;
  int w = t >> 6;

  if (t < 256) qv[t] = (float)qb[(size_t)row * HD + t];
  __syncthreads();

  int h = t >> 8, key = t & 255;
  float e = 0.f;
  {
    const half8* kr = (const half8*)(kb + (size_t)key * HD + h * HC);
    const float* qh = qv + h * HC;
#pragma unroll
    for (int d = 0; d < 8; ++d) {
      half8 kk = kr[d];
#pragma unroll
      for (int u = 0; u < 8; ++u) e += qh[d * 8 + u] * (float)kk[u];
    }
    e *= 0.125f;
  }
  float wm = e;
#pragma unroll
  for (int d = 1; d < 64; d <<= 1) wm = fmaxf(wm, __shfl_xor(wm, d));
  if ((t & 63) == 0) redm[w] = wm;
  __syncthreads();
  float mx = fmaxf(fmaxf(redm[4 * h], redm[4 * h + 1]), fmaxf(redm[4 * h + 2], redm[4 * h + 3]));
  float pw = __expf(e - mx);
  float ws = wsum(pw);
  if ((t & 63) == 0) reds[w] = ws;
  att[t] = pw;
  __syncthreads();

  int kq = t >> 8, j = t & 255;
  int hj = j >> 6;
  float p = 0.f;
  const float* arow = att + hj * 256 + kq * 64;
  const _Float16* vcol = vb + (size_t)(kq * 64) * HD + j;
  for (int k = 0; k < 64; ++k)
    p += arow[k] * (float)vcol[(size_t)k * HD];
  red4[t] = p;
  __syncthreads();
  if (t < 256) {
    int hh = t >> 6;
    float dsum = reds[4 * hh] + reds[4 * hh + 1] + reds[4 * hh + 2] + reds[4 * hh + 3];
    float pv = (red4[t] + red4[256 + t] + red4[512 + t] + red4[768 + t]) / dsum;
    pv16[(size_t)row * HD + t] = (_Float16)pv;
  }
}

// ---------------- done predictor ----------------
__global__ __launch_bounds__(256) void k_done(const float* __restrict__ gvec,
    const float* __restrict__ W1, const float* __restrict__ b1,
    const float* __restrict__ g1, const float* __restrict__ be1,
    const float* __restrict__ W2, const float* __restrict__ b2,
    float* __restrict__ out)
{
  __shared__ float gl[256];
  __shared__ float redc[256];
  __shared__ float red16[16];
  int t = threadIdx.x;
  gl[t] = gvec[t];
  __syncthreads();
  int j2 = t & 127, half = t >> 7;
  float p = 0.f;
#pragma unroll 8
  for (int k = half * 128; k < half * 128 + 128; ++k) p += gl[k] * W1[(size_t)k * 128 + j2];
  redc[t] = p;
  __syncthreads();
  float a = 0.f;
  if (t < 128) a = b1[t] + redc[t] + redc[128 + t];
  float hd = ln_fast(a, t, 128, red16, g1, be1, true);
  float vterm = (t < 128) ? hd * W2[t] : 0.f;
  float ss = wsum(vterm);
  if ((t & 63) == 0) red16[t >> 6] = ss;
  __syncthreads();
  if (t == 0) out[0] = red16[0] + red16[1] + red16[2] + red16[3] + b2[0];
}

// =====================================================================
extern "C" void kernel_launch(void* const* d_in, const int* in_sizes, int n_in,
                              void* d_out, int out_size, void* d_ws, size_t ws_size,
                              hipStream_t stream) {
  const float* x      = (const float*)d_in[0];
  const int*   ei     = (const int*)d_in[1];
  const int*   batch  = (const int*)d_in[2];
  const int*   sheet_idx = (const int*)d_in[3];
  const float* sheet_feat = (const float*)d_in[4];
  const float* pre_W  = (const float*)d_in[5];
  const float* pre_b  = (const float*)d_in[6];
  const float* gat_Wl = (const float*)d_in[7];
  const float* gat_Wr = (const float*)d_in[8];
  const float* gat_att = (const float*)d_in[9];
  const float* gat_b  = (const float*)d_in[10];
  const float* geo_W1 = (const float*)d_in[11];
  const float* geo_b1 = (const float*)d_in[12];
  const float* geo_g1 = (const float*)d_in[13];
  const float* geo_be1 = (const float*)d_in[14];
  const float* geo_W2 = (const float*)d_in[15];
  const float* geo_b2 = (const float*)d_in[16];
  const float* geo_g2 = (const float*)d_in[17];
  const float* geo_be2 = (const float*)d_in[18];
  const float* ca_Wq = (const float*)d_in[19];
  const float* ca_bq = (const float*)d_in[20];
  const float* ca_Wk = (const float*)d_in[21];
  const float* ca_bk = (const float*)d_in[22];
  const float* ca_Wv = (const float*)d_in[23];
  const float* ca_bv = (const float*)d_in[24];
  const float* ca_Wo = (const float*)d_in[25];
  const float* ca_bo = (const float*)d_in[26];
  const float* q_W1 = (const float*)d_in[27];
  const float* q_b1 = (const float*)d_in[28];
  const float* q_g1 = (const float*)d_in[29];
  const float* q_be1 = (const float*)d_in[30];
  const float* q_W2 = (const float*)d_in[31];
  const float* q_b2 = (const float*)d_in[32];
  const float* q_g2 = (const float*)d_in[33];
  const float* q_be2 = (const float*)d_in[34];
  const float* q_W3 = (const float*)d_in[35];
  const float* q_b3 = (const float*)d_in[36];
  const float* d_W1 = (const float*)d_in[37];
  const float* d_b1 = (const float*)d_in[38];
  const float* d_g1 = (const float*)d_in[39];
  const float* d_be1 = (const float*)d_in[40];
  const float* d_W2 = (const float*)d_in[41];
  const float* d_b2 = (const float*)d_in[42];

  char* wsb = (char*)d_ws;
  auto alloc = [&](size_t bytes) { char* p = wsb; wsb += (bytes + 255) & ~(size_t)255; return p; };

  _Float16* h16  = (_Float16*)alloc((size_t)MPAD * HD * 2);
  _Float16* Xl16 = (_Float16*)alloc((size_t)MPAD * HD * 2);
  _Float16* Xr16 = (_Float16*)alloc((size_t)MPAD * HD * 2);
  _Float16* WT   = (_Float16*)alloc((size_t)6 * HD * HD * 2);
  _Float16* Tgeo2 = (_Float16*)alloc((size_t)HD * HD * 2);
  _Float16* Tq   = (_Float16*)alloc((size_t)HD * HD * 2);
  _Float16* Tk   = (_Float16*)alloc((size_t)HD * HD * 2);
  _Float16* Tv   = (_Float16*)alloc((size_t)HD * HD * 2);
  _Float16* To   = (_Float16*)alloc((size_t)HD * HD * 2);
  _Float16* Tq1  = (_Float16*)alloc((size_t)HD * 512 * 2);
  _Float16* Tq2  = (_Float16*)alloc((size_t)128 * HD * 2);
  _Float16* sh16 = (_Float16*)alloc((size_t)SS * HD * 2);
  _Float16* g116 = (_Float16*)alloc((size_t)SS * HD * 2);
  _Float16* g216 = (_Float16*)alloc((size_t)SS * HD * 2);
  _Float16* qb16 = (_Float16*)alloc((size_t)SS * HD * 2);
  _Float16* kb16 = (_Float16*)alloc((size_t)SS * HD * 2);
  _Float16* vb16 = (_Float16*)alloc((size_t)SS * HD * 2);
  _Float16* pv16 = (_Float16*)alloc((size_t)SS * HD * 2);
  _Float16* hqin16 = (_Float16*)alloc((size_t)SS * 512 * 2);
  _Float16* hq116 = (_Float16*)alloc((size_t)SS * HD * 2);
  float* gpart   = (float*)alloc((size_t)GSB * HD * 4);
  float* gvec    = (float*)alloc(256 * 4);
  int* cnt       = (int*)alloc((size_t)NN * 4);
  int* rowptr    = (int*)alloc((size_t)(NN + 1) * 4);
  int* wptr      = (int*)alloc((size_t)NN * 4);
  int* csr_src   = (int*)alloc((size_t)ETOT * 4);
  int* btot      = (int*)alloc((size_t)SCB * 4);
  int* boff      = (int*)alloc((size_t)SCB * 4);
  int* gcnt      = (int*)alloc(4);

  float* out_q = (float*)d_out;        // [256]
  float* out_d = out_q + SS;           // [1]

  k_init<<<118, 256, 0, stream>>>(cnt, gcnt, h16 + (size_t)NN * HD);

  // CSR build
  k_count<<<(ETOT + 255) / 256, 256, 0, stream>>>(ei, cnt);
  k_scanA<<<SCB, 256, 0, stream>>>(cnt, rowptr, btot);
  k_scanB<<<1, 128, 0, stream>>>(btot, boff, rowptr);
  k_scanC<<<SCB, 256, 0, stream>>>(rowptr, boff, wptr);
  k_scatter<<<(ETOT + 255) / 256, 256, 0, stream>>>(ei, wptr, csr_src);

  // weights + pre-transform
  k_wconv<<<6 * 256, 256, 0, stream>>>(gat_Wl, gat_Wr, WT);
  k_wconvT<<<1664, 256, 0, stream>>>(geo_W2, ca_Wq, ca_Wk, ca_Wv, ca_Wo, q_W1, q_W2,
                                     Tgeo2, Tq, Tk, Tv, To, Tq1, Tq2);
  k_pre<<<NN / 8, 256, 0, stream>>>(x, pre_W, pre_b, h16);

  // GAT layers
  dim3 ggrid(MPAD / 128, 4);
  for (int l = 0; l < NL; ++l) {
    k_gemm16<<<ggrid, 256, 0, stream>>>(h16, WT + (size_t)l * 2 * HD * HD, Xl16, Xr16);
    k_edgeagg<<<(NN + 3) / 4, 256, 0, stream>>>(Xl16, Xr16, gat_att + l * NH * CH,
                                                gat_b + l * HD, rowptr, csr_src, h16);
  }

  // global mean
  k_gsum<<<GSB, 256, 0, stream>>>(h16, batch, gpart, gcnt);
  k_gfin<<<1, 256, 0, stream>>>(gpart, gcnt, gvec);

  // tail
  k_tail1<<<SS, 256, 0, stream>>>(h16, sheet_idx, sheet_feat,
      geo_W1, geo_b1, geo_g1, geo_be1, sh16, g116);
  k_stageLN<256, 4><<<16, 256, 0, stream>>>(g116, Tgeo2, geo_b2, geo_g2, geo_be2,
      g216, nullptr, nullptr, nullptr);
  dim3 qkvg(16, 4, 3);
  k_qkv<<<qkvg, 64, 0, stream>>>(sh16, g216, Tq, Tk, Tv, ca_bq, ca_bk, ca_bv,
                                 qb16, kb16, vb16);
  k_attn<<<SS, 1024, 0, stream>>>(qb16, kb16, vb16, pv16);
  dim3 wog(16, 4);
  k_wo<<<wog, 64, 0, stream>>>(pv16, To, ca_bo, gvec, hqin16);
  k_stageLN<512, 4><<<16, 256, 0, stream>>>(hqin16, Tq1, q_b1, q_g1, q_be1,
      hq116, nullptr, nullptr, nullptr);
  k_stageLN<256, 2><<<16, 128, 0, stream>>>(hq116, Tq2, q_b2, q_g2, q_be2,
      nullptr, q_W3, q_b3, out_q);
  k_done<<<1, 256, 0, stream>>>(gvec, d_W1, d_b1, d_g1, d_be1, d_W2, d_b2, out_d);
}

// Round 9
// 309.401 us; speedup vs baseline: 1.3284x; 1.0451x over previous
//
#include <hip/hip_runtime.h>
#include <hip/hip_bf16.h>
#include <stdint.h>

#define NN 30000
#define MPAD 30080
#define FI 16
#define EE 300000
#define ETOT (EE + NN)
#define HD 256
#define NH 8
#define CH 32
#define NL 3
#define SS 256
#define KS 128
#define NHC 4
#define HC 64
#define GSB 256
#define RPB 118
#define SCB 118

typedef _Float16 half8 __attribute__((ext_vector_type(8)));
typedef _Float16 half4v __attribute__((ext_vector_type(4)));
typedef _Float16 half2v __attribute__((ext_vector_type(2)));
typedef float f32x4 __attribute__((ext_vector_type(4)));

// ---------------- wave helpers ----------------
__device__ __forceinline__ float wsum(float v) {
#pragma unroll
  for (int d = 1; d < 64; d <<= 1) v += __shfl_xor(v, d);
  return v;
}

__device__ __forceinline__ half2v mk2(_Float16 a, _Float16 b) {
  half2v r; r[0] = a; r[1] = b; return r;
}

__device__ __forceinline__ half2v h2max(half2v a, half2v b) {
#if __has_builtin(__builtin_elementwise_max)
  return __builtin_elementwise_max(a, b);
#else
  half2v r; r[0] = a[0] > b[0] ? a[0] : b[0]; r[1] = a[1] > b[1] ? a[1] : b[1];
  return r;
#endif
}

__device__ __forceinline__ float h2dot(half2v a, half2v b, float c) {
#if __has_builtin(__builtin_amdgcn_fdot2)
  return __builtin_amdgcn_fdot2(a, b, c, false);
#else
  return c + (float)a[0] * (float)b[0] + (float)a[1] * (float)b[1];
#endif
}

// LN over n channels, 256 threads, t<n holds a. 2 barriers.
__device__ __forceinline__ float ln_fast(float a, int t, int n, float* red16,
    const float* __restrict__ G, const float* __restrict__ Be, bool relu)
{
  float av = (t < n) ? a : 0.f;
  float s = wsum(av), s2 = wsum(av * av);
  if ((t & 63) == 0) { red16[t >> 6] = s; red16[8 + (t >> 6)] = s2; }
  __syncthreads();
  float sum = red16[0] + red16[1] + red16[2] + red16[3];
  float sq  = red16[8] + red16[9] + red16[10] + red16[11];
  float mu = sum / n;
  float var = sq / n - mu * mu;
  float o = 0.f;
  if (t < n) {
    o = (a - mu) * rsqrtf(var + 1e-5f) * G[t] + Be[t];
    if (relu) o = fmaxf(o, 0.f);
  }
  __syncthreads();
  return o;
}

// ---------------- init ----------------
__global__ __launch_bounds__(256) void k_init(int* __restrict__ cnt,
    int* __restrict__ gcnt, _Float16* __restrict__ h16pad, int* __restrict__ csr_pad)
{
  int i = blockIdx.x * 256 + threadIdx.x;
  if (i < NN) cnt[i] = 0;
  if (i == 0) gcnt[0] = 0;
  if (i < 8) csr_pad[i] = 0;
  if (i < (MPAD - NN) * HD) h16pad[i] = (_Float16)0.f;
}

// ---------------- all weight transpose+convert (GAT + tail) ----------------
__global__ __launch_bounds__(256) void k_wconvAll(
    const float* __restrict__ Wl, const float* __restrict__ Wr,
    const float* __restrict__ geo_W2, const float* __restrict__ ca_Wq,
    const float* __restrict__ ca_Wk, const float* __restrict__ ca_Wv,
    const float* __restrict__ ca_Wo, const float* __restrict__ q_W1,
    const float* __restrict__ q_W2,
    _Float16* __restrict__ WT,
    _Float16* __restrict__ Tgeo2, _Float16* __restrict__ Tq,
    _Float16* __restrict__ Tk, _Float16* __restrict__ Tv,
    _Float16* __restrict__ To, _Float16* __restrict__ Tq1,
    _Float16* __restrict__ Tq2)
{
  int b = blockIdx.x, t = threadIdx.x;
  if (b < 1536) {
    int m = b >> 8;
    int n = b & 255;
    int l = m >> 1;
    const float* W = (m & 1) ? (Wr + (size_t)l * HD * HD) : (Wl + (size_t)l * HD * HD);
    WT[((size_t)m * HD + n) * HD + t] = (_Float16)W[t * HD + n];
    return;
  }
  b -= 1536;
  if (b < 1280) {
    int seg = b >> 8;
    int n = b & 255;
    const float* src = (seg == 0) ? geo_W2 : (seg == 1) ? ca_Wq : (seg == 2) ? ca_Wk
                     : (seg == 3) ? ca_Wv : ca_Wo;
    _Float16* dst = (seg == 0) ? Tgeo2 : (seg == 1) ? Tq : (seg == 2) ? Tk
                  : (seg == 3) ? Tv : To;
    dst[(size_t)n * 256 + t] = (_Float16)src[(size_t)t * 256 + n];
  } else if (b < 1536) {
    int n = b - 1280;
    Tq1[(size_t)n * 512 + t]       = (_Float16)q_W1[(size_t)t * 256 + n];
    Tq1[(size_t)n * 512 + 256 + t] = (_Float16)q_W1[(size_t)(256 + t) * 256 + n];
  } else {
    int n = b - 1536;
    Tq2[(size_t)n * 256 + t] = (_Float16)q_W2[(size_t)t * 128 + n];
  }
}

// ---------------- pre-transform ----------------
__global__ __launch_bounds__(256) void k_pre(const float* __restrict__ x,
    const float* __restrict__ W, const float* __restrict__ b,
    _Float16* __restrict__ H16)
{
  __shared__ float Ws[FI][HD];
  __shared__ float xs[8][FI];
  int r0 = blockIdx.x * 8;
  int t = threadIdx.x;
  for (int i = t; i < FI * HD; i += 256) Ws[i >> 8][i & 255] = W[i];
  if (t < 8 * FI) xs[t >> 4][t & 15] = x[(size_t)(r0 + (t >> 4)) * FI + (t & 15)];
  __syncthreads();
  float bj = b[t];
  for (int r = 0; r < 8; ++r) {
    float acc = bj;
#pragma unroll
    for (int k = 0; k < FI; ++k) acc += xs[r][k] * Ws[k][t];
    H16[(size_t)(r0 + r) * HD + t] = (_Float16)acc;
  }
}

// ---------------- CSR build ----------------
__global__ __launch_bounds__(256) void k_count(const int* __restrict__ ei, int* __restrict__ cnt)
{
  int i = blockIdx.x * 256 + threadIdx.x;
  if (i >= ETOT) return;
  int dst = (i < EE) ? ei[EE + i] : (i - EE);
  atomicAdd(&cnt[dst], 1);
}

__global__ __launch_bounds__(256) void k_scanA(const int* __restrict__ cnt,
    int* __restrict__ rowptr, int* __restrict__ btot)
{
  __shared__ int wt[4];
  int b = blockIdx.x, t = threadIdx.x;
  int i = b * 256 + t;
  int v = (i < NN) ? cnt[i] : 0;
  int lane = t & 63, w = t >> 6;
  int s = v;
#pragma unroll
  for (int d = 1; d < 64; d <<= 1) {
    int u = __shfl_up(s, d);
    if (lane >= d) s += u;
  }
  if (lane == 63) wt[w] = s;
  __syncthreads();
  int off = 0;
  for (int k = 0; k < w; ++k) off += wt[k];
  if (i < NN) rowptr[i] = off + s - v;
  if (t == 255) btot[b] = off + s;
}

__global__ __launch_bounds__(128) void k_scanB(const int* __restrict__ btot,
    int* __restrict__ boff, int* __restrict__ rowptr)
{
  __shared__ int wt[2];
  int t = threadIdx.x;
  int v = (t < SCB) ? btot[t] : 0;
  int lane = t & 63, w = t >> 6;
  int s = v;
#pragma unroll
  for (int d = 1; d < 64; d <<= 1) {
    int u = __shfl_up(s, d);
    if (lane >= d) s += u;
  }
  if (lane == 63) wt[w] = s;
  __syncthreads();
  int off = (w == 1) ? wt[0] : 0;
  if (t < SCB) boff[t] = off + s - v;
  if (t == 127) rowptr[NN] = wt[0] + wt[1];
}

__global__ __launch_bounds__(256) void k_scanC(int* __restrict__ rowptr,
    const int* __restrict__ boff, int* __restrict__ wptr)
{
  int b = blockIdx.x, t = threadIdx.x;
  int i = b * 256 + t;
  if (i < NN) {
    int r = rowptr[i] + boff[b];
    rowptr[i] = r;
    wptr[i] = r;
  }
}

__global__ __launch_bounds__(256) void k_scatter(const int* __restrict__ ei,
    int* __restrict__ wptr, int* __restrict__ csr_src)
{
  int i = blockIdx.x * 256 + threadIdx.x;
  if (i >= ETOT) return;
  int src = (i < EE) ? ei[i] : (i - EE);
  int dst = (i < EE) ? ei[EE + i] : (i - EE);
  int pos = atomicAdd(&wptr[dst], 1);
  csr_src[pos] = src;
}

// ---------------- fp16 MFMA GEMM (GAT layers) ----------------
#define BK 64
__global__ __launch_bounds__(256) void k_gemm16(const _Float16* __restrict__ A,
    const _Float16* __restrict__ WT,
    _Float16* __restrict__ Xl, _Float16* __restrict__ Xr)
{
  __shared__ __align__(16) _Float16 As[128 * BK];
  __shared__ __align__(16) _Float16 Bs[128 * BK];
  int t = threadIdx.x;
  int w = t >> 6, lane = t & 63;
  int row0 = blockIdx.x * 128;
  int ct = blockIdx.y;
  const _Float16* Bmat = WT + (size_t)(ct >> 1) * HD * HD + (size_t)(ct & 1) * 128 * HD;
  _Float16* Out = (ct >> 1) ? Xr : Xl;
  int j0 = (ct & 1) * 128;

  f32x4 acc[4][4] = {};
  int wr = w >> 1, wc = w & 1;

  for (int k0 = 0; k0 < HD; k0 += BK) {
#pragma unroll
    for (int i = 0; i < 4; ++i) {
      int p = (i * 4 + w) * 64 + lane;
      int row = p >> 3, s = p & 7;
      int g = s ^ (row & 7);
      const _Float16* srcA = A + (size_t)(row0 + row) * HD + k0 + g * 8;
      __builtin_amdgcn_global_load_lds(
        (const __attribute__((address_space(1))) void*)srcA,
        (__attribute__((address_space(3))) void*)((char*)As + (i * 4 + w) * 1024),
        16, 0, 0);
      const _Float16* srcB = Bmat + (size_t)row * HD + k0 + g * 8;
      __builtin_amdgcn_global_load_lds(
        (const __attribute__((address_space(1))) void*)srcB,
        (__attribute__((address_space(3))) void*)((char*)Bs + (i * 4 + w) * 1024),
        16, 0, 0);
    }
    __syncthreads();
#pragma unroll
    for (int ks = 0; ks < 2; ++ks) {
      half8 af[4], bfr[4];
      int kslot = ks * 4 + (lane >> 4);
#pragma unroll
      for (int mi = 0; mi < 4; ++mi) {
        int rl = wr * 64 + mi * 16 + (lane & 15);
        int ps = kslot ^ (rl & 7);
        af[mi] = *(const half8*)((const char*)As + rl * 128 + ps * 16);
      }
#pragma unroll
      for (int ni = 0; ni < 4; ++ni) {
        int nl = wc * 64 + ni * 16 + (lane & 15);
        int ps = kslot ^ (nl & 7);
        bfr[ni] = *(const half8*)((const char*)Bs + nl * 128 + ps * 16);
      }
#pragma unroll
      for (int mi = 0; mi < 4; ++mi)
#pragma unroll
        for (int ni = 0; ni < 4; ++ni)
          acc[mi][ni] = __builtin_amdgcn_mfma_f32_16x16x32_f16(af[mi], bfr[ni], acc[mi][ni], 0, 0, 0);
    }
    __syncthreads();
  }
  int crow = (lane >> 4) * 4;
  int ccol = lane & 15;
#pragma unroll
  for (int mi = 0; mi < 4; ++mi)
#pragma unroll
    for (int ni = 0; ni < 4; ++ni) {
      size_t base_r = row0 + wr * 64 + mi * 16 + crow;
      int c = j0 + wc * 64 + ni * 16 + ccol;
#pragma unroll
      for (int r = 0; r < 4; ++r)
        Out[(base_r + r) * HD + c] = (_Float16)acc[mi][ni][r];
    }
}

// ---------------- fused edge + online-softmax agg ----------------
// one wave per node; lanes 0-31 / 32-63 process interleaved edge streams with
// independent online softmax, merged exactly at the end. 8 ch/lane (16B loads).
__global__ __launch_bounds__(256) void k_edgeagg(const _Float16* __restrict__ Xl,
    const _Float16* __restrict__ Xr, const float* __restrict__ attw,
    const float* __restrict__ bias, const int* __restrict__ rowptr,
    const int* __restrict__ csr_src, _Float16* __restrict__ H16)
{
  int node = blockIdx.x * 4 + (threadIdx.x >> 6);
  int lane = threadIdx.x & 63;
  if (node >= NN) return;
  int st = rowptr[node], en = rowptr[node + 1];
  int n = en - st;
  int hf = lane >> 5, sl = lane & 31;
  int c = sl * 8;
  half8 xrv = *(const half8*)(Xr + (size_t)node * HD + c);
  float4 wa = *(const float4*)(attw + c);
  float4 wb = *(const float4*)(attw + c + 4);
  half2v w0 = mk2((_Float16)wa.x, (_Float16)wa.y);
  half2v w1 = mk2((_Float16)wa.z, (_Float16)wa.w);
  half2v w2 = mk2((_Float16)wb.x, (_Float16)wb.y);
  half2v w3 = mk2((_Float16)wb.z, (_Float16)wb.w);
  half2v r0 = mk2(xrv[0], xrv[1]), r1 = mk2(xrv[2], xrv[3]);
  half2v r2 = mk2(xrv[4], xrv[5]), r3 = mk2(xrv[6], xrv[7]);
  half2v c02 = mk2((_Float16)0.2f, (_Float16)0.2f);

  float mh = -1e30f, dsum = 0.f;
  float a[8] = {};
  int trips = (n + 1) >> 1;

  int idx0 = csr_src[st + hf];            // padded-safe
  half8 xv = *(const half8*)(Xl + (size_t)idx0 * HD + c);

  for (int it = 0; it < trips; ++it) {
    bool valid = (2 * it + hf) < n;
    half8 xc = xv;
    if (it + 1 < trips) {
      int nidx = csr_src[st + 2 * (it + 1) + hf];   // padded-safe
      xv = *(const half8*)(Xl + (size_t)nidx * HD + c);
    }
    half2v x0 = mk2(xc[0], xc[1]), x1 = mk2(xc[2], xc[3]);
    half2v x2 = mk2(xc[4], xc[5]), x3 = mk2(xc[6], xc[7]);
    half2v s0 = x0 + r0, s1 = x1 + r1, s2 = x2 + r2, s3 = x3 + r3;
    half2v m0 = h2max(s0, s0 * c02);
    half2v m1 = h2max(s1, s1 * c02);
    half2v m2 = h2max(s2, s2 * c02);
    half2v m3 = h2max(s3, s3 * c02);
    float e = h2dot(m3, w3, h2dot(m2, w2, h2dot(m1, w1, h2dot(m0, w0, 0.f))));
    e += __shfl_xor(e, 1);
    e += __shfl_xor(e, 2);
    e = valid ? e : -1e30f;
    if (__any(e > mh + 8.f)) {
      float nm = fmaxf(mh, e);
      float sc = __expf(mh - nm);
      dsum *= sc;
#pragma unroll
      for (int j = 0; j < 8; ++j) a[j] *= sc;
      mh = nm;
    }
    float pw = valid ? __expf(e - mh) : 0.f;
#pragma unroll
    for (int j = 0; j < 8; ++j) a[j] += pw * (float)xc[j];
    dsum += pw;
  }
  // merge the two halves' online softmaxes (exact)
  float om = __shfl_xor(mh, 32);
  float od = __shfl_xor(dsum, 32);
  float nm = fmaxf(mh, om);
  float scs = __expf(mh - nm);
  float sco = __expf(om - nm);
  float d = dsum * scs + od * sco;
#pragma unroll
  for (int j = 0; j < 8; ++j) {
    float oa = __shfl_xor(a[j], 32);
    a[j] = a[j] * scs + oa * sco;
  }
  if (hf == 0) {
    float inv = 1.f / (d + 1e-16f);
    float4 ba = *(const float4*)(bias + c);
    float4 bb = *(const float4*)(bias + c + 4);
    float ob[8] = {ba.x, ba.y, ba.z, ba.w, bb.x, bb.y, bb.z, bb.w};
    half8 h8;
#pragma unroll
    for (int j = 0; j < 8; ++j) {
      float o = a[j] * inv + ob[j];
      o = (o > 0.f) ? o : expm1f(o);
      h8[j] = (_Float16)o;
    }
    *(half8*)(H16 + (size_t)node * HD + c) = h8;
  }
}

// ---------------- global sum: per-block partials ----------------
__global__ __launch_bounds__(256) void k_gsum(const _Float16* __restrict__ H,
    const int* __restrict__ batch, float* __restrict__ gpart, int* __restrict__ gcnt)
{
  __shared__ float flagf[RPB];
  __shared__ int scount;
  int b = blockIdx.x, t = threadIdx.x;
  int r0 = b * RPB;
  int nr = NN - r0; if (nr > RPB) nr = RPB; if (nr < 0) nr = 0;
  if (t == 0) scount = 0;
  __syncthreads();
  if (t < nr) {
    int ok = (batch[r0 + t] == 0) ? 1 : 0;
    flagf[t] = (float)ok;
    if (ok) atomicAdd(&scount, 1);
  }
  __syncthreads();
  float a0 = 0.f, a1 = 0.f, a2 = 0.f, a3 = 0.f;
  const _Float16* Hp = H + (size_t)r0 * HD + t;
  int r = 0;
  for (; r + 4 <= nr; r += 4) {
    float v0 = (float)Hp[(size_t)(r + 0) * HD];
    float v1 = (float)Hp[(size_t)(r + 1) * HD];
    float v2 = (float)Hp[(size_t)(r + 2) * HD];
    float v3 = (float)Hp[(size_t)(r + 3) * HD];
    a0 += v0 * flagf[r + 0]; a1 += v1 * flagf[r + 1];
    a2 += v2 * flagf[r + 2]; a3 += v3 * flagf[r + 3];
  }
  for (; r < nr; ++r) a0 += (float)Hp[(size_t)r * HD] * flagf[r];
  gpart[(size_t)b * HD + t] = (a0 + a1) + (a2 + a3);
  if (t == 0 && scount) atomicAdd(gcnt, scount);
}

// ---------------- tail head: sheet pool + geo1 (+gfin at blk SS) ----------------
__global__ __launch_bounds__(256) void k_tail1(const _Float16* __restrict__ h16,
    const int* __restrict__ sheet_idx, const float* __restrict__ sheet_feat,
    const float* __restrict__ geo_W1, const float* __restrict__ geo_b1,
    const float* __restrict__ geo_g1, const float* __restrict__ geo_be1,
    const float* __restrict__ gpart, const int* __restrict__ gcnt,
    float* __restrict__ gvec,
    _Float16* __restrict__ sh16, _Float16* __restrict__ g116)
{
  __shared__ float xf[FI];
  __shared__ int sidx[KS];
  __shared__ float red16[16];
  int s = blockIdx.x, t = threadIdx.x;

  if (s == SS) {
    float a0 = 0.f, a1 = 0.f, a2 = 0.f, a3 = 0.f;
    for (int b = 0; b < GSB; b += 4) {
      a0 += gpart[(size_t)b * HD + t];
      a1 += gpart[(size_t)(b + 1) * HD + t];
      a2 += gpart[(size_t)(b + 2) * HD + t];
      a3 += gpart[(size_t)(b + 3) * HD + t];
    }
    gvec[t] = ((a0 + a1) + (a2 + a3)) / (float)(*gcnt);
    return;
  }

  if (t < KS) sidx[t] = sheet_idx[s * KS + t];
  if (t >= 240) xf[t - 240] = sheet_feat[s * FI + (t - 240)];
  __syncthreads();

  float pa[8] = {};
#pragma unroll 2
  for (int r = 0; r < KS; r += 8) {
#pragma unroll
    for (int u = 0; u < 8; ++u)
      pa[u] += (float)h16[(size_t)sidx[r + u] * HD + t];
  }
  float shv = ((pa[0] + pa[1]) + (pa[2] + pa[3]) + (pa[4] + pa[5]) + (pa[6] + pa[7])) * (1.f / KS);
  sh16[(size_t)s * HD + t] = (_Float16)shv;

  float a = geo_b1[t];
#pragma unroll
  for (int k = 0; k < FI; ++k) a += xf[k] * geo_W1[k * HD + t];
  float g1 = ln_fast(a, t, 256, red16, geo_g1, geo_be1, true);
  g116[(size_t)s * HD + t] = (_Float16)g1;
}

// ---------------- MFMA tail stage with LN (NW waves, 16 rows/block) ----------------
// optional qval fold (W3/b3/outq) and done-head (block 16) when outd != nullptr
template <int KD, int NW>
__global__ __launch_bounds__(NW * 64) void k_stageLN(
    const _Float16* __restrict__ X, const _Float16* __restrict__ WT,
    const float* __restrict__ b, const float* __restrict__ G,
    const float* __restrict__ Be, _Float16* __restrict__ Y,
    const float* __restrict__ W3, const float* __restrict__ b3,
    float* __restrict__ outq,
    const float* __restrict__ gvec,
    const float* __restrict__ dW1, const float* __restrict__ db1,
    const float* __restrict__ dg1, const float* __restrict__ dbe1,
    const float* __restrict__ dW2, const float* __restrict__ db2,
    float* __restrict__ outd)
{
  __shared__ float ps[NW * 16], ps2[NW * 16], pq[NW * 16];
  const int NCOL = NW * 64;
  int t = threadIdx.x;

  if (outd != nullptr && blockIdx.x == 16) {
    // ---- done head (128 threads assumed: NW==2) ----
    int w2 = t >> 6;
    float acc2 = db1[t];
    for (int k = 0; k < 256; ++k) acc2 += gvec[k] * dW1[(size_t)k * 128 + t];
    float s = wsum(acc2), s2v = wsum(acc2 * acc2);
    if ((t & 63) == 0) { ps[w2] = s; ps2[w2] = s2v; }
    __syncthreads();
    float S = ps[0] + ps[1], S2 = ps2[0] + ps2[1];
    float mu = S * (1.f / 128.f), var = S2 * (1.f / 128.f) - mu * mu;
    float hdv = fmaxf((acc2 - mu) * rsqrtf(var + 1e-5f) * dg1[t] + dbe1[t], 0.f);
    float o = wsum(hdv * dW2[t]);
    if ((t & 63) == 0) pq[w2] = o;
    __syncthreads();
    if (t == 0) outd[0] = pq[0] + pq[1] + db2[0];
    return;
  }

  int w = t >> 6, lane = t & 63;
  int arow = lane & 15, kg = lane >> 4;
  int m0 = blockIdx.x * 16;
  int col0 = w * 64;

  f32x4 acc[4] = {};
#pragma unroll
  for (int ks = 0; ks < KD / 32; ++ks) {
    half8 af = *(const half8*)(X + (size_t)(m0 + arow) * KD + ks * 32 + kg * 8);
#pragma unroll
    for (int n = 0; n < 4; ++n) {
      half8 bf = *(const half8*)(WT + (size_t)(col0 + n * 16 + arow) * KD + ks * 32 + kg * 8);
      acc[n] = __builtin_amdgcn_mfma_f32_16x16x32_f16(af, bf, acc[n], 0, 0, 0);
    }
  }
#pragma unroll
  for (int n = 0; n < 4; ++n) {
    float bv = b[col0 + n * 16 + arow];
#pragma unroll
    for (int r = 0; r < 4; ++r) acc[n][r] += bv;
  }
  float s[4] = {}, s2[4] = {};
#pragma unroll
  for (int n = 0; n < 4; ++n)
#pragma unroll
    for (int r = 0; r < 4; ++r) { float v = acc[n][r]; s[r] += v; s2[r] += v * v; }
#pragma unroll
  for (int d = 1; d < 16; d <<= 1)
#pragma unroll
    for (int r = 0; r < 4; ++r) { s[r] += __shfl_xor(s[r], d); s2[r] += __shfl_xor(s2[r], d); }
  if (arow == 0) {
#pragma unroll
    for (int r = 0; r < 4; ++r) {
      ps[w * 16 + kg * 4 + r] = s[r];
      ps2[w * 16 + kg * 4 + r] = s2[r];
    }
  }
  __syncthreads();
  float mu[4], rs[4];
#pragma unroll
  for (int r = 0; r < 4; ++r) {
    float S = 0.f, S2 = 0.f;
#pragma unroll
    for (int w2 = 0; w2 < NW; ++w2) { S += ps[w2 * 16 + kg * 4 + r]; S2 += ps2[w2 * 16 + kg * 4 + r]; }
    float m = S / NCOL;
    float var = S2 / NCOL - m * m;
    mu[r] = m; rs[r] = rsqrtf(var + 1e-5f);
  }
#pragma unroll
  for (int n = 0; n < 4; ++n) {
    int col = col0 + n * 16 + arow;
    float gv = G[col], bev = Be[col];
#pragma unroll
    for (int r = 0; r < 4; ++r)
      acc[n][r] = fmaxf((acc[n][r] - mu[r]) * rs[r] * gv + bev, 0.f);
  }
  if (Y) {
#pragma unroll
    for (int n = 0; n < 4; ++n) {
      int col = col0 + n * 16 + arow;
#pragma unroll
      for (int r = 0; r < 4; ++r)
        Y[(size_t)(m0 + kg * 4 + r) * NCOL + col] = (_Float16)acc[n][r];
    }
  }
  if (outq) {
    float p[4] = {};
#pragma unroll
    for (int n = 0; n < 4; ++n) {
      float w3 = W3[col0 + n * 16 + arow];
#pragma unroll
      for (int r = 0; r < 4; ++r) p[r] += acc[n][r] * w3;
    }
#pragma unroll
    for (int d = 1; d < 16; d <<= 1)
#pragma unroll
      for (int r = 0; r < 4; ++r) p[r] += __shfl_xor(p[r], d);
    if (arow == 0)
#pragma unroll
      for (int r = 0; r < 4; ++r) pq[w * 16 + kg * 4 + r] = p[r];
    __syncthreads();
    if (w == 0 && arow == 0) {
#pragma unroll
      for (int r = 0; r < 4; ++r) {
        float o = b3[0];
#pragma unroll
        for (int w2 = 0; w2 < NW; ++w2) o += pq[w2 * 16 + kg * 4 + r];
        outq[m0 + kg * 4 + r] = o;
      }
    }
  }
}

// ---------------- q/k/v stage (no LN): grid (16, 4, 3) ----------------
__global__ __launch_bounds__(64) void k_qkv(
    const _Float16* __restrict__ sh16, const _Float16* __restrict__ g216,
    const _Float16* __restrict__ Tq, const _Float16* __restrict__ Tk,
    const _Float16* __restrict__ Tv,
    const float* __restrict__ bq, const float* __restrict__ bk,
    const float* __restrict__ bv,
    _Float16* __restrict__ qb, _Float16* __restrict__ kb, _Float16* __restrict__ vb)
{
  int lane = threadIdx.x;
  int arow = lane & 15, kg = lane >> 4;
  int m0 = blockIdx.x * 16;
  int col0 = blockIdx.y * 64;
  int mat = blockIdx.z;
  const _Float16* X = (mat == 0) ? sh16 : g216;
  const _Float16* WT = (mat == 0) ? Tq : (mat == 1) ? Tk : Tv;
  const float* b = (mat == 0) ? bq : (mat == 1) ? bk : bv;
  _Float16* Y = (mat == 0) ? qb : (mat == 1) ? kb : vb;

  f32x4 acc[4] = {};
#pragma unroll
  for (int ks = 0; ks < 8; ++ks) {
    half8 af = *(const half8*)(X + (size_t)(m0 + arow) * 256 + ks * 32 + kg * 8);
#pragma unroll
    for (int n = 0; n < 4; ++n) {
      half8 bf = *(const half8*)(WT + (size_t)(col0 + n * 16 + arow) * 256 + ks * 32 + kg * 8);
      acc[n] = __builtin_amdgcn_mfma_f32_16x16x32_f16(af, bf, acc[n], 0, 0, 0);
    }
  }
#pragma unroll
  for (int n = 0; n < 4; ++n) {
    int col = col0 + n * 16 + arow;
    float bv2 = b[col];
#pragma unroll
    for (int r = 0; r < 4; ++r)
      Y[(size_t)(m0 + kg * 4 + r) * 256 + col] = (_Float16)(acc[n][r] + bv2);
  }
}

// ---------------- Wo stage + gv concat: grid (16, 4) ----------------
__global__ __launch_bounds__(64) void k_wo(
    const _Float16* __restrict__ pv16, const _Float16* __restrict__ To,
    const float* __restrict__ bo, const float* __restrict__ gvec,
    _Float16* __restrict__ hqin)
{
  int lane = threadIdx.x;
  int arow = lane & 15, kg = lane >> 4;
  int m0 = blockIdx.x * 16;
  int col0 = blockIdx.y * 64;

  f32x4 acc[4] = {};
#pragma unroll
  for (int ks = 0; ks < 8; ++ks) {
    half8 af = *(const half8*)(pv16 + (size_t)(m0 + arow) * 256 + ks * 32 + kg * 8);
#pragma unroll
    for (int n = 0; n < 4; ++n) {
      half8 bf = *(const half8*)(To + (size_t)(col0 + n * 16 + arow) * 256 + ks * 32 + kg * 8);
      acc[n] = __builtin_amdgcn_mfma_f32_16x16x32_f16(af, bf, acc[n], 0, 0, 0);
    }
  }
#pragma unroll
  for (int n = 0; n < 4; ++n) {
    int col = col0 + n * 16 + arow;
    float bv = bo[col];
    _Float16 gg = (_Float16)gvec[col];
#pragma unroll
    for (int r = 0; r < 4; ++r) {
      hqin[(size_t)(m0 + kg * 4 + r) * 512 + col] = (_Float16)(acc[n][r] + bv);
      hqin[(size_t)(m0 + kg * 4 + r) * 512 + 256 + col] = gg;
    }
  }
}

// ---------------- cross-attention per query row (1024 thr) ----------------
__global__ __launch_bounds__(1024) void k_attn(const _Float16* __restrict__ qb,
    const _Float16* __restrict__ kb, const _Float16* __restrict__ vb,
    _Float16* __restrict__ pv16)
{
  __shared__ float qv[HD];
  __shared__ float att[1024];
  __shared__ float red4[1024];
  __shared__ float redm[16];
  __shared__ float reds[16];
  int row = blockIdx.x, t = threadIdx.x;
  int w = t >> 6;

  if (t < 256) qv[t] = (float)qb[(size_t)row * HD + t];
  __syncthreads();

  int h = t >> 8, key = t & 255;
  float e = 0.f;
  {
    const half8* kr = (const half8*)(kb + (size_t)key * HD + h * HC);
    const float* qh = qv + h * HC;
#pragma unroll
    for (int d = 0; d < 8; ++d) {
      half8 kk = kr[d];
#pragma unroll
      for (int u = 0; u < 8; ++u) e += qh[d * 8 + u] * (float)kk[u];
    }
    e *= 0.125f;
  }
  float wm = e;
#pragma unroll
  for (int d = 1; d < 64; d <<= 1) wm = fmaxf(wm, __shfl_xor(wm, d));
  if ((t & 63) == 0) redm[w] = wm;
  __syncthreads();
  float mx = fmaxf(fmaxf(redm[4 * h], redm[4 * h + 1]), fmaxf(redm[4 * h + 2], redm[4 * h + 3]));
  float pw = __expf(e - mx);
  float ws = wsum(pw);
  if ((t & 63) == 0) reds[w] = ws;
  att[t] = pw;
  __syncthreads();

  int kq = t >> 8, j = t & 255;
  int hj = j >> 6;
  float p = 0.f;
  const float* arow = att + hj * 256 + kq * 64;
  const _Float16* vcol = vb + (size_t)(kq * 64) * HD + j;
  for (int k = 0; k < 64; ++k)
    p += arow[k] * (float)vcol[(size_t)k * HD];
  red4[t] = p;
  __syncthreads();
  if (t < 256) {
    int hh = t >> 6;
    float dsum = reds[4 * hh] + reds[4 * hh + 1] + reds[4 * hh + 2] + reds[4 * hh + 3];
    float pv = (red4[t] + red4[256 + t] + red4[512 + t] + red4[768 + t]) / dsum;
    pv16[(size_t)row * HD + t] = (_Float16)pv;
  }
}

// =====================================================================
extern "C" void kernel_launch(void* const* d_in, const int* in_sizes, int n_in,
                              void* d_out, int out_size, void* d_ws, size_t ws_size,
                              hipStream_t stream) {
  const float* x      = (const float*)d_in[0];
  const int*   ei     = (const int*)d_in[1];
  const int*   batch  = (const int*)d_in[2];
  const int*   sheet_idx = (const int*)d_in[3];
  const float* sheet_feat = (const float*)d_in[4];
  const float* pre_W  = (const float*)d_in[5];
  const float* pre_b  = (const float*)d_in[6];
  const float* gat_Wl = (const float*)d_in[7];
  const float* gat_Wr = (const float*)d_in[8];
  const float* gat_att = (const float*)d_in[9];
  const float* gat_b  = (const float*)d_in[10];
  const float* geo_W1 = (const float*)d_in[11];
  const float* geo_b1 = (const float*)d_in[12];
  const float* geo_g1 = (const float*)d_in[13];
  const float* geo_be1 = (const float*)d_in[14];
  const float* geo_W2 = (const float*)d_in[15];
  const float* geo_b2 = (const float*)d_in[16];
  const float* geo_g2 = (const float*)d_in[17];
  const float* geo_be2 = (const float*)d_in[18];
  const float* ca_Wq = (const float*)d_in[19];
  const float* ca_bq = (const float*)d_in[20];
  const float* ca_Wk = (const float*)d_in[21];
  const float* ca_bk = (const float*)d_in[22];
  const float* ca_Wv = (const float*)d_in[23];
  const float* ca_bv = (const float*)d_in[24];
  const float* ca_Wo = (const float*)d_in[25];
  const float* ca_bo = (const float*)d_in[26];
  const float* q_W1 = (const float*)d_in[27];
  const float* q_b1 = (const float*)d_in[28];
  const float* q_g1 = (const float*)d_in[29];
  const float* q_be1 = (const float*)d_in[30];
  const float* q_W2 = (const float*)d_in[31];
  const float* q_b2 = (const float*)d_in[32];
  const float* q_g2 = (const float*)d_in[33];
  const float* q_be2 = (const float*)d_in[34];
  const float* q_W3 = (const float*)d_in[35];
  const float* q_b3 = (const float*)d_in[36];
  const float* d_W1 = (const float*)d_in[37];
  const float* d_b1 = (const float*)d_in[38];
  const float* d_g1 = (const float*)d_in[39];
  const float* d_be1 = (const float*)d_in[40];
  const float* d_W2 = (const float*)d_in[41];
  const float* d_b2 = (const float*)d_in[42];

  char* wsb = (char*)d_ws;
  auto alloc = [&](size_t bytes) { char* p = wsb; wsb += (bytes + 255) & ~(size_t)255; return p; };

  _Float16* h16  = (_Float16*)alloc((size_t)MPAD * HD * 2);
  _Float16* Xl16 = (_Float16*)alloc((size_t)MPAD * HD * 2);
  _Float16* Xr16 = (_Float16*)alloc((size_t)MPAD * HD * 2);
  _Float16* WT   = (_Float16*)alloc((size_t)6 * HD * HD * 2);
  _Float16* Tgeo2 = (_Float16*)alloc((size_t)HD * HD * 2);
  _Float16* Tq   = (_Float16*)alloc((size_t)HD * HD * 2);
  _Float16* Tk   = (_Float16*)alloc((size_t)HD * HD * 2);
  _Float16* Tv   = (_Float16*)alloc((size_t)HD * HD * 2);
  _Float16* To   = (_Float16*)alloc((size_t)HD * HD * 2);
  _Float16* Tq1  = (_Float16*)alloc((size_t)HD * 512 * 2);
  _Float16* Tq2  = (_Float16*)alloc((size_t)128 * HD * 2);
  _Float16* sh16 = (_Float16*)alloc((size_t)SS * HD * 2);
  _Float16* g116 = (_Float16*)alloc((size_t)SS * HD * 2);
  _Float16* g216 = (_Float16*)alloc((size_t)SS * HD * 2);
  _Float16* qb16 = (_Float16*)alloc((size_t)SS * HD * 2);
  _Float16* kb16 = (_Float16*)alloc((size_t)SS * HD * 2);
  _Float16* vb16 = (_Float16*)alloc((size_t)SS * HD * 2);
  _Float16* pv16 = (_Float16*)alloc((size_t)SS * HD * 2);
  _Float16* hqin16 = (_Float16*)alloc((size_t)SS * 512 * 2);
  _Float16* hq116 = (_Float16*)alloc((size_t)SS * HD * 2);
  float* gpart   = (float*)alloc((size_t)GSB * HD * 4);
  float* gvec    = (float*)alloc(256 * 4);
  int* cnt       = (int*)alloc((size_t)NN * 4);
  int* rowptr    = (int*)alloc((size_t)(NN + 1) * 4);
  int* wptr      = (int*)alloc((size_t)NN * 4);
  int* csr_src   = (int*)alloc((size_t)(ETOT + 8) * 4);
  int* btot      = (int*)alloc((size_t)SCB * 4);
  int* boff      = (int*)alloc((size_t)SCB * 4);
  int* gcnt      = (int*)alloc(4);

  float* out_q = (float*)d_out;        // [256]
  float* out_d = out_q + SS;           // [1]

  k_init<<<118, 256, 0, stream>>>(cnt, gcnt, h16 + (size_t)NN * HD, csr_src + ETOT);

  // CSR build
  k_count<<<(ETOT + 255) / 256, 256, 0, stream>>>(ei, cnt);
  k_scanA<<<SCB, 256, 0, stream>>>(cnt, rowptr, btot);
  k_scanB<<<1, 128, 0, stream>>>(btot, boff, rowptr);
  k_scanC<<<SCB, 256, 0, stream>>>(rowptr, boff, wptr);
  k_scatter<<<(ETOT + 255) / 256, 256, 0, stream>>>(ei, wptr, csr_src);

  // weights + pre-transform
  k_wconvAll<<<3200, 256, 0, stream>>>(gat_Wl, gat_Wr, geo_W2, ca_Wq, ca_Wk, ca_Wv,
                                       ca_Wo, q_W1, q_W2,
                                       WT, Tgeo2, Tq, Tk, Tv, To, Tq1, Tq2);
  k_pre<<<NN / 8, 256, 0, stream>>>(x, pre_W, pre_b, h16);

  // GAT layers
  dim3 ggrid(MPAD / 128, 4);
  for (int l = 0; l < NL; ++l) {
    k_gemm16<<<ggrid, 256, 0, stream>>>(h16, WT + (size_t)l * 2 * HD * HD, Xl16, Xr16);
    k_edgeagg<<<(NN + 3) / 4, 256, 0, stream>>>(Xl16, Xr16, gat_att + l * NH * CH,
                                                gat_b + l * HD, rowptr, csr_src, h16);
  }

  // global mean partials
  k_gsum<<<GSB, 256, 0, stream>>>(h16, batch, gpart, gcnt);

  // tail (+gfin folded into block SS)
  k_tail1<<<SS + 1, 256, 0, stream>>>(h16, sheet_idx, sheet_feat,
      geo_W1, geo_b1, geo_g1, geo_be1, gpart, gcnt, gvec, sh16, g116);
  k_stageLN<256, 4><<<16, 256, 0, stream>>>(g116, Tgeo2, geo_b2, geo_g2, geo_be2,
      g216, nullptr, nullptr, nullptr,
      nullptr, nullptr, nullptr, nullptr, nullptr, nullptr, nullptr, nullptr);
  dim3 qkvg(16, 4, 3);
  k_qkv<<<qkvg, 64, 0, stream>>>(sh16, g216, Tq, Tk, Tv, ca_bq, ca_bk, ca_bv,
                                 qb16, kb16, vb16);
  k_attn<<<SS, 1024, 0, stream>>>(qb16, kb16, vb16, pv16);
  dim3 wog(16, 4);
  k_wo<<<wog, 64, 0, stream>>>(pv16, To, ca_bo, gvec, hqin16);
  k_stageLN<512, 4><<<16, 256, 0, stream>>>(hqin16, Tq1, q_b1, q_g1, q_be1,
      hq116, nullptr, nullptr, nullptr,
      nullptr, nullptr, nullptr, nullptr, nullptr, nullptr, nullptr, nullptr);
  // hq2 + qval (blocks 0..15) + done head (block 16)
  k_stageLN<256, 2><<<17, 128, 0, stream>>>(hq116, Tq2, q_b2, q_g2, q_be2,
      nullptr, q_W3, q_b3, out_q,
      gvec, d_W1, d_b1, d_g1, d_be1, d_W2, d_b2, out_d);
}

// Round 10
// 305.638 us; speedup vs baseline: 1.3447x; 1.0123x over previous
//
#include <hip/hip_runtime.h>
#include <hip/hip_bf16.h>
#include <stdint.h>

#define NN 30000
#define MPAD 30080
#define FI 16
#define EE 300000
#define ETOT (EE + NN)
#define HD 256
#define NH 8
#define CH 32
#define NL 3
#define SS 256
#define KS 128
#define NHC 4
#define HC 64
#define GSB 256
#define RPB 118
#define SCB 118

typedef _Float16 half8 __attribute__((ext_vector_type(8)));
typedef _Float16 half4v __attribute__((ext_vector_type(4)));
typedef _Float16 half2v __attribute__((ext_vector_type(2)));
typedef float f32x4 __attribute__((ext_vector_type(4)));

// ---------------- wave helpers ----------------
__device__ __forceinline__ float wsum(float v) {
#pragma unroll
  for (int d = 1; d < 64; d <<= 1) v += __shfl_xor(v, d);
  return v;
}

__device__ __forceinline__ half2v mk2(_Float16 a, _Float16 b) {
  half2v r; r[0] = a; r[1] = b; return r;
}

__device__ __forceinline__ half2v h2max(half2v a, half2v b) {
#if __has_builtin(__builtin_elementwise_max)
  return __builtin_elementwise_max(a, b);
#else
  half2v r; r[0] = a[0] > b[0] ? a[0] : b[0]; r[1] = a[1] > b[1] ? a[1] : b[1];
  return r;
#endif
}

__device__ __forceinline__ float h2dot(half2v a, half2v b, float c) {
#if __has_builtin(__builtin_amdgcn_fdot2)
  return __builtin_amdgcn_fdot2(a, b, c, false);
#else
  return c + (float)a[0] * (float)b[0] + (float)a[1] * (float)b[1];
#endif
}

// LN over n channels, 256 threads, t<n holds a. 2 barriers.
__device__ __forceinline__ float ln_fast(float a, int t, int n, float* red16,
    const float* __restrict__ G, const float* __restrict__ Be, bool relu)
{
  float av = (t < n) ? a : 0.f;
  float s = wsum(av), s2 = wsum(av * av);
  if ((t & 63) == 0) { red16[t >> 6] = s; red16[8 + (t >> 6)] = s2; }
  __syncthreads();
  float sum = red16[0] + red16[1] + red16[2] + red16[3];
  float sq  = red16[8] + red16[9] + red16[10] + red16[11];
  float mu = sum / n;
  float var = sq / n - mu * mu;
  float o = 0.f;
  if (t < n) {
    o = (a - mu) * rsqrtf(var + 1e-5f) * G[t] + Be[t];
    if (relu) o = fmaxf(o, 0.f);
  }
  __syncthreads();
  return o;
}

// ---------------- init ----------------
__global__ __launch_bounds__(256) void k_init(int* __restrict__ cnt,
    int* __restrict__ gcnt, _Float16* __restrict__ h16pad, int* __restrict__ csr_pad)
{
  int i = blockIdx.x * 256 + threadIdx.x;
  if (i < NN) cnt[i] = 0;
  if (i == 0) gcnt[0] = 0;
  if (i < 8) csr_pad[i] = 0;
  if (i < (MPAD - NN) * HD) h16pad[i] = (_Float16)0.f;
}

// ---------------- all weight transpose+convert (GAT + tail) ----------------
__global__ __launch_bounds__(256) void k_wconvAll(
    const float* __restrict__ Wl, const float* __restrict__ Wr,
    const float* __restrict__ geo_W2, const float* __restrict__ ca_Wq,
    const float* __restrict__ ca_Wk, const float* __restrict__ ca_Wv,
    const float* __restrict__ ca_Wo, const float* __restrict__ q_W1,
    const float* __restrict__ q_W2,
    _Float16* __restrict__ WT,
    _Float16* __restrict__ Tgeo2, _Float16* __restrict__ Tq,
    _Float16* __restrict__ Tk, _Float16* __restrict__ Tv,
    _Float16* __restrict__ To, _Float16* __restrict__ Tq1,
    _Float16* __restrict__ Tq2)
{
  int b = blockIdx.x, t = threadIdx.x;
  if (b < 1536) {
    int m = b >> 8;
    int n = b & 255;
    int l = m >> 1;
    const float* W = (m & 1) ? (Wr + (size_t)l * HD * HD) : (Wl + (size_t)l * HD * HD);
    WT[((size_t)m * HD + n) * HD + t] = (_Float16)W[t * HD + n];
    return;
  }
  b -= 1536;
  if (b < 1280) {
    int seg = b >> 8;
    int n = b & 255;
    const float* src = (seg == 0) ? geo_W2 : (seg == 1) ? ca_Wq : (seg == 2) ? ca_Wk
                     : (seg == 3) ? ca_Wv : ca_Wo;
    _Float16* dst = (seg == 0) ? Tgeo2 : (seg == 1) ? Tq : (seg == 2) ? Tk
                  : (seg == 3) ? Tv : To;
    dst[(size_t)n * 256 + t] = (_Float16)src[(size_t)t * 256 + n];
  } else if (b < 1536) {
    int n = b - 1280;
    Tq1[(size_t)n * 512 + t]       = (_Float16)q_W1[(size_t)t * 256 + n];
    Tq1[(size_t)n * 512 + 256 + t] = (_Float16)q_W1[(size_t)(256 + t) * 256 + n];
  } else {
    int n = b - 1536;
    Tq2[(size_t)n * 256 + t] = (_Float16)q_W2[(size_t)t * 128 + n];
  }
}

// ---------------- pre-transform ----------------
__global__ __launch_bounds__(256) void k_pre(const float* __restrict__ x,
    const float* __restrict__ W, const float* __restrict__ b,
    _Float16* __restrict__ H16)
{
  __shared__ float Ws[FI][HD];
  __shared__ float xs[8][FI];
  int r0 = blockIdx.x * 8;
  int t = threadIdx.x;
  for (int i = t; i < FI * HD; i += 256) Ws[i >> 8][i & 255] = W[i];
  if (t < 8 * FI) xs[t >> 4][t & 15] = x[(size_t)(r0 + (t >> 4)) * FI + (t & 15)];
  __syncthreads();
  float bj = b[t];
  for (int r = 0; r < 8; ++r) {
    float acc = bj;
#pragma unroll
    for (int k = 0; k < FI; ++k) acc += xs[r][k] * Ws[k][t];
    H16[(size_t)(r0 + r) * HD + t] = (_Float16)acc;
  }
}

// ---------------- CSR build ----------------
__global__ __launch_bounds__(256) void k_count(const int* __restrict__ ei, int* __restrict__ cnt)
{
  int i = blockIdx.x * 256 + threadIdx.x;
  if (i >= ETOT) return;
  int dst = (i < EE) ? ei[EE + i] : (i - EE);
  atomicAdd(&cnt[dst], 1);
}

__global__ __launch_bounds__(256) void k_scanA(const int* __restrict__ cnt,
    int* __restrict__ rowptr, int* __restrict__ btot)
{
  __shared__ int wt[4];
  int b = blockIdx.x, t = threadIdx.x;
  int i = b * 256 + t;
  int v = (i < NN) ? cnt[i] : 0;
  int lane = t & 63, w = t >> 6;
  int s = v;
#pragma unroll
  for (int d = 1; d < 64; d <<= 1) {
    int u = __shfl_up(s, d);
    if (lane >= d) s += u;
  }
  if (lane == 63) wt[w] = s;
  __syncthreads();
  int off = 0;
  for (int k = 0; k < w; ++k) off += wt[k];
  if (i < NN) rowptr[i] = off + s - v;
  if (t == 255) btot[b] = off + s;
}

__global__ __launch_bounds__(128) void k_scanB(const int* __restrict__ btot,
    int* __restrict__ boff, int* __restrict__ rowptr)
{
  __shared__ int wt[2];
  int t = threadIdx.x;
  int v = (t < SCB) ? btot[t] : 0;
  int lane = t & 63, w = t >> 6;
  int s = v;
#pragma unroll
  for (int d = 1; d < 64; d <<= 1) {
    int u = __shfl_up(s, d);
    if (lane >= d) s += u;
  }
  if (lane == 63) wt[w] = s;
  __syncthreads();
  int off = (w == 1) ? wt[0] : 0;
  if (t < SCB) boff[t] = off + s - v;
  if (t == 127) rowptr[NN] = wt[0] + wt[1];
}

__global__ __launch_bounds__(256) void k_scanC(int* __restrict__ rowptr,
    const int* __restrict__ boff, int* __restrict__ wptr)
{
  int b = blockIdx.x, t = threadIdx.x;
  int i = b * 256 + t;
  if (i < NN) {
    int r = rowptr[i] + boff[b];
    rowptr[i] = r;
    wptr[i] = r;
  }
}

__global__ __launch_bounds__(256) void k_scatter(const int* __restrict__ ei,
    int* __restrict__ wptr, int* __restrict__ csr_src)
{
  int i = blockIdx.x * 256 + threadIdx.x;
  if (i >= ETOT) return;
  int src = (i < EE) ? ei[i] : (i - EE);
  int dst = (i < EE) ? ei[EE + i] : (i - EE);
  int pos = atomicAdd(&wptr[dst], 1);
  csr_src[pos] = src;
}

// ---------------- fp16 MFMA GEMM: 128x256 tile, 8 waves ----------------
// grid (MPAD/128, 2): y selects Wl->Xl / Wr->Xr. A staged once per block.
#define BKG 64
__global__ __launch_bounds__(512) void k_gemm16(const _Float16* __restrict__ A,
    const _Float16* __restrict__ WT,
    _Float16* __restrict__ Xl, _Float16* __restrict__ Xr)
{
  __shared__ __align__(16) _Float16 As[128 * BKG];   // 16KB
  __shared__ __align__(16) _Float16 Bs[256 * BKG];   // 32KB
  int t = threadIdx.x;
  int w = t >> 6, lane = t & 63;
  int row0 = blockIdx.x * 128;
  int ct = blockIdx.y;
  const _Float16* Bmat = WT + (size_t)ct * HD * HD;   // [n][k]
  _Float16* Out = ct ? Xr : Xl;

  f32x4 acc[4][4] = {};
  int wr = w >> 2, wc = w & 3;   // 2x4 wave grid: 64x64 each

  for (int k0 = 0; k0 < HD; k0 += BKG) {
    // stage A: 1024 16B-slots, 2 per thread
#pragma unroll
    for (int i = 0; i < 2; ++i) {
      int p = i * 512 + t;
      int row = p >> 3, s = p & 7;
      int g = s ^ (row & 7);
      __builtin_amdgcn_global_load_lds(
        (const __attribute__((address_space(1))) void*)(A + (size_t)(row0 + row) * HD + k0 + g * 8),
        (__attribute__((address_space(3))) void*)((char*)As + (i * 8 + w) * 1024),
        16, 0, 0);
    }
    // stage B: 2048 slots, 4 per thread
#pragma unroll
    for (int i = 0; i < 4; ++i) {
      int p = i * 512 + t;
      int row = p >> 3, s = p & 7;
      int g = s ^ (row & 7);
      __builtin_amdgcn_global_load_lds(
        (const __attribute__((address_space(1))) void*)(Bmat + (size_t)row * HD + k0 + g * 8),
        (__attribute__((address_space(3))) void*)((char*)Bs + (i * 8 + w) * 1024),
        16, 0, 0);
    }
    __syncthreads();
#pragma unroll
    for (int ks = 0; ks < 2; ++ks) {
      half8 af[4], bfr[4];
      int kslot = ks * 4 + (lane >> 4);
#pragma unroll
      for (int mi = 0; mi < 4; ++mi) {
        int rl = wr * 64 + mi * 16 + (lane & 15);
        int ps = kslot ^ (rl & 7);
        af[mi] = *(const half8*)((const char*)As + rl * 128 + ps * 16);
      }
#pragma unroll
      for (int ni = 0; ni < 4; ++ni) {
        int nl = wc * 64 + ni * 16 + (lane & 15);
        int ps = kslot ^ (nl & 7);
        bfr[ni] = *(const half8*)((const char*)Bs + nl * 128 + ps * 16);
      }
#pragma unroll
      for (int mi = 0; mi < 4; ++mi)
#pragma unroll
        for (int ni = 0; ni < 4; ++ni)
          acc[mi][ni] = __builtin_amdgcn_mfma_f32_16x16x32_f16(af[mi], bfr[ni], acc[mi][ni], 0, 0, 0);
    }
    __syncthreads();
  }
  int crow = (lane >> 4) * 4;
  int ccol = lane & 15;
#pragma unroll
  for (int mi = 0; mi < 4; ++mi)
#pragma unroll
    for (int ni = 0; ni < 4; ++ni) {
      size_t base_r = row0 + wr * 64 + mi * 16 + crow;
      int c = wc * 64 + ni * 16 + ccol;
#pragma unroll
      for (int r = 0; r < 4; ++r)
        Out[(base_r + r) * HD + c] = (_Float16)acc[mi][ni][r];
    }
}

// ---------------- fused edge + online-softmax agg ----------------
// one wave per node; lanes 0-31 / 32-63 = interleaved edge streams with
// independent online softmax, merged at end. 8 ch/lane, 3-deep prefetch.
__global__ __launch_bounds__(256) void k_edgeagg(const _Float16* __restrict__ Xl,
    const _Float16* __restrict__ Xr, const float* __restrict__ attw,
    const float* __restrict__ bias, const int* __restrict__ rowptr,
    const int* __restrict__ csr_src, _Float16* __restrict__ H16)
{
  int node = blockIdx.x * 4 + (threadIdx.x >> 6);
  int lane = threadIdx.x & 63;
  if (node >= NN) return;
  int st = rowptr[node], en = rowptr[node + 1];
  int n = en - st;
  int hf = lane >> 5, sl = lane & 31;
  int c = sl * 8;
  half8 xrv = *(const half8*)(Xr + (size_t)node * HD + c);
  float4 wa = *(const float4*)(attw + c);
  float4 wb = *(const float4*)(attw + c + 4);
  half2v w0 = mk2((_Float16)wa.x, (_Float16)wa.y);
  half2v w1 = mk2((_Float16)wa.z, (_Float16)wa.w);
  half2v w2 = mk2((_Float16)wb.x, (_Float16)wb.y);
  half2v w3 = mk2((_Float16)wb.z, (_Float16)wb.w);
  half2v r0 = mk2(xrv[0], xrv[1]), r1 = mk2(xrv[2], xrv[3]);
  half2v r2 = mk2(xrv[4], xrv[5]), r3 = mk2(xrv[6], xrv[7]);
  half2v c02 = mk2((_Float16)0.2f, (_Float16)0.2f);

  float mh = -1e30f, dsum = 0.f;
  float a[8] = {};
  int trips = (n + 1) >> 1;
  int base = st + hf;

  // 3-deep prefetch pipeline (reads past en land in CSR pad / next node: safe)
  half8 b0 = *(const half8*)(Xl + (size_t)csr_src[base] * HD + c);
  half8 b1 = *(const half8*)(Xl + (size_t)csr_src[base + 2] * HD + c);
  half8 b2 = *(const half8*)(Xl + (size_t)csr_src[base + 4] * HD + c);

  for (int it = 0; it < trips; ++it) {
    bool valid = (2 * it + hf) < n;
    half8 xc = b0;
    b0 = b1; b1 = b2;
    if (it + 3 < trips + 3) {   // always issue; stays within pad
      int nidx = csr_src[base + 2 * (it + 3)];
      b2 = *(const half8*)(Xl + (size_t)nidx * HD + c);
    }
    half2v x0 = mk2(xc[0], xc[1]), x1 = mk2(xc[2], xc[3]);
    half2v x2 = mk2(xc[4], xc[5]), x3 = mk2(xc[6], xc[7]);
    half2v s0 = x0 + r0, s1 = x1 + r1, s2 = x2 + r2, s3 = x3 + r3;
    half2v m0 = h2max(s0, s0 * c02);
    half2v m1 = h2max(s1, s1 * c02);
    half2v m2 = h2max(s2, s2 * c02);
    half2v m3 = h2max(s3, s3 * c02);
    float eA = h2dot(m1, w1, h2dot(m0, w0, 0.f));
    float eB = h2dot(m3, w3, h2dot(m2, w2, 0.f));
    float e = eA + eB;
    e += __shfl_xor(e, 1);
    e += __shfl_xor(e, 2);
    e = valid ? e : -1e30f;
    if (__any(e > mh + 8.f)) {
      float nm = fmaxf(mh, e);
      float sc = __expf(mh - nm);
      dsum *= sc;
#pragma unroll
      for (int j = 0; j < 8; ++j) a[j] *= sc;
      mh = nm;
    }
    float pw = valid ? __expf(e - mh) : 0.f;
#pragma unroll
    for (int j = 0; j < 8; ++j) a[j] += pw * (float)xc[j];
    dsum += pw;
  }
  // merge the two halves' online softmaxes (exact)
  float om = __shfl_xor(mh, 32);
  float od = __shfl_xor(dsum, 32);
  float nm = fmaxf(mh, om);
  float scs = __expf(mh - nm);
  float sco = __expf(om - nm);
  float d = dsum * scs + od * sco;
#pragma unroll
  for (int j = 0; j < 8; ++j) {
    float oa = __shfl_xor(a[j], 32);
    a[j] = a[j] * scs + oa * sco;
  }
  if (hf == 0) {
    float inv = 1.f / (d + 1e-16f);
    float4 ba = *(const float4*)(bias + c);
    float4 bb = *(const float4*)(bias + c + 4);
    float ob[8] = {ba.x, ba.y, ba.z, ba.w, bb.x, bb.y, bb.z, bb.w};
    half8 h8;
#pragma unroll
    for (int j = 0; j < 8; ++j) {
      float o = a[j] * inv + ob[j];
      o = (o > 0.f) ? o : expm1f(o);
      h8[j] = (_Float16)o;
    }
    *(half8*)(H16 + (size_t)node * HD + c) = h8;
  }
}

// ---------------- global sum: per-block partials ----------------
__global__ __launch_bounds__(256) void k_gsum(const _Float16* __restrict__ H,
    const int* __restrict__ batch, float* __restrict__ gpart, int* __restrict__ gcnt)
{
  __shared__ float flagf[RPB];
  __shared__ int scount;
  int b = blockIdx.x, t = threadIdx.x;
  int r0 = b * RPB;
  int nr = NN - r0; if (nr > RPB) nr = RPB; if (nr < 0) nr = 0;
  if (t == 0) scount = 0;
  __syncthreads();
  if (t < nr) {
    int ok = (batch[r0 + t] == 0) ? 1 : 0;
    flagf[t] = (float)ok;
    if (ok) atomicAdd(&scount, 1);
  }
  __syncthreads();
  float a0 = 0.f, a1 = 0.f, a2 = 0.f, a3 = 0.f;
  const _Float16* Hp = H + (size_t)r0 * HD + t;
  int r = 0;
  for (; r + 4 <= nr; r += 4) {
    float v0 = (float)Hp[(size_t)(r + 0) * HD];
    float v1 = (float)Hp[(size_t)(r + 1) * HD];
    float v2 = (float)Hp[(size_t)(r + 2) * HD];
    float v3 = (float)Hp[(size_t)(r + 3) * HD];
    a0 += v0 * flagf[r + 0]; a1 += v1 * flagf[r + 1];
    a2 += v2 * flagf[r + 2]; a3 += v3 * flagf[r + 3];
  }
  for (; r < nr; ++r) a0 += (float)Hp[(size_t)r * HD] * flagf[r];
  gpart[(size_t)b * HD + t] = (a0 + a1) + (a2 + a3);
  if (t == 0 && scount) atomicAdd(gcnt, scount);
}

// ---------------- tail head: sheet pool + geo1 (+gfin at blk SS) ----------------
__global__ __launch_bounds__(256) void k_tail1(const _Float16* __restrict__ h16,
    const int* __restrict__ sheet_idx, const float* __restrict__ sheet_feat,
    const float* __restrict__ geo_W1, const float* __restrict__ geo_b1,
    const float* __restrict__ geo_g1, const float* __restrict__ geo_be1,
    const float* __restrict__ gpart, const int* __restrict__ gcnt,
    float* __restrict__ gvec,
    _Float16* __restrict__ sh16, _Float16* __restrict__ g116)
{
  __shared__ float xf[FI];
  __shared__ int sidx[KS];
  __shared__ float red16[16];
  int s = blockIdx.x, t = threadIdx.x;

  if (s == SS) {
    float a0 = 0.f, a1 = 0.f, a2 = 0.f, a3 = 0.f;
    for (int b = 0; b < GSB; b += 4) {
      a0 += gpart[(size_t)b * HD + t];
      a1 += gpart[(size_t)(b + 1) * HD + t];
      a2 += gpart[(size_t)(b + 2) * HD + t];
      a3 += gpart[(size_t)(b + 3) * HD + t];
    }
    gvec[t] = ((a0 + a1) + (a2 + a3)) / (float)(*gcnt);
    return;
  }

  if (t < KS) sidx[t] = sheet_idx[s * KS + t];
  if (t >= 240) xf[t - 240] = sheet_feat[s * FI + (t - 240)];
  __syncthreads();

  float pa[8] = {};
#pragma unroll 2
  for (int r = 0; r < KS; r += 8) {
#pragma unroll
    for (int u = 0; u < 8; ++u)
      pa[u] += (float)h16[(size_t)sidx[r + u] * HD + t];
  }
  float shv = ((pa[0] + pa[1]) + (pa[2] + pa[3]) + (pa[4] + pa[5]) + (pa[6] + pa[7])) * (1.f / KS);
  sh16[(size_t)s * HD + t] = (_Float16)shv;

  float a = geo_b1[t];
#pragma unroll
  for (int k = 0; k < FI; ++k) a += xf[k] * geo_W1[k * HD + t];
  float g1 = ln_fast(a, t, 256, red16, geo_g1, geo_be1, true);
  g116[(size_t)s * HD + t] = (_Float16)g1;
}

// ---------------- MFMA tail stage with LN (NW waves, 16 rows/block) ----------------
template <int KD, int NW>
__global__ __launch_bounds__(NW * 64) void k_stageLN(
    const _Float16* __restrict__ X, const _Float16* __restrict__ WT,
    const float* __restrict__ b, const float* __restrict__ G,
    const float* __restrict__ Be, _Float16* __restrict__ Y,
    const float* __restrict__ W3, const float* __restrict__ b3,
    float* __restrict__ outq,
    const float* __restrict__ gvec,
    const float* __restrict__ dW1, const float* __restrict__ db1,
    const float* __restrict__ dg1, const float* __restrict__ dbe1,
    const float* __restrict__ dW2, const float* __restrict__ db2,
    float* __restrict__ outd)
{
  __shared__ float ps[NW * 16], ps2[NW * 16], pq[NW * 16];
  const int NCOL = NW * 64;
  int t = threadIdx.x;

  if (outd != nullptr && blockIdx.x == 16) {
    int w2 = t >> 6;
    float acc2 = db1[t];
    for (int k = 0; k < 256; ++k) acc2 += gvec[k] * dW1[(size_t)k * 128 + t];
    float s = wsum(acc2), s2v = wsum(acc2 * acc2);
    if ((t & 63) == 0) { ps[w2] = s; ps2[w2] = s2v; }
    __syncthreads();
    float S = ps[0] + ps[1], S2 = ps2[0] + ps2[1];
    float mu = S * (1.f / 128.f), var = S2 * (1.f / 128.f) - mu * mu;
    float hdv = fmaxf((acc2 - mu) * rsqrtf(var + 1e-5f) * dg1[t] + dbe1[t], 0.f);
    float o = wsum(hdv * dW2[t]);
    if ((t & 63) == 0) pq[w2] = o;
    __syncthreads();
    if (t == 0) outd[0] = pq[0] + pq[1] + db2[0];
    return;
  }

  int w = t >> 6, lane = t & 63;
  int arow = lane & 15, kg = lane >> 4;
  int m0 = blockIdx.x * 16;
  int col0 = w * 64;

  f32x4 acc[4] = {};
#pragma unroll
  for (int ks = 0; ks < KD / 32; ++ks) {
    half8 af = *(const half8*)(X + (size_t)(m0 + arow) * KD + ks * 32 + kg * 8);
#pragma unroll
    for (int n = 0; n < 4; ++n) {
      half8 bf = *(const half8*)(WT + (size_t)(col0 + n * 16 + arow) * KD + ks * 32 + kg * 8);
      acc[n] = __builtin_amdgcn_mfma_f32_16x16x32_f16(af, bf, acc[n], 0, 0, 0);
    }
  }
#pragma unroll
  for (int n = 0; n < 4; ++n) {
    float bv = b[col0 + n * 16 + arow];
#pragma unroll
    for (int r = 0; r < 4; ++r) acc[n][r] += bv;
  }
  float s[4] = {}, s2[4] = {};
#pragma unroll
  for (int n = 0; n < 4; ++n)
#pragma unroll
    for (int r = 0; r < 4; ++r) { float v = acc[n][r]; s[r] += v; s2[r] += v * v; }
#pragma unroll
  for (int d = 1; d < 16; d <<= 1)
#pragma unroll
    for (int r = 0; r < 4; ++r) { s[r] += __shfl_xor(s[r], d); s2[r] += __shfl_xor(s2[r], d); }
  if (arow == 0) {
#pragma unroll
    for (int r = 0; r < 4; ++r) {
      ps[w * 16 + kg * 4 + r] = s[r];
      ps2[w * 16 + kg * 4 + r] = s2[r];
    }
  }
  __syncthreads();
  float mu[4], rs[4];
#pragma unroll
  for (int r = 0; r < 4; ++r) {
    float S = 0.f, S2 = 0.f;
#pragma unroll
    for (int w2 = 0; w2 < NW; ++w2) { S += ps[w2 * 16 + kg * 4 + r]; S2 += ps2[w2 * 16 + kg * 4 + r]; }
    float m = S / NCOL;
    float var = S2 / NCOL - m * m;
    mu[r] = m; rs[r] = rsqrtf(var + 1e-5f);
  }
#pragma unroll
  for (int n = 0; n < 4; ++n) {
    int col = col0 + n * 16 + arow;
    float gv = G[col], bev = Be[col];
#pragma unroll
    for (int r = 0; r < 4; ++r)
      acc[n][r] = fmaxf((acc[n][r] - mu[r]) * rs[r] * gv + bev, 0.f);
  }
  if (Y) {
#pragma unroll
    for (int n = 0; n < 4; ++n) {
      int col = col0 + n * 16 + arow;
#pragma unroll
      for (int r = 0; r < 4; ++r)
        Y[(size_t)(m0 + kg * 4 + r) * NCOL + col] = (_Float16)acc[n][r];
    }
  }
  if (outq) {
    float p[4] = {};
#pragma unroll
    for (int n = 0; n < 4; ++n) {
      float w3 = W3[col0 + n * 16 + arow];
#pragma unroll
      for (int r = 0; r < 4; ++r) p[r] += acc[n][r] * w3;
    }
#pragma unroll
    for (int d = 1; d < 16; d <<= 1)
#pragma unroll
      for (int r = 0; r < 4; ++r) p[r] += __shfl_xor(p[r], d);
    if (arow == 0)
#pragma unroll
      for (int r = 0; r < 4; ++r) pq[w * 16 + kg * 4 + r] = p[r];
    __syncthreads();
    if (w == 0 && arow == 0) {
#pragma unroll
      for (int r = 0; r < 4; ++r) {
        float o = b3[0];
#pragma unroll
        for (int w2 = 0; w2 < NW; ++w2) o += pq[w2 * 16 + kg * 4 + r];
        outq[m0 + kg * 4 + r] = o;
      }
    }
  }
}

// ---------------- q/k/v stage (no LN): grid (16, 4, 3) ----------------
__global__ __launch_bounds__(64) void k_qkv(
    const _Float16* __restrict__ sh16, const _Float16* __restrict__ g216,
    const _Float16* __restrict__ Tq, const _Float16* __restrict__ Tk,
    const _Float16* __restrict__ Tv,
    const float* __restrict__ bq, const float* __restrict__ bk,
    const float* __restrict__ bv,
    _Float16* __restrict__ qb, _Float16* __restrict__ kb, _Float16* __restrict__ vb)
{
  int lane = threadIdx.x;
  int arow = lane & 15, kg = lane >> 4;
  int m0 = blockIdx.x * 16;
  int col0 = blockIdx.y * 64;
  int mat = blockIdx.z;
  const _Float16* X = (mat == 0) ? sh16 : g216;
  const _Float16* WT = (mat == 0) ? Tq : (mat == 1) ? Tk : Tv;
  const float* b = (mat == 0) ? bq : (mat == 1) ? bk : bv;
  _Float16* Y = (mat == 0) ? qb : (mat == 1) ? kb : vb;

  f32x4 acc[4] = {};
#pragma unroll
  for (int ks = 0; ks < 8; ++ks) {
    half8 af = *(const half8*)(X + (size_t)(m0 + arow) * 256 + ks * 32 + kg * 8);
#pragma unroll
    for (int n = 0; n < 4; ++n) {
      half8 bf = *(const half8*)(WT + (size_t)(col0 + n * 16 + arow) * 256 + ks * 32 + kg * 8);
      acc[n] = __builtin_amdgcn_mfma_f32_16x16x32_f16(af, bf, acc[n], 0, 0, 0);
    }
  }
#pragma unroll
  for (int n = 0; n < 4; ++n) {
    int col = col0 + n * 16 + arow;
    float bv2 = b[col];
#pragma unroll
    for (int r = 0; r < 4; ++r)
      Y[(size_t)(m0 + kg * 4 + r) * 256 + col] = (_Float16)(acc[n][r] + bv2);
  }
}

// ---------------- Wo stage + gv concat: grid (16, 4) ----------------
__global__ __launch_bounds__(64) void k_wo(
    const _Float16* __restrict__ pv16, const _Float16* __restrict__ To,
    const float* __restrict__ bo, const float* __restrict__ gvec,
    _Float16* __restrict__ hqin)
{
  int lane = threadIdx.x;
  int arow = lane & 15, kg = lane >> 4;
  int m0 = blockIdx.x * 16;
  int col0 = blockIdx.y * 64;

  f32x4 acc[4] = {};
#pragma unroll
  for (int ks = 0; ks < 8; ++ks) {
    half8 af = *(const half8*)(pv16 + (size_t)(m0 + arow) * 256 + ks * 32 + kg * 8);
#pragma unroll
    for (int n = 0; n < 4; ++n) {
      half8 bf = *(const half8*)(To + (size_t)(col0 + n * 16 + arow) * 256 + ks * 32 + kg * 8);
      acc[n] = __builtin_amdgcn_mfma_f32_16x16x32_f16(af, bf, acc[n], 0, 0, 0);
    }
  }
#pragma unroll
  for (int n = 0; n < 4; ++n) {
    int col = col0 + n * 16 + arow;
    float bv = bo[col];
    _Float16 gg = (_Float16)gvec[col];
#pragma unroll
    for (int r = 0; r < 4; ++r) {
      hqin[(size_t)(m0 + kg * 4 + r) * 512 + col] = (_Float16)(acc[n][r] + bv);
      hqin[(size_t)(m0 + kg * 4 + r) * 512 + 256 + col] = gg;
    }
  }
}

// ---------------- cross-attention per query row (1024 thr) ----------------
__global__ __launch_bounds__(1024) void k_attn(const _Float16* __restrict__ qb,
    const _Float16* __restrict__ kb, const _Float16* __restrict__ vb,
    _Float16* __restrict__ pv16)
{
  __shared__ float qv[HD];
  __shared__ float att[1024];
  __shared__ float red4[1024];
  __shared__ float redm[16];
  __shared__ float reds[16];
  int row = blockIdx.x, t = threadIdx.x;
  int w = t >> 6;

  if (t < 256) qv[t] = (float)qb[(size_t)row * HD + t];
  __syncthreads();

  int h = t >> 8, key = t & 255;
  float e = 0.f;
  {
    const half8* kr = (const half8*)(kb + (size_t)key * HD + h * HC);
    const float* qh = qv + h * HC;
#pragma unroll
    for (int d = 0; d < 8; ++d) {
      half8 kk = kr[d];
#pragma unroll
      for (int u = 0; u < 8; ++u) e += qh[d * 8 + u] * (float)kk[u];
    }
    e *= 0.125f;
  }
  float wm = e;
#pragma unroll
  for (int d = 1; d < 64; d <<= 1) wm = fmaxf(wm, __shfl_xor(wm, d));
  if ((t & 63) == 0) redm[w] = wm;
  __syncthreads();
  float mx = fmaxf(fmaxf(redm[4 * h], redm[4 * h + 1]), fmaxf(redm[4 * h + 2], redm[4 * h + 3]));
  float pw = __expf(e - mx);
  float ws = wsum(pw);
  if ((t & 63) == 0) reds[w] = ws;
  att[t] = pw;
  __syncthreads();

  int kq = t >> 8, j = t & 255;
  int hj = j >> 6;
  float p = 0.f;
  const float* arow = att + hj * 256 + kq * 64;
  const _Float16* vcol = vb + (size_t)(kq * 64) * HD + j;
  for (int k = 0; k < 64; ++k)
    p += arow[k] * (float)vcol[(size_t)k * HD];
  red4[t] = p;
  __syncthreads();
  if (t < 256) {
    int hh = t >> 6;
    float dsum = reds[4 * hh] + reds[4 * hh + 1] + reds[4 * hh + 2] + reds[4 * hh + 3];
    float pv = (red4[t] + red4[256 + t] + red4[512 + t] + red4[768 + t]) / dsum;
    pv16[(size_t)row * HD + t] = (_Float16)pv;
  }
}

// =====================================================================
extern "C" void kernel_launch(void* const* d_in, const int* in_sizes, int n_in,
                              void* d_out, int out_size, void* d_ws, size_t ws_size,
                              hipStream_t stream) {
  const float* x      = (const float*)d_in[0];
  const int*   ei     = (const int*)d_in[1];
  const int*   batch  = (const int*)d_in[2];
  const int*   sheet_idx = (const int*)d_in[3];
  const float* sheet_feat = (const float*)d_in[4];
  const float* pre_W  = (const float*)d_in[5];
  const float* pre_b  = (const float*)d_in[6];
  const float* gat_Wl = (const float*)d_in[7];
  const float* gat_Wr = (const float*)d_in[8];
  const float* gat_att = (const float*)d_in[9];
  const float* gat_b  = (const float*)d_in[10];
  const float* geo_W1 = (const float*)d_in[11];
  const float* geo_b1 = (const float*)d_in[12];
  const float* geo_g1 = (const float*)d_in[13];
  const float* geo_be1 = (const float*)d_in[14];
  const float* geo_W2 = (const float*)d_in[15];
  const float* geo_b2 = (const float*)d_in[16];
  const float* geo_g2 = (const float*)d_in[17];
  const float* geo_be2 = (const float*)d_in[18];
  const float* ca_Wq = (const float*)d_in[19];
  const float* ca_bq = (const float*)d_in[20];
  const float* ca_Wk = (const float*)d_in[21];
  const float* ca_bk = (const float*)d_in[22];
  const float* ca_Wv = (const float*)d_in[23];
  const float* ca_bv = (const float*)d_in[24];
  const float* ca_Wo = (const float*)d_in[25];
  const float* ca_bo = (const float*)d_in[26];
  const float* q_W1 = (const float*)d_in[27];
  const float* q_b1 = (const float*)d_in[28];
  const float* q_g1 = (const float*)d_in[29];
  const float* q_be1 = (const float*)d_in[30];
  const float* q_W2 = (const float*)d_in[31];
  const float* q_b2 = (const float*)d_in[32];
  const float* q_g2 = (const float*)d_in[33];
  const float* q_be2 = (const float*)d_in[34];
  const float* q_W3 = (const float*)d_in[35];
  const float* q_b3 = (const float*)d_in[36];
  const float* d_W1 = (const float*)d_in[37];
  const float* d_b1 = (const float*)d_in[38];
  const float* d_g1 = (const float*)d_in[39];
  const float* d_be1 = (const float*)d_in[40];
  const float* d_W2 = (const float*)d_in[41];
  const float* d_b2 = (const float*)d_in[42];

  char* wsb = (char*)d_ws;
  auto alloc = [&](size_t bytes) { char* p = wsb; wsb += (bytes + 255) & ~(size_t)255; return p; };

  _Float16* h16  = (_Float16*)alloc((size_t)MPAD * HD * 2);
  _Float16* Xl16 = (_Float16*)alloc((size_t)MPAD * HD * 2);
  _Float16* Xr16 = (_Float16*)alloc((size_t)MPAD * HD * 2);
  _Float16* WT   = (_Float16*)alloc((size_t)6 * HD * HD * 2);
  _Float16* Tgeo2 = (_Float16*)alloc((size_t)HD * HD * 2);
  _Float16* Tq   = (_Float16*)alloc((size_t)HD * HD * 2);
  _Float16* Tk   = (_Float16*)alloc((size_t)HD * HD * 2);
  _Float16* Tv   = (_Float16*)alloc((size_t)HD * HD * 2);
  _Float16* To   = (_Float16*)alloc((size_t)HD * HD * 2);
  _Float16* Tq1  = (_Float16*)alloc((size_t)HD * 512 * 2);
  _Float16* Tq2  = (_Float16*)alloc((size_t)128 * HD * 2);
  _Float16* sh16 = (_Float16*)alloc((size_t)SS * HD * 2);
  _Float16* g116 = (_Float16*)alloc((size_t)SS * HD * 2);
  _Float16* g216 = (_Float16*)alloc((size_t)SS * HD * 2);
  _Float16* qb16 = (_Float16*)alloc((size_t)SS * HD * 2);
  _Float16* kb16 = (_Float16*)alloc((size_t)SS * HD * 2);
  _Float16* vb16 = (_Float16*)alloc((size_t)SS * HD * 2);
  _Float16* pv16 = (_Float16*)alloc((size_t)SS * HD * 2);
  _Float16* hqin16 = (_Float16*)alloc((size_t)SS * 512 * 2);
  _Float16* hq116 = (_Float16*)alloc((size_t)SS * HD * 2);
  float* gpart   = (float*)alloc((size_t)GSB * HD * 4);
  float* gvec    = (float*)alloc(256 * 4);
  int* cnt       = (int*)alloc((size_t)NN * 4);
  int* rowptr    = (int*)alloc((size_t)(NN + 1) * 4);
  int* wptr      = (int*)alloc((size_t)NN * 4);
  int* csr_src   = (int*)alloc((size_t)(ETOT + 8) * 4);
  int* btot      = (int*)alloc((size_t)SCB * 4);
  int* boff      = (int*)alloc((size_t)SCB * 4);
  int* gcnt      = (int*)alloc(4);

  float* out_q = (float*)d_out;        // [256]
  float* out_d = out_q + SS;           // [1]

  k_init<<<118, 256, 0, stream>>>(cnt, gcnt, h16 + (size_t)NN * HD, csr_src + ETOT);

  // CSR build
  k_count<<<(ETOT + 255) / 256, 256, 0, stream>>>(ei, cnt);
  k_scanA<<<SCB, 256, 0, stream>>>(cnt, rowptr, btot);
  k_scanB<<<1, 128, 0, stream>>>(btot, boff, rowptr);
  k_scanC<<<SCB, 256, 0, stream>>>(rowptr, boff, wptr);
  k_scatter<<<(ETOT + 255) / 256, 256, 0, stream>>>(ei, wptr, csr_src);

  // weights + pre-transform
  k_wconvAll<<<3200, 256, 0, stream>>>(gat_Wl, gat_Wr, geo_W2, ca_Wq, ca_Wk, ca_Wv,
                                       ca_Wo, q_W1, q_W2,
                                       WT, Tgeo2, Tq, Tk, Tv, To, Tq1, Tq2);
  k_pre<<<NN / 8, 256, 0, stream>>>(x, pre_W, pre_b, h16);

  // GAT layers
  dim3 ggrid(MPAD / 128, 2);
  for (int l = 0; l < NL; ++l) {
    k_gemm16<<<ggrid, 512, 0, stream>>>(h16, WT + (size_t)l * 2 * HD * HD, Xl16, Xr16);
    k_edgeagg<<<(NN + 3) / 4, 256, 0, stream>>>(Xl16, Xr16, gat_att + l * NH * CH,
                                                gat_b + l * HD, rowptr, csr_src, h16);
  }

  // global mean partials
  k_gsum<<<GSB, 256, 0, stream>>>(h16, batch, gpart, gcnt);

  // tail (+gfin folded into block SS)
  k_tail1<<<SS + 1, 256, 0, stream>>>(h16, sheet_idx, sheet_feat,
      geo_W1, geo_b1, geo_g1, geo_be1, gpart, gcnt, gvec, sh16, g116);
  k_stageLN<256, 4><<<16, 256, 0, stream>>>(g116, Tgeo2, geo_b2, geo_g2, geo_be2,
      g216, nullptr, nullptr, nullptr,
      nullptr, nullptr, nullptr, nullptr, nullptr, nullptr, nullptr, nullptr);
  dim3 qkvg(16, 4, 3);
  k_qkv<<<qkvg, 64, 0, stream>>>(sh16, g216, Tq, Tk, Tv, ca_bq, ca_bk, ca_bv,
                                 qb16, kb16, vb16);
  k_attn<<<SS, 1024, 0, stream>>>(qb16, kb16, vb16, pv16);
  dim3 wog(16, 4);
  k_wo<<<wog, 64, 0, stream>>>(pv16, To, ca_bo, gvec, hqin16);
  k_stageLN<512, 4><<<16, 256, 0, stream>>>(hqin16, Tq1, q_b1, q_g1, q_be1,
      hq116, nullptr, nullptr, nullptr,
      nullptr, nullptr, nullptr, nullptr, nullptr, nullptr, nullptr, nullptr);
  // hq2 + qval (blocks 0..15) + done head (block 16)
  k_stageLN<256, 2><<<17, 128, 0, stream>>>(hq116, Tq2, q_b2, q_g2, q_be2,
      nullptr, q_W3, q_b3, out_q,
      gvec, d_W1, d_b1, d_g1, d_be1, d_W2, d_b2, out_d);
}

// Round 11
// 303.357 us; speedup vs baseline: 1.3548x; 1.0075x over previous
//
#include <hip/hip_runtime.h>
#include <hip/hip_bf16.h>
#include <stdint.h>

#define NN 30000
#define MPAD 30080
#define FI 16
#define EE 300000
#define ETOT (EE + NN)
#define HD 256
#define NH 8
#define CH 32
#define NL 3
#define SS 256
#define KS 128
#define NHC 4
#define HC 64
#define GSB 256
#define RPB 118
#define SCB 118

typedef _Float16 half8 __attribute__((ext_vector_type(8)));
typedef _Float16 half4v __attribute__((ext_vector_type(4)));
typedef _Float16 half2v __attribute__((ext_vector_type(2)));
typedef float f32x4 __attribute__((ext_vector_type(4)));

// ---------------- wave helpers ----------------
__device__ __forceinline__ float wsum(float v) {
#pragma unroll
  for (int d = 1; d < 64; d <<= 1) v += __shfl_xor(v, d);
  return v;
}

__device__ __forceinline__ half2v mk2(_Float16 a, _Float16 b) {
  half2v r; r[0] = a; r[1] = b; return r;
}

__device__ __forceinline__ half2v h2max(half2v a, half2v b) {
#if __has_builtin(__builtin_elementwise_max)
  return __builtin_elementwise_max(a, b);
#else
  half2v r; r[0] = a[0] > b[0] ? a[0] : b[0]; r[1] = a[1] > b[1] ? a[1] : b[1];
  return r;
#endif
}

__device__ __forceinline__ float h2dot(half2v a, half2v b, float c) {
#if __has_builtin(__builtin_amdgcn_fdot2)
  return __builtin_amdgcn_fdot2(a, b, c, false);
#else
  return c + (float)a[0] * (float)b[0] + (float)a[1] * (float)b[1];
#endif
}

// LN over n channels, 256 threads, t<n holds a. 2 barriers.
__device__ __forceinline__ float ln_fast(float a, int t, int n, float* red16,
    const float* __restrict__ G, const float* __restrict__ Be, bool relu)
{
  float av = (t < n) ? a : 0.f;
  float s = wsum(av), s2 = wsum(av * av);
  if ((t & 63) == 0) { red16[t >> 6] = s; red16[8 + (t >> 6)] = s2; }
  __syncthreads();
  float sum = red16[0] + red16[1] + red16[2] + red16[3];
  float sq  = red16[8] + red16[9] + red16[10] + red16[11];
  float mu = sum / n;
  float var = sq / n - mu * mu;
  float o = 0.f;
  if (t < n) {
    o = (a - mu) * rsqrtf(var + 1e-5f) * G[t] + Be[t];
    if (relu) o = fmaxf(o, 0.f);
  }
  __syncthreads();
  return o;
}

// ---------------- init ----------------
__global__ __launch_bounds__(256) void k_init(int* __restrict__ cnt,
    int* __restrict__ gcnt, _Float16* __restrict__ h16pad, int* __restrict__ csr_pad)
{
  int i = blockIdx.x * 256 + threadIdx.x;
  if (i < NN) cnt[i] = 0;
  if (i == 0) gcnt[0] = 0;
  if (i < 8) csr_pad[i] = 0;
  if (i < (MPAD - NN) * HD) h16pad[i] = (_Float16)0.f;
}

// ---------------- all weight transpose+convert (GAT + tail) ----------------
__global__ __launch_bounds__(256) void k_wconvAll(
    const float* __restrict__ Wl, const float* __restrict__ Wr,
    const float* __restrict__ geo_W2, const float* __restrict__ ca_Wq,
    const float* __restrict__ ca_Wk, const float* __restrict__ ca_Wv,
    const float* __restrict__ ca_Wo, const float* __restrict__ q_W1,
    const float* __restrict__ q_W2,
    _Float16* __restrict__ WT,
    _Float16* __restrict__ Tgeo2, _Float16* __restrict__ Tq,
    _Float16* __restrict__ Tk, _Float16* __restrict__ Tv,
    _Float16* __restrict__ To, _Float16* __restrict__ Tq1,
    _Float16* __restrict__ Tq2)
{
  int b = blockIdx.x, t = threadIdx.x;
  if (b < 1536) {
    int m = b >> 8;
    int n = b & 255;
    int l = m >> 1;
    const float* W = (m & 1) ? (Wr + (size_t)l * HD * HD) : (Wl + (size_t)l * HD * HD);
    WT[((size_t)m * HD + n) * HD + t] = (_Float16)W[t * HD + n];
    return;
  }
  b -= 1536;
  if (b < 1280) {
    int seg = b >> 8;
    int n = b & 255;
    const float* src = (seg == 0) ? geo_W2 : (seg == 1) ? ca_Wq : (seg == 2) ? ca_Wk
                     : (seg == 3) ? ca_Wv : ca_Wo;
    _Float16* dst = (seg == 0) ? Tgeo2 : (seg == 1) ? Tq : (seg == 2) ? Tk
                  : (seg == 3) ? Tv : To;
    dst[(size_t)n * 256 + t] = (_Float16)src[(size_t)t * 256 + n];
  } else if (b < 1536) {
    int n = b - 1280;
    Tq1[(size_t)n * 512 + t]       = (_Float16)q_W1[(size_t)t * 256 + n];
    Tq1[(size_t)n * 512 + 256 + t] = (_Float16)q_W1[(size_t)(256 + t) * 256 + n];
  } else {
    int n = b - 1536;
    Tq2[(size_t)n * 256 + t] = (_Float16)q_W2[(size_t)t * 128 + n];
  }
}

// ---------------- pre-transform ----------------
__global__ __launch_bounds__(256) void k_pre(const float* __restrict__ x,
    const float* __restrict__ W, const float* __restrict__ b,
    _Float16* __restrict__ H16)
{
  __shared__ float Ws[FI][HD];
  __shared__ float xs[8][FI];
  int r0 = blockIdx.x * 8;
  int t = threadIdx.x;
  for (int i = t; i < FI * HD; i += 256) Ws[i >> 8][i & 255] = W[i];
  if (t < 8 * FI) xs[t >> 4][t & 15] = x[(size_t)(r0 + (t >> 4)) * FI + (t & 15)];
  __syncthreads();
  float bj = b[t];
  for (int r = 0; r < 8; ++r) {
    float acc = bj;
#pragma unroll
    for (int k = 0; k < FI; ++k) acc += xs[r][k] * Ws[k][t];
    H16[(size_t)(r0 + r) * HD + t] = (_Float16)acc;
  }
}

// ---------------- CSR build ----------------
__global__ __launch_bounds__(256) void k_count(const int* __restrict__ ei, int* __restrict__ cnt)
{
  int i = blockIdx.x * 256 + threadIdx.x;
  if (i >= ETOT) return;
  int dst = (i < EE) ? ei[EE + i] : (i - EE);
  atomicAdd(&cnt[dst], 1);
}

__global__ __launch_bounds__(256) void k_scanA(const int* __restrict__ cnt,
    int* __restrict__ rowptr, int* __restrict__ btot)
{
  __shared__ int wt[4];
  int b = blockIdx.x, t = threadIdx.x;
  int i = b * 256 + t;
  int v = (i < NN) ? cnt[i] : 0;
  int lane = t & 63, w = t >> 6;
  int s = v;
#pragma unroll
  for (int d = 1; d < 64; d <<= 1) {
    int u = __shfl_up(s, d);
    if (lane >= d) s += u;
  }
  if (lane == 63) wt[w] = s;
  __syncthreads();
  int off = 0;
  for (int k = 0; k < w; ++k) off += wt[k];
  if (i < NN) rowptr[i] = off + s - v;
  if (t == 255) btot[b] = off + s;
}

__global__ __launch_bounds__(128) void k_scanB(const int* __restrict__ btot,
    int* __restrict__ boff, int* __restrict__ rowptr)
{
  __shared__ int wt[2];
  int t = threadIdx.x;
  int v = (t < SCB) ? btot[t] : 0;
  int lane = t & 63, w = t >> 6;
  int s = v;
#pragma unroll
  for (int d = 1; d < 64; d <<= 1) {
    int u = __shfl_up(s, d);
    if (lane >= d) s += u;
  }
  if (lane == 63) wt[w] = s;
  __syncthreads();
  int off = (w == 1) ? wt[0] : 0;
  if (t < SCB) boff[t] = off + s - v;
  if (t == 127) rowptr[NN] = wt[0] + wt[1];
}

__global__ __launch_bounds__(256) void k_scanC(int* __restrict__ rowptr,
    const int* __restrict__ boff, int* __restrict__ wptr)
{
  int b = blockIdx.x, t = threadIdx.x;
  int i = b * 256 + t;
  if (i < NN) {
    int r = rowptr[i] + boff[b];
    rowptr[i] = r;
    wptr[i] = r;
  }
}

__global__ __launch_bounds__(256) void k_scatter(const int* __restrict__ ei,
    int* __restrict__ wptr, int* __restrict__ csr_src)
{
  int i = blockIdx.x * 256 + threadIdx.x;
  if (i >= ETOT) return;
  int src = (i < EE) ? ei[i] : (i - EE);
  int dst = (i < EE) ? ei[EE + i] : (i - EE);
  int pos = atomicAdd(&wptr[dst], 1);
  csr_src[pos] = src;
}

// ---------------- fp16 MFMA GEMM: 128x256 tile, 8 waves ----------------
#define BKG 64
__global__ __launch_bounds__(512) void k_gemm16(const _Float16* __restrict__ A,
    const _Float16* __restrict__ WT,
    _Float16* __restrict__ Xl, _Float16* __restrict__ Xr)
{
  __shared__ __align__(16) _Float16 As[128 * BKG];   // 16KB
  __shared__ __align__(16) _Float16 Bs[256 * BKG];   // 32KB
  int t = threadIdx.x;
  int w = t >> 6, lane = t & 63;
  int row0 = blockIdx.x * 128;
  int ct = blockIdx.y;
  const _Float16* Bmat = WT + (size_t)ct * HD * HD;   // [n][k]
  _Float16* Out = ct ? Xr : Xl;

  f32x4 acc[4][4] = {};
  int wr = w >> 2, wc = w & 3;

  for (int k0 = 0; k0 < HD; k0 += BKG) {
#pragma unroll
    for (int i = 0; i < 2; ++i) {
      int p = i * 512 + t;
      int row = p >> 3, s = p & 7;
      int g = s ^ (row & 7);
      __builtin_amdgcn_global_load_lds(
        (const __attribute__((address_space(1))) void*)(A + (size_t)(row0 + row) * HD + k0 + g * 8),
        (__attribute__((address_space(3))) void*)((char*)As + (i * 8 + w) * 1024),
        16, 0, 0);
    }
#pragma unroll
    for (int i = 0; i < 4; ++i) {
      int p = i * 512 + t;
      int row = p >> 3, s = p & 7;
      int g = s ^ (row & 7);
      __builtin_amdgcn_global_load_lds(
        (const __attribute__((address_space(1))) void*)(Bmat + (size_t)row * HD + k0 + g * 8),
        (__attribute__((address_space(3))) void*)((char*)Bs + (i * 8 + w) * 1024),
        16, 0, 0);
    }
    __syncthreads();
#pragma unroll
    for (int ks = 0; ks < 2; ++ks) {
      half8 af[4], bfr[4];
      int kslot = ks * 4 + (lane >> 4);
#pragma unroll
      for (int mi = 0; mi < 4; ++mi) {
        int rl = wr * 64 + mi * 16 + (lane & 15);
        int ps = kslot ^ (rl & 7);
        af[mi] = *(const half8*)((const char*)As + rl * 128 + ps * 16);
      }
#pragma unroll
      for (int ni = 0; ni < 4; ++ni) {
        int nl = wc * 64 + ni * 16 + (lane & 15);
        int ps = kslot ^ (nl & 7);
        bfr[ni] = *(const half8*)((const char*)Bs + nl * 128 + ps * 16);
      }
#pragma unroll
      for (int mi = 0; mi < 4; ++mi)
#pragma unroll
        for (int ni = 0; ni < 4; ++ni)
          acc[mi][ni] = __builtin_amdgcn_mfma_f32_16x16x32_f16(af[mi], bfr[ni], acc[mi][ni], 0, 0, 0);
    }
    __syncthreads();
  }
  int crow = (lane >> 4) * 4;
  int ccol = lane & 15;
#pragma unroll
  for (int mi = 0; mi < 4; ++mi)
#pragma unroll
    for (int ni = 0; ni < 4; ++ni) {
      size_t base_r = row0 + wr * 64 + mi * 16 + crow;
      int c = wc * 64 + ni * 16 + ccol;
#pragma unroll
      for (int r = 0; r < 4; ++r)
        Out[(base_r + r) * HD + c] = (_Float16)acc[mi][ni][r];
    }
}

// ---------------- fused edge + online-softmax agg ----------------
// one wave per node; lanes 0-31/32-63 = interleaved edge streams, independent
// online softmax merged at end. 8 ch/lane, 3-deep prefetch, fp16 pk accum.
__global__ __launch_bounds__(256) void k_edgeagg(const _Float16* __restrict__ Xl,
    const _Float16* __restrict__ Xr, const float* __restrict__ attw,
    const float* __restrict__ bias, const int* __restrict__ rowptr,
    const int* __restrict__ csr_src, _Float16* __restrict__ H16)
{
  int node = blockIdx.x * 4 + (threadIdx.x >> 6);
  int lane = threadIdx.x & 63;
  if (node >= NN) return;
  int st = rowptr[node], en = rowptr[node + 1];
  int n = en - st;
  int hf = lane >> 5, sl = lane & 31;
  int c = sl * 8;
  half8 xrv = *(const half8*)(Xr + (size_t)node * HD + c);
  float4 wa = *(const float4*)(attw + c);
  float4 wb = *(const float4*)(attw + c + 4);
  half2v w0 = mk2((_Float16)wa.x, (_Float16)wa.y);
  half2v w1 = mk2((_Float16)wa.z, (_Float16)wa.w);
  half2v w2 = mk2((_Float16)wb.x, (_Float16)wb.y);
  half2v w3 = mk2((_Float16)wb.z, (_Float16)wb.w);
  half2v r0 = mk2(xrv[0], xrv[1]), r1 = mk2(xrv[2], xrv[3]);
  half2v r2 = mk2(xrv[4], xrv[5]), r3 = mk2(xrv[6], xrv[7]);
  half2v c02 = mk2((_Float16)0.2f, (_Float16)0.2f);

  float mh = -1e30f, dsum = 0.f;
  half2v acch0 = {}, acch1 = {}, acch2 = {}, acch3 = {};
  int trips = (n + 1) >> 1;
  int base = st + hf;

  half8 b0 = *(const half8*)(Xl + (size_t)csr_src[base] * HD + c);
  half8 b1 = *(const half8*)(Xl + (size_t)csr_src[base + 2] * HD + c);
  half8 b2 = *(const half8*)(Xl + (size_t)csr_src[base + 4] * HD + c);

  for (int it = 0; it < trips; ++it) {
    bool valid = (2 * it + hf) < n;
    half8 xc = b0;
    b0 = b1; b1 = b2;
    {
      int nidx = csr_src[base + 2 * (it + 3)];   // stays within pad for last node
      b2 = *(const half8*)(Xl + (size_t)nidx * HD + c);
    }
    half2v x0 = mk2(xc[0], xc[1]), x1 = mk2(xc[2], xc[3]);
    half2v x2 = mk2(xc[4], xc[5]), x3 = mk2(xc[6], xc[7]);
    half2v s0 = x0 + r0, s1 = x1 + r1, s2 = x2 + r2, s3 = x3 + r3;
    half2v m0 = h2max(s0, s0 * c02);
    half2v m1 = h2max(s1, s1 * c02);
    half2v m2 = h2max(s2, s2 * c02);
    half2v m3 = h2max(s3, s3 * c02);
    float eA = h2dot(m1, w1, h2dot(m0, w0, 0.f));
    float eB = h2dot(m3, w3, h2dot(m2, w2, 0.f));
    float e = eA + eB;
    e += __shfl_xor(e, 1);
    e += __shfl_xor(e, 2);
    e = valid ? e : -1e30f;
    // defer-max THR=4 so deferred weights <= e^4 (fp16 accum overflow-safe)
    if (__any(e > mh + 4.f)) {
      float nm = fmaxf(mh, e);
      float sc = __expf(mh - nm);
      _Float16 sch16 = (_Float16)sc;
      half2v sch = mk2(sch16, sch16);
      acch0 *= sch; acch1 *= sch; acch2 *= sch; acch3 *= sch;
      dsum *= sc;
      mh = nm;
    }
    float pw = valid ? __expf(e - mh) : 0.f;
    _Float16 pwh16 = (_Float16)pw;
    half2v pwh = mk2(pwh16, pwh16);
    acch0 += pwh * x0;
    acch1 += pwh * x1;
    acch2 += pwh * x2;
    acch3 += pwh * x3;
    dsum += pw;
  }
  // to fp32, then exact cross-half merge
  float a[8];
  a[0] = (float)acch0[0]; a[1] = (float)acch0[1];
  a[2] = (float)acch1[0]; a[3] = (float)acch1[1];
  a[4] = (float)acch2[0]; a[5] = (float)acch2[1];
  a[6] = (float)acch3[0]; a[7] = (float)acch3[1];
  float om = __shfl_xor(mh, 32);
  float od = __shfl_xor(dsum, 32);
  float nm = fmaxf(mh, om);
  float scs = __expf(mh - nm);
  float sco = __expf(om - nm);
  float d = dsum * scs + od * sco;
#pragma unroll
  for (int j = 0; j < 8; ++j) {
    float oa = __shfl_xor(a[j], 32);
    a[j] = a[j] * scs + oa * sco;
  }
  if (hf == 0) {
    float inv = 1.f / (d + 1e-16f);
    float4 ba = *(const float4*)(bias + c);
    float4 bb = *(const float4*)(bias + c + 4);
    float ob[8] = {ba.x, ba.y, ba.z, ba.w, bb.x, bb.y, bb.z, bb.w};
    half8 h8;
#pragma unroll
    for (int j = 0; j < 8; ++j) {
      float o = a[j] * inv + ob[j];
      o = (o > 0.f) ? o : expm1f(o);
      h8[j] = (_Float16)o;
    }
    *(half8*)(H16 + (size_t)node * HD + c) = h8;
  }
}

// ---------------- global sum: per-block partials ----------------
__global__ __launch_bounds__(256) void k_gsum(const _Float16* __restrict__ H,
    const int* __restrict__ batch, float* __restrict__ gpart, int* __restrict__ gcnt)
{
  __shared__ float flagf[RPB];
  __shared__ int scount;
  int b = blockIdx.x, t = threadIdx.x;
  int r0 = b * RPB;
  int nr = NN - r0; if (nr > RPB) nr = RPB; if (nr < 0) nr = 0;
  if (t == 0) scount = 0;
  __syncthreads();
  if (t < nr) {
    int ok = (batch[r0 + t] == 0) ? 1 : 0;
    flagf[t] = (float)ok;
    if (ok) atomicAdd(&scount, 1);
  }
  __syncthreads();
  float a0 = 0.f, a1 = 0.f, a2 = 0.f, a3 = 0.f;
  const _Float16* Hp = H + (size_t)r0 * HD + t;
  int r = 0;
  for (; r + 4 <= nr; r += 4) {
    float v0 = (float)Hp[(size_t)(r + 0) * HD];
    float v1 = (float)Hp[(size_t)(r + 1) * HD];
    float v2 = (float)Hp[(size_t)(r + 2) * HD];
    float v3 = (float)Hp[(size_t)(r + 3) * HD];
    a0 += v0 * flagf[r + 0]; a1 += v1 * flagf[r + 1];
    a2 += v2 * flagf[r + 2]; a3 += v3 * flagf[r + 3];
  }
  for (; r < nr; ++r) a0 += (float)Hp[(size_t)r * HD] * flagf[r];
  gpart[(size_t)b * HD + t] = (a0 + a1) + (a2 + a3);
  if (t == 0 && scount) atomicAdd(gcnt, scount);
}

// ---------------- tail head: sheet pool + geo1 (+gfin at blk SS) ----------------
__global__ __launch_bounds__(256) void k_tail1(const _Float16* __restrict__ h16,
    const int* __restrict__ sheet_idx, const float* __restrict__ sheet_feat,
    const float* __restrict__ geo_W1, const float* __restrict__ geo_b1,
    const float* __restrict__ geo_g1, const float* __restrict__ geo_be1,
    const float* __restrict__ gpart, const int* __restrict__ gcnt,
    float* __restrict__ gvec,
    _Float16* __restrict__ sh16, _Float16* __restrict__ g116)
{
  __shared__ float xf[FI];
  __shared__ int sidx[KS];
  __shared__ float red16[16];
  int s = blockIdx.x, t = threadIdx.x;

  if (s == SS) {
    float a0 = 0.f, a1 = 0.f, a2 = 0.f, a3 = 0.f;
    for (int b = 0; b < GSB; b += 4) {
      a0 += gpart[(size_t)b * HD + t];
      a1 += gpart[(size_t)(b + 1) * HD + t];
      a2 += gpart[(size_t)(b + 2) * HD + t];
      a3 += gpart[(size_t)(b + 3) * HD + t];
    }
    gvec[t] = ((a0 + a1) + (a2 + a3)) / (float)(*gcnt);
    return;
  }

  if (t < KS) sidx[t] = sheet_idx[s * KS + t];
  if (t >= 240) xf[t - 240] = sheet_feat[s * FI + (t - 240)];
  __syncthreads();

  float pa[8] = {};
#pragma unroll 2
  for (int r = 0; r < KS; r += 8) {
#pragma unroll
    for (int u = 0; u < 8; ++u)
      pa[u] += (float)h16[(size_t)sidx[r + u] * HD + t];
  }
  float shv = ((pa[0] + pa[1]) + (pa[2] + pa[3]) + (pa[4] + pa[5]) + (pa[6] + pa[7])) * (1.f / KS);
  sh16[(size_t)s * HD + t] = (_Float16)shv;

  float a = geo_b1[t];
#pragma unroll
  for (int k = 0; k < FI; ++k) a += xf[k] * geo_W1[k * HD + t];
  float g1 = ln_fast(a, t, 256, red16, geo_g1, geo_be1, true);
  g116[(size_t)s * HD + t] = (_Float16)g1;
}

// ---------------- MFMA tail stage with LN (NW waves, 16 rows/block) ----------------
template <int KD, int NW>
__global__ __launch_bounds__(NW * 64) void k_stageLN(
    const _Float16* __restrict__ X, const _Float16* __restrict__ WT,
    const float* __restrict__ b, const float* __restrict__ G,
    const float* __restrict__ Be, _Float16* __restrict__ Y,
    const float* __restrict__ W3, const float* __restrict__ b3,
    float* __restrict__ outq,
    const float* __restrict__ gvec,
    const float* __restrict__ dW1, const float* __restrict__ db1,
    const float* __restrict__ dg1, const float* __restrict__ dbe1,
    const float* __restrict__ dW2, const float* __restrict__ db2,
    float* __restrict__ outd)
{
  __shared__ float ps[NW * 16], ps2[NW * 16], pq[NW * 16];
  const int NCOL = NW * 64;
  int t = threadIdx.x;

  if (outd != nullptr && blockIdx.x == 16) {
    int w2 = t >> 6;
    float acc2 = db1[t];
    for (int k = 0; k < 256; ++k) acc2 += gvec[k] * dW1[(size_t)k * 128 + t];
    float s = wsum(acc2), s2v = wsum(acc2 * acc2);
    if ((t & 63) == 0) { ps[w2] = s; ps2[w2] = s2v; }
    __syncthreads();
    float S = ps[0] + ps[1], S2 = ps2[0] + ps2[1];
    float mu = S * (1.f / 128.f), var = S2 * (1.f / 128.f) - mu * mu;
    float hdv = fmaxf((acc2 - mu) * rsqrtf(var + 1e-5f) * dg1[t] + dbe1[t], 0.f);
    float o = wsum(hdv * dW2[t]);
    if ((t & 63) == 0) pq[w2] = o;
    __syncthreads();
    if (t == 0) outd[0] = pq[0] + pq[1] + db2[0];
    return;
  }

  int w = t >> 6, lane = t & 63;
  int arow = lane & 15, kg = lane >> 4;
  int m0 = blockIdx.x * 16;
  int col0 = w * 64;

  f32x4 acc[4] = {};
#pragma unroll
  for (int ks = 0; ks < KD / 32; ++ks) {
    half8 af = *(const half8*)(X + (size_t)(m0 + arow) * KD + ks * 32 + kg * 8);
#pragma unroll
    for (int n = 0; n < 4; ++n) {
      half8 bf = *(const half8*)(WT + (size_t)(col0 + n * 16 + arow) * KD + ks * 32 + kg * 8);
      acc[n] = __builtin_amdgcn_mfma_f32_16x16x32_f16(af, bf, acc[n], 0, 0, 0);
    }
  }
#pragma unroll
  for (int n = 0; n < 4; ++n) {
    float bv = b[col0 + n * 16 + arow];
#pragma unroll
    for (int r = 0; r < 4; ++r) acc[n][r] += bv;
  }
  float s[4] = {}, s2[4] = {};
#pragma unroll
  for (int n = 0; n < 4; ++n)
#pragma unroll
    for (int r = 0; r < 4; ++r) { float v = acc[n][r]; s[r] += v; s2[r] += v * v; }
#pragma unroll
  for (int d = 1; d < 16; d <<= 1)
#pragma unroll
    for (int r = 0; r < 4; ++r) { s[r] += __shfl_xor(s[r], d); s2[r] += __shfl_xor(s2[r], d); }
  if (arow == 0) {
#pragma unroll
    for (int r = 0; r < 4; ++r) {
      ps[w * 16 + kg * 4 + r] = s[r];
      ps2[w * 16 + kg * 4 + r] = s2[r];
    }
  }
  __syncthreads();
  float mu[4], rs[4];
#pragma unroll
  for (int r = 0; r < 4; ++r) {
    float S = 0.f, S2 = 0.f;
#pragma unroll
    for (int w2 = 0; w2 < NW; ++w2) { S += ps[w2 * 16 + kg * 4 + r]; S2 += ps2[w2 * 16 + kg * 4 + r]; }
    float m = S / NCOL;
    float var = S2 / NCOL - m * m;
    mu[r] = m; rs[r] = rsqrtf(var + 1e-5f);
  }
#pragma unroll
  for (int n = 0; n < 4; ++n) {
    int col = col0 + n * 16 + arow;
    float gv = G[col], bev = Be[col];
#pragma unroll
    for (int r = 0; r < 4; ++r)
      acc[n][r] = fmaxf((acc[n][r] - mu[r]) * rs[r] * gv + bev, 0.f);
  }
  if (Y) {
#pragma unroll
    for (int n = 0; n < 4; ++n) {
      int col = col0 + n * 16 + arow;
#pragma unroll
      for (int r = 0; r < 4; ++r)
        Y[(size_t)(m0 + kg * 4 + r) * NCOL + col] = (_Float16)acc[n][r];
    }
  }
  if (outq) {
    float p[4] = {};
#pragma unroll
    for (int n = 0; n < 4; ++n) {
      float w3 = W3[col0 + n * 16 + arow];
#pragma unroll
      for (int r = 0; r < 4; ++r) p[r] += acc[n][r] * w3;
    }
#pragma unroll
    for (int d = 1; d < 16; d <<= 1)
#pragma unroll
      for (int r = 0; r < 4; ++r) p[r] += __shfl_xor(p[r], d);
    if (arow == 0)
#pragma unroll
      for (int r = 0; r < 4; ++r) pq[w * 16 + kg * 4 + r] = p[r];
    __syncthreads();
    if (w == 0 && arow == 0) {
#pragma unroll
      for (int r = 0; r < 4; ++r) {
        float o = b3[0];
#pragma unroll
        for (int w2 = 0; w2 < NW; ++w2) o += pq[w2 * 16 + kg * 4 + r];
        outq[m0 + kg * 4 + r] = o;
      }
    }
  }
}

// ---------------- q/k/v stage (no LN): grid (16, 4, 3) ----------------
__global__ __launch_bounds__(64) void k_qkv(
    const _Float16* __restrict__ sh16, const _Float16* __restrict__ g216,
    const _Float16* __restrict__ Tq, const _Float16* __restrict__ Tk,
    const _Float16* __restrict__ Tv,
    const float* __restrict__ bq, const float* __restrict__ bk,
    const float* __restrict__ bv,
    _Float16* __restrict__ qb, _Float16* __restrict__ kb, _Float16* __restrict__ vb)
{
  int lane = threadIdx.x;
  int arow = lane & 15, kg = lane >> 4;
  int m0 = blockIdx.x * 16;
  int col0 = blockIdx.y * 64;
  int mat = blockIdx.z;
  const _Float16* X = (mat == 0) ? sh16 : g216;
  const _Float16* WT = (mat == 0) ? Tq : (mat == 1) ? Tk : Tv;
  const float* b = (mat == 0) ? bq : (mat == 1) ? bk : bv;
  _Float16* Y = (mat == 0) ? qb : (mat == 1) ? kb : vb;

  f32x4 acc[4] = {};
#pragma unroll
  for (int ks = 0; ks < 8; ++ks) {
    half8 af = *(const half8*)(X + (size_t)(m0 + arow) * 256 + ks * 32 + kg * 8);
#pragma unroll
    for (int n = 0; n < 4; ++n) {
      half8 bf = *(const half8*)(WT + (size_t)(col0 + n * 16 + arow) * 256 + ks * 32 + kg * 8);
      acc[n] = __builtin_amdgcn_mfma_f32_16x16x32_f16(af, bf, acc[n], 0, 0, 0);
    }
  }
#pragma unroll
  for (int n = 0; n < 4; ++n) {
    int col = col0 + n * 16 + arow;
    float bv2 = b[col];
#pragma unroll
    for (int r = 0; r < 4; ++r)
      Y[(size_t)(m0 + kg * 4 + r) * 256 + col] = (_Float16)(acc[n][r] + bv2);
  }
}

// ---------------- Wo stage + gv concat: grid (16, 4) ----------------
__global__ __launch_bounds__(64) void k_wo(
    const _Float16* __restrict__ pv16, const _Float16* __restrict__ To,
    const float* __restrict__ bo, const float* __restrict__ gvec,
    _Float16* __restrict__ hqin)
{
  int lane = threadIdx.x;
  int arow = lane & 15, kg = lane >> 4;
  int m0 = blockIdx.x * 16;
  int col0 = blockIdx.y * 64;

  f32x4 acc[4] = {};
#pragma unroll
  for (int ks = 0; ks < 8; ++ks) {
    half8 af = *(const half8*)(pv16 + (size_t)(m0 + arow) * 256 + ks * 32 + kg * 8);
#pragma unroll
    for (int n = 0; n < 4; ++n) {
      half8 bf = *(const half8*)(To + (size_t)(col0 + n * 16 + arow) * 256 + ks * 32 + kg * 8);
      acc[n] = __builtin_amdgcn_mfma_f32_16x16x32_f16(af, bf, acc[n], 0, 0, 0);
    }
  }
#pragma unroll
  for (int n = 0; n < 4; ++n) {
    int col = col0 + n * 16 + arow;
    float bv = bo[col];
    _Float16 gg = (_Float16)gvec[col];
#pragma unroll
    for (int r = 0; r < 4; ++r) {
      hqin[(size_t)(m0 + kg * 4 + r) * 512 + col] = (_Float16)(acc[n][r] + bv);
      hqin[(size_t)(m0 + kg * 4 + r) * 512 + 256 + col] = gg;
    }
  }
}

// ---------------- cross-attention per query row (1024 thr) ----------------
__global__ __launch_bounds__(1024) void k_attn(const _Float16* __restrict__ qb,
    const _Float16* __restrict__ kb, const _Float16* __restrict__ vb,
    _Float16* __restrict__ pv16)
{
  __shared__ float qv[HD];
  __shared__ float att[1024];
  __shared__ float red4[1024];
  __shared__ float redm[16];
  __shared__ float reds[16];
  int row = blockIdx.x, t = threadIdx.x;
  int w = t >> 6;

  if (t < 256) qv[t] = (float)qb[(size_t)row * HD + t];
  __syncthreads();

  int h = t >> 8, key = t & 255;
  float e = 0.f;
  {
    const half8* kr = (const half8*)(kb + (size_t)key * HD + h * HC);
    const float* qh = qv + h * HC;
#pragma unroll
    for (int d = 0; d < 8; ++d) {
      half8 kk = kr[d];
#pragma unroll
      for (int u = 0; u < 8; ++u) e += qh[d * 8 + u] * (float)kk[u];
    }
    e *= 0.125f;
  }
  float wm = e;
#pragma unroll
  for (int d = 1; d < 64; d <<= 1) wm = fmaxf(wm, __shfl_xor(wm, d));
  if ((t & 63) == 0) redm[w] = wm;
  __syncthreads();
  float mx = fmaxf(fmaxf(redm[4 * h], redm[4 * h + 1]), fmaxf(redm[4 * h + 2], redm[4 * h + 3]));
  float pw = __expf(e - mx);
  float ws = wsum(pw);
  if ((t & 63) == 0) reds[w] = ws;
  att[t] = pw;
  __syncthreads();

  int kq = t >> 8, j = t & 255;
  int hj = j >> 6;
  float p = 0.f;
  const float* arow = att + hj * 256 + kq * 64;
  const _Float16* vcol = vb + (size_t)(kq * 64) * HD + j;
  for (int k = 0; k < 64; ++k)
    p += arow[k] * (float)vcol[(size_t)k * HD];
  red4[t] = p;
  __syncthreads();
  if (t < 256) {
    int hh = t >> 6;
    float dsum = reds[4 * hh] + reds[4 * hh + 1] + reds[4 * hh + 2] + reds[4 * hh + 3];
    float pv = (red4[t] + red4[256 + t] + red4[512 + t] + red4[768 + t]) / dsum;
    pv16[(size_t)row * HD + t] = (_Float16)pv;
  }
}

// =====================================================================
extern "C" void kernel_launch(void* const* d_in, const int* in_sizes, int n_in,
                              void* d_out, int out_size, void* d_ws, size_t ws_size,
                              hipStream_t stream) {
  const float* x      = (const float*)d_in[0];
  const int*   ei     = (const int*)d_in[1];
  const int*   batch  = (const int*)d_in[2];
  const int*   sheet_idx = (const int*)d_in[3];
  const float* sheet_feat = (const float*)d_in[4];
  const float* pre_W  = (const float*)d_in[5];
  const float* pre_b  = (const float*)d_in[6];
  const float* gat_Wl = (const float*)d_in[7];
  const float* gat_Wr = (const float*)d_in[8];
  const float* gat_att = (const float*)d_in[9];
  const float* gat_b  = (const float*)d_in[10];
  const float* geo_W1 = (const float*)d_in[11];
  const float* geo_b1 = (const float*)d_in[12];
  const float* geo_g1 = (const float*)d_in[13];
  const float* geo_be1 = (const float*)d_in[14];
  const float* geo_W2 = (const float*)d_in[15];
  const float* geo_b2 = (const float*)d_in[16];
  const float* geo_g2 = (const float*)d_in[17];
  const float* geo_be2 = (const float*)d_in[18];
  const float* ca_Wq = (const float*)d_in[19];
  const float* ca_bq = (const float*)d_in[20];
  const float* ca_Wk = (const float*)d_in[21];
  const float* ca_bk = (const float*)d_in[22];
  const float* ca_Wv = (const float*)d_in[23];
  const float* ca_bv = (const float*)d_in[24];
  const float* ca_Wo = (const float*)d_in[25];
  const float* ca_bo = (const float*)d_in[26];
  const float* q_W1 = (const float*)d_in[27];
  const float* q_b1 = (const float*)d_in[28];
  const float* q_g1 = (const float*)d_in[29];
  const float* q_be1 = (const float*)d_in[30];
  const float* q_W2 = (const float*)d_in[31];
  const float* q_b2 = (const float*)d_in[32];
  const float* q_g2 = (const float*)d_in[33];
  const float* q_be2 = (const float*)d_in[34];
  const float* q_W3 = (const float*)d_in[35];
  const float* q_b3 = (const float*)d_in[36];
  const float* d_W1 = (const float*)d_in[37];
  const float* d_b1 = (const float*)d_in[38];
  const float* d_g1 = (const float*)d_in[39];
  const float* d_be1 = (const float*)d_in[40];
  const float* d_W2 = (const float*)d_in[41];
  const float* d_b2 = (const float*)d_in[42];

  char* wsb = (char*)d_ws;
  auto alloc = [&](size_t bytes) { char* p = wsb; wsb += (bytes + 255) & ~(size_t)255; return p; };

  _Float16* h16  = (_Float16*)alloc((size_t)MPAD * HD * 2);
  _Float16* Xl16 = (_Float16*)alloc((size_t)MPAD * HD * 2);
  _Float16* Xr16 = (_Float16*)alloc((size_t)MPAD * HD * 2);
  _Float16* WT   = (_Float16*)alloc((size_t)6 * HD * HD * 2);
  _Float16* Tgeo2 = (_Float16*)alloc((size_t)HD * HD * 2);
  _Float16* Tq   = (_Float16*)alloc((size_t)HD * HD * 2);
  _Float16* Tk   = (_Float16*)alloc((size_t)HD * HD * 2);
  _Float16* Tv   = (_Float16*)alloc((size_t)HD * HD * 2);
  _Float16* To   = (_Float16*)alloc((size_t)HD * HD * 2);
  _Float16* Tq1  = (_Float16*)alloc((size_t)HD * 512 * 2);
  _Float16* Tq2  = (_Float16*)alloc((size_t)128 * HD * 2);
  _Float16* sh16 = (_Float16*)alloc((size_t)SS * HD * 2);
  _Float16* g116 = (_Float16*)alloc((size_t)SS * HD * 2);
  _Float16* g216 = (_Float16*)alloc((size_t)SS * HD * 2);
  _Float16* qb16 = (_Float16*)alloc((size_t)SS * HD * 2);
  _Float16* kb16 = (_Float16*)alloc((size_t)SS * HD * 2);
  _Float16* vb16 = (_Float16*)alloc((size_t)SS * HD * 2);
  _Float16* pv16 = (_Float16*)alloc((size_t)SS * HD * 2);
  _Float16* hqin16 = (_Float16*)alloc((size_t)SS * 512 * 2);
  _Float16* hq116 = (_Float16*)alloc((size_t)SS * HD * 2);
  float* gpart   = (float*)alloc((size_t)GSB * HD * 4);
  float* gvec    = (float*)alloc(256 * 4);
  int* cnt       = (int*)alloc((size_t)NN * 4);
  int* rowptr    = (int*)alloc((size_t)(NN + 1) * 4);
  int* wptr      = (int*)alloc((size_t)NN * 4);
  int* csr_src   = (int*)alloc((size_t)(ETOT + 8) * 4);
  int* btot      = (int*)alloc((size_t)SCB * 4);
  int* boff      = (int*)alloc((size_t)SCB * 4);
  int* gcnt      = (int*)alloc(4);

  float* out_q = (float*)d_out;        // [256]
  float* out_d = out_q + SS;           // [1]

  k_init<<<118, 256, 0, stream>>>(cnt, gcnt, h16 + (size_t)NN * HD, csr_src + ETOT);

  // CSR build
  k_count<<<(ETOT + 255) / 256, 256, 0, stream>>>(ei, cnt);
  k_scanA<<<SCB, 256, 0, stream>>>(cnt, rowptr, btot);
  k_scanB<<<1, 128, 0, stream>>>(btot, boff, rowptr);
  k_scanC<<<SCB, 256, 0, stream>>>(rowptr, boff, wptr);
  k_scatter<<<(ETOT + 255) / 256, 256, 0, stream>>>(ei, wptr, csr_src);

  // weights + pre-transform
  k_wconvAll<<<3200, 256, 0, stream>>>(gat_Wl, gat_Wr, geo_W2, ca_Wq, ca_Wk, ca_Wv,
                                       ca_Wo, q_W1, q_W2,
                                       WT, Tgeo2, Tq, Tk, Tv, To, Tq1, Tq2);
  k_pre<<<NN / 8, 256, 0, stream>>>(x, pre_W, pre_b, h16);

  // GAT layers
  dim3 ggrid(MPAD / 128, 2);
  for (int l = 0; l < NL; ++l) {
    k_gemm16<<<ggrid, 512, 0, stream>>>(h16, WT + (size_t)l * 2 * HD * HD, Xl16, Xr16);
    k_edgeagg<<<(NN + 3) / 4, 256, 0, stream>>>(Xl16, Xr16, gat_att + l * NH * CH,
                                                gat_b + l * HD, rowptr, csr_src, h16);
  }

  // global mean partials
  k_gsum<<<GSB, 256, 0, stream>>>(h16, batch, gpart, gcnt);

  // tail (+gfin folded into block SS)
  k_tail1<<<SS + 1, 256, 0, stream>>>(h16, sheet_idx, sheet_feat,
      geo_W1, geo_b1, geo_g1, geo_be1, gpart, gcnt, gvec, sh16, g116);
  k_stageLN<256, 4><<<16, 256, 0, stream>>>(g116, Tgeo2, geo_b2, geo_g2, geo_be2,
      g216, nullptr, nullptr, nullptr,
      nullptr, nullptr, nullptr, nullptr, nullptr, nullptr, nullptr, nullptr);
  dim3 qkvg(16, 4, 3);
  k_qkv<<<qkvg, 64, 0, stream>>>(sh16, g216, Tq, Tk, Tv, ca_bq, ca_bk, ca_bv,
                                 qb16, kb16, vb16);
  k_attn<<<SS, 1024, 0, stream>>>(qb16, kb16, vb16, pv16);
  dim3 wog(16, 4);
  k_wo<<<wog, 64, 0, stream>>>(pv16, To, ca_bo, gvec, hqin16);
  k_stageLN<512, 4><<<16, 256, 0, stream>>>(hqin16, Tq1, q_b1, q_g1, q_be1,
      hq116, nullptr, nullptr, nullptr,
      nullptr, nullptr, nullptr, nullptr, nullptr, nullptr, nullptr, nullptr);
  // hq2 + qval (blocks 0..15) + done head (block 16)
  k_stageLN<256, 2><<<17, 128, 0, stream>>>(hq116, Tq2, q_b2, q_g2, q_be2,
      nullptr, q_W3, q_b3, out_q,
      gvec, d_W1, d_b1, d_g1, d_be1, d_W2, d_b2, out_d);
}

// Round 12
// 286.119 us; speedup vs baseline: 1.4365x; 1.0602x over previous
//
#include <hip/hip_runtime.h>
#include <hip/hip_bf16.h>
#include <stdint.h>

#define NN 30000
#define MPAD 30080
#define FI 16
#define EE 300000
#define ETOT (EE + NN)
#define HD 256
#define NH 8
#define CH 32
#define NL 3
#define SS 256
#define KS 128
#define NHC 4
#define HC 64
#define GSB 256
#define RPB 118
#define SCB 118

typedef _Float16 half8 __attribute__((ext_vector_type(8)));
typedef _Float16 half4v __attribute__((ext_vector_type(4)));
typedef _Float16 half2v __attribute__((ext_vector_type(2)));
typedef float f32x4 __attribute__((ext_vector_type(4)));

// ---------------- wave helpers ----------------
__device__ __forceinline__ float wsum(float v) {
#pragma unroll
  for (int d = 1; d < 64; d <<= 1) v += __shfl_xor(v, d);
  return v;
}

__device__ __forceinline__ half2v mk2(_Float16 a, _Float16 b) {
  half2v r; r[0] = a; r[1] = b; return r;
}

__device__ __forceinline__ half2v h2max(half2v a, half2v b) {
#if __has_builtin(__builtin_elementwise_max)
  return __builtin_elementwise_max(a, b);
#else
  half2v r; r[0] = a[0] > b[0] ? a[0] : b[0]; r[1] = a[1] > b[1] ? a[1] : b[1];
  return r;
#endif
}

__device__ __forceinline__ float h2dot(half2v a, half2v b, float c) {
#if __has_builtin(__builtin_amdgcn_fdot2)
  return __builtin_amdgcn_fdot2(a, b, c, false);
#else
  return c + (float)a[0] * (float)b[0] + (float)a[1] * (float)b[1];
#endif
}

// LN over n channels, 256 threads, t<n holds a. 2 barriers.
__device__ __forceinline__ float ln_fast(float a, int t, int n, float* red16,
    const float* __restrict__ G, const float* __restrict__ Be, bool relu)
{
  float av = (t < n) ? a : 0.f;
  float s = wsum(av), s2 = wsum(av * av);
  if ((t & 63) == 0) { red16[t >> 6] = s; red16[8 + (t >> 6)] = s2; }
  __syncthreads();
  float sum = red16[0] + red16[1] + red16[2] + red16[3];
  float sq  = red16[8] + red16[9] + red16[10] + red16[11];
  float mu = sum / n;
  float var = sq / n - mu * mu;
  float o = 0.f;
  if (t < n) {
    o = (a - mu) * rsqrtf(var + 1e-5f) * G[t] + Be[t];
    if (relu) o = fmaxf(o, 0.f);
  }
  __syncthreads();
  return o;
}

// ---------------- weights transpose+convert + init (blocks 3200+) ----------------
__global__ __launch_bounds__(256) void k_wconvAll(
    const float* __restrict__ Wl, const float* __restrict__ Wr,
    const float* __restrict__ geo_W2, const float* __restrict__ ca_Wq,
    const float* __restrict__ ca_Wk, const float* __restrict__ ca_Wv,
    const float* __restrict__ ca_Wo, const float* __restrict__ q_W1,
    const float* __restrict__ q_W2,
    _Float16* __restrict__ WT,
    _Float16* __restrict__ Tgeo2, _Float16* __restrict__ Tq,
    _Float16* __restrict__ Tk, _Float16* __restrict__ Tv,
    _Float16* __restrict__ To, _Float16* __restrict__ Tq1,
    _Float16* __restrict__ Tq2,
    int* __restrict__ cnt, int* __restrict__ gcnt,
    _Float16* __restrict__ h16pad, int* __restrict__ csr_pad)
{
  int b = blockIdx.x, t = threadIdx.x;
  if (b >= 3200) {
    int i = (b - 3200) * 256 + t;
    if (i < NN) cnt[i] = 0;
    if (i == 0) gcnt[0] = 0;
    if (i < 8) csr_pad[i] = 0;
    if (i < (MPAD - NN) * HD) h16pad[i] = (_Float16)0.f;
    return;
  }
  if (b < 1536) {
    int m = b >> 8;
    int n = b & 255;
    int l = m >> 1;
    const float* W = (m & 1) ? (Wr + (size_t)l * HD * HD) : (Wl + (size_t)l * HD * HD);
    WT[((size_t)m * HD + n) * HD + t] = (_Float16)W[t * HD + n];
    return;
  }
  b -= 1536;
  if (b < 1280) {
    int seg = b >> 8;
    int n = b & 255;
    const float* src = (seg == 0) ? geo_W2 : (seg == 1) ? ca_Wq : (seg == 2) ? ca_Wk
                     : (seg == 3) ? ca_Wv : ca_Wo;
    _Float16* dst = (seg == 0) ? Tgeo2 : (seg == 1) ? Tq : (seg == 2) ? Tk
                  : (seg == 3) ? Tv : To;
    dst[(size_t)n * 256 + t] = (_Float16)src[(size_t)t * 256 + n];
  } else if (b < 1536) {
    int n = b - 1280;
    Tq1[(size_t)n * 512 + t]       = (_Float16)q_W1[(size_t)t * 256 + n];
    Tq1[(size_t)n * 512 + 256 + t] = (_Float16)q_W1[(size_t)(256 + t) * 256 + n];
  } else {
    int n = b - 1536;
    Tq2[(size_t)n * 256 + t] = (_Float16)q_W2[(size_t)t * 128 + n];
  }
}

// ---------------- pre-transform ----------------
__global__ __launch_bounds__(256) void k_pre(const float* __restrict__ x,
    const float* __restrict__ W, const float* __restrict__ b,
    _Float16* __restrict__ H16)
{
  __shared__ float Ws[FI][HD];
  __shared__ float xs[8][FI];
  int r0 = blockIdx.x * 8;
  int t = threadIdx.x;
  for (int i = t; i < FI * HD; i += 256) Ws[i >> 8][i & 255] = W[i];
  if (t < 8 * FI) xs[t >> 4][t & 15] = x[(size_t)(r0 + (t >> 4)) * FI + (t & 15)];
  __syncthreads();
  float bj = b[t];
  for (int r = 0; r < 8; ++r) {
    float acc = bj;
#pragma unroll
    for (int k = 0; k < FI; ++k) acc += xs[r][k] * Ws[k][t];
    H16[(size_t)(r0 + r) * HD + t] = (_Float16)acc;
  }
}

// ---------------- CSR build ----------------
__global__ __launch_bounds__(256) void k_count(const int* __restrict__ ei, int* __restrict__ cnt)
{
  int i = blockIdx.x * 256 + threadIdx.x;
  if (i >= ETOT) return;
  int dst = (i < EE) ? ei[EE + i] : (i - EE);
  atomicAdd(&cnt[dst], 1);
}

__global__ __launch_bounds__(256) void k_scanA(const int* __restrict__ cnt,
    int* __restrict__ rowptr, int* __restrict__ btot)
{
  __shared__ int wt[4];
  int b = blockIdx.x, t = threadIdx.x;
  int i = b * 256 + t;
  int v = (i < NN) ? cnt[i] : 0;
  int lane = t & 63, w = t >> 6;
  int s = v;
#pragma unroll
  for (int d = 1; d < 64; d <<= 1) {
    int u = __shfl_up(s, d);
    if (lane >= d) s += u;
  }
  if (lane == 63) wt[w] = s;
  __syncthreads();
  int off = 0;
  for (int k = 0; k < w; ++k) off += wt[k];
  if (i < NN) rowptr[i] = off + s - v;
  if (t == 255) btot[b] = off + s;
}

__global__ __launch_bounds__(128) void k_scanB(const int* __restrict__ btot,
    int* __restrict__ boff, int* __restrict__ rowptr)
{
  __shared__ int wt[2];
  int t = threadIdx.x;
  int v = (t < SCB) ? btot[t] : 0;
  int lane = t & 63, w = t >> 6;
  int s = v;
#pragma unroll
  for (int d = 1; d < 64; d <<= 1) {
    int u = __shfl_up(s, d);
    if (lane >= d) s += u;
  }
  if (lane == 63) wt[w] = s;
  __syncthreads();
  int off = (w == 1) ? wt[0] : 0;
  if (t < SCB) boff[t] = off + s - v;
  if (t == 127) rowptr[NN] = wt[0] + wt[1];
}

__global__ __launch_bounds__(256) void k_scanC(int* __restrict__ rowptr,
    const int* __restrict__ boff, int* __restrict__ wptr)
{
  int b = blockIdx.x, t = threadIdx.x;
  int i = b * 256 + t;
  if (i < NN) {
    int r = rowptr[i] + boff[b];
    rowptr[i] = r;
    wptr[i] = r;
  }
}

// csr_src stores src*HD (pre-scaled element offset)
__global__ __launch_bounds__(256) void k_scatter(const int* __restrict__ ei,
    int* __restrict__ wptr, int* __restrict__ csr_src)
{
  int i = blockIdx.x * 256 + threadIdx.x;
  if (i >= ETOT) return;
  int src = (i < EE) ? ei[i] : (i - EE);
  int dst = (i < EE) ? ei[EE + i] : (i - EE);
  int pos = atomicAdd(&wptr[dst], 1);
  csr_src[pos] = src * HD;
}

// ---------------- fp16 MFMA GEMM: 64x512 tile (both mats), 8 waves ----------------
// grid (MPAD/64). A staged once; wave w owns cols w*64..w*64+63 of [Wl|Wr].
#define BKG 64
__global__ __launch_bounds__(512) void k_gemm16(const _Float16* __restrict__ A,
    const _Float16* __restrict__ WT,    // layer base: [512 rows][256 k]
    _Float16* __restrict__ Xl, _Float16* __restrict__ Xr)
{
  __shared__ __align__(16) _Float16 As[64 * BKG];    // 8KB
  __shared__ __align__(16) _Float16 Bs[512 * BKG];   // 64KB
  int t = threadIdx.x;
  int w = t >> 6, lane = t & 63;
  int row0 = blockIdx.x * 64;

  f32x4 acc[4][4] = {};

  for (int k0 = 0; k0 < HD; k0 += BKG) {
    // stage A: 512 slots, 1 per thread
    {
      int row = t >> 3, s = t & 7;
      int g = s ^ (row & 7);
      __builtin_amdgcn_global_load_lds(
        (const __attribute__((address_space(1))) void*)(A + (size_t)(row0 + row) * HD + k0 + g * 8),
        (__attribute__((address_space(3))) void*)((char*)As + w * 1024),
        16, 0, 0);
    }
    // stage B: 4096 slots, 8 per thread
#pragma unroll
    for (int i = 0; i < 8; ++i) {
      int p = i * 512 + t;
      int row = p >> 3, s = p & 7;
      int g = s ^ (row & 7);
      __builtin_amdgcn_global_load_lds(
        (const __attribute__((address_space(1))) void*)(WT + (size_t)row * HD + k0 + g * 8),
        (__attribute__((address_space(3))) void*)((char*)Bs + (i * 8 + w) * 1024),
        16, 0, 0);
    }
    __syncthreads();
#pragma unroll
    for (int ks = 0; ks < 2; ++ks) {
      half8 af[4], bfr[4];
      int kslot = ks * 4 + (lane >> 4);
#pragma unroll
      for (int mi = 0; mi < 4; ++mi) {
        int rl = mi * 16 + (lane & 15);
        int ps = kslot ^ (rl & 7);
        af[mi] = *(const half8*)((const char*)As + rl * 128 + ps * 16);
      }
#pragma unroll
      for (int ni = 0; ni < 4; ++ni) {
        int nl = w * 64 + ni * 16 + (lane & 15);
        int ps = kslot ^ (nl & 7);
        bfr[ni] = *(const half8*)((const char*)Bs + nl * 128 + ps * 16);
      }
#pragma unroll
      for (int mi = 0; mi < 4; ++mi)
#pragma unroll
        for (int ni = 0; ni < 4; ++ni)
          acc[mi][ni] = __builtin_amdgcn_mfma_f32_16x16x32_f16(af[mi], bfr[ni], acc[mi][ni], 0, 0, 0);
    }
    __syncthreads();
  }
  int crow = (lane >> 4) * 4;
  int ccol = lane & 15;
  _Float16* Out = (w < 4) ? Xl : Xr;
  int cbase = (w < 4) ? (w * 64) : ((w - 4) * 64);
#pragma unroll
  for (int mi = 0; mi < 4; ++mi)
#pragma unroll
    for (int ni = 0; ni < 4; ++ni) {
      size_t base_r = row0 + mi * 16 + crow;
      int c = cbase + ni * 16 + ccol;
#pragma unroll
      for (int r = 0; r < 4; ++r)
        Out[(base_r + r) * HD + c] = (_Float16)acc[mi][ni][r];
    }
}

// ---------------- fused edge + online-softmax agg ----------------
// one wave per node; lanes 0-31/32-63 = interleaved edge streams, independent
// online softmax merged at end. 8 ch/lane, 3-deep prefetch, fp16 pk accum.
// csr_src holds src*HD.
__global__ __launch_bounds__(256) void k_edgeagg(const _Float16* __restrict__ Xl,
    const _Float16* __restrict__ Xr, const float* __restrict__ attw,
    const float* __restrict__ bias, const int* __restrict__ rowptr,
    const int* __restrict__ csr_src, _Float16* __restrict__ H16)
{
  int node = blockIdx.x * 4 + (threadIdx.x >> 6);
  int lane = threadIdx.x & 63;
  if (node >= NN) return;
  int st = rowptr[node], en = rowptr[node + 1];
  int n = en - st;
  int hf = lane >> 5, sl = lane & 31;
  int c = sl * 8;
  half8 xrv = *(const half8*)(Xr + (size_t)node * HD + c);
  float4 wa = *(const float4*)(attw + c);
  float4 wb = *(const float4*)(attw + c + 4);
  half2v w0 = mk2((_Float16)wa.x, (_Float16)wa.y);
  half2v w1 = mk2((_Float16)wa.z, (_Float16)wa.w);
  half2v w2 = mk2((_Float16)wb.x, (_Float16)wb.y);
  half2v w3 = mk2((_Float16)wb.z, (_Float16)wb.w);
  half2v r0 = mk2(xrv[0], xrv[1]), r1 = mk2(xrv[2], xrv[3]);
  half2v r2 = mk2(xrv[4], xrv[5]), r3 = mk2(xrv[6], xrv[7]);
  half2v c02 = mk2((_Float16)0.2f, (_Float16)0.2f);

  float mh = -1e30f, dsum = 0.f;
  half2v acch0 = {}, acch1 = {}, acch2 = {}, acch3 = {};
  int trips = (n + 1) >> 1;
  int base = st + hf;

  half8 b0 = *(const half8*)(Xl + (size_t)csr_src[base] + c);
  half8 b1 = *(const half8*)(Xl + (size_t)csr_src[base + 2] + c);
  half8 b2 = *(const half8*)(Xl + (size_t)csr_src[base + 4] + c);

  for (int it = 0; it < trips; ++it) {
    bool valid = (2 * it + hf) < n;
    half8 xc = b0;
    b0 = b1; b1 = b2;
    {
      int noff = csr_src[base + 2 * (it + 3)];   // stays within pad for last node
      b2 = *(const half8*)(Xl + (size_t)noff + c);
    }
    half2v x0 = mk2(xc[0], xc[1]), x1 = mk2(xc[2], xc[3]);
    half2v x2 = mk2(xc[4], xc[5]), x3 = mk2(xc[6], xc[7]);
    half2v s0 = x0 + r0, s1 = x1 + r1, s2 = x2 + r2, s3 = x3 + r3;
    half2v m0 = h2max(s0, s0 * c02);
    half2v m1 = h2max(s1, s1 * c02);
    half2v m2 = h2max(s2, s2 * c02);
    half2v m3 = h2max(s3, s3 * c02);
    float eA = h2dot(m1, w1, h2dot(m0, w0, 0.f));
    float eB = h2dot(m3, w3, h2dot(m2, w2, 0.f));
    float e = eA + eB;
    e += __shfl_xor(e, 1);
    e += __shfl_xor(e, 2);
    e = valid ? e : -1e30f;
    // defer-max THR=4 so deferred weights <= e^4 (fp16 accum overflow-safe)
    if (__any(e > mh + 4.f)) {
      float nm = fmaxf(mh, e);
      float sc = __expf(mh - nm);
      _Float16 sch16 = (_Float16)sc;
      half2v sch = mk2(sch16, sch16);
      acch0 *= sch; acch1 *= sch; acch2 *= sch; acch3 *= sch;
      dsum *= sc;
      mh = nm;
    }
    float pw = valid ? __expf(e - mh) : 0.f;
    _Float16 pwh16 = (_Float16)pw;
    half2v pwh = mk2(pwh16, pwh16);
    acch0 += pwh * x0;
    acch1 += pwh * x1;
    acch2 += pwh * x2;
    acch3 += pwh * x3;
    dsum += pw;
  }
  // to fp32, then exact cross-half merge
  float a[8];
  a[0] = (float)acch0[0]; a[1] = (float)acch0[1];
  a[2] = (float)acch1[0]; a[3] = (float)acch1[1];
  a[4] = (float)acch2[0]; a[5] = (float)acch2[1];
  a[6] = (float)acch3[0]; a[7] = (float)acch3[1];
  float om = __shfl_xor(mh, 32);
  float od = __shfl_xor(dsum, 32);
  float nm = fmaxf(mh, om);
  float scs = __expf(mh - nm);
  float sco = __expf(om - nm);
  float d = dsum * scs + od * sco;
#pragma unroll
  for (int j = 0; j < 8; ++j) {
    float oa = __shfl_xor(a[j], 32);
    a[j] = a[j] * scs + oa * sco;
  }
  if (hf == 0) {
    float inv = 1.f / (d + 1e-16f);
    float4 ba = *(const float4*)(bias + c);
    float4 bb = *(const float4*)(bias + c + 4);
    float ob[8] = {ba.x, ba.y, ba.z, ba.w, bb.x, bb.y, bb.z, bb.w};
    half8 h8;
#pragma unroll
    for (int j = 0; j < 8; ++j) {
      float o = a[j] * inv + ob[j];
      o = (o > 0.f) ? o : (__expf(o) - 1.f);   // fast ELU
      h8[j] = (_Float16)o;
    }
    *(half8*)(H16 + (size_t)node * HD + c) = h8;
  }
}

// ---------------- global sum: per-block partials ----------------
__global__ __launch_bounds__(256) void k_gsum(const _Float16* __restrict__ H,
    const int* __restrict__ batch, float* __restrict__ gpart, int* __restrict__ gcnt)
{
  __shared__ float flagf[RPB];
  __shared__ int scount;
  int b = blockIdx.x, t = threadIdx.x;
  int r0 = b * RPB;
  int nr = NN - r0; if (nr > RPB) nr = RPB; if (nr < 0) nr = 0;
  if (t == 0) scount = 0;
  __syncthreads();
  if (t < nr) {
    int ok = (batch[r0 + t] == 0) ? 1 : 0;
    flagf[t] = (float)ok;
    if (ok) atomicAdd(&scount, 1);
  }
  __syncthreads();
  float a0 = 0.f, a1 = 0.f, a2 = 0.f, a3 = 0.f;
  const _Float16* Hp = H + (size_t)r0 * HD + t;
  int r = 0;
  for (; r + 4 <= nr; r += 4) {
    float v0 = (float)Hp[(size_t)(r + 0) * HD];
    float v1 = (float)Hp[(size_t)(r + 1) * HD];
    float v2 = (float)Hp[(size_t)(r + 2) * HD];
    float v3 = (float)Hp[(size_t)(r + 3) * HD];
    a0 += v0 * flagf[r + 0]; a1 += v1 * flagf[r + 1];
    a2 += v2 * flagf[r + 2]; a3 += v3 * flagf[r + 3];
  }
  for (; r < nr; ++r) a0 += (float)Hp[(size_t)r * HD] * flagf[r];
  gpart[(size_t)b * HD + t] = (a0 + a1) + (a2 + a3);
  if (t == 0 && scount) atomicAdd(gcnt, scount);
}

// ---------------- tail head: sheet pool + geo1 (+gfin at blk SS) ----------------
__global__ __launch_bounds__(256) void k_tail1(const _Float16* __restrict__ h16,
    const int* __restrict__ sheet_idx, const float* __restrict__ sheet_feat,
    const float* __restrict__ geo_W1, const float* __restrict__ geo_b1,
    const float* __restrict__ geo_g1, const float* __restrict__ geo_be1,
    const float* __restrict__ gpart, const int* __restrict__ gcnt,
    float* __restrict__ gvec,
    _Float16* __restrict__ sh16, _Float16* __restrict__ g116)
{
  __shared__ float xf[FI];
  __shared__ int sidx[KS];
  __shared__ float red16[16];
  int s = blockIdx.x, t = threadIdx.x;

  if (s == SS) {
    float a0 = 0.f, a1 = 0.f, a2 = 0.f, a3 = 0.f;
    for (int b = 0; b < GSB; b += 4) {
      a0 += gpart[(size_t)b * HD + t];
      a1 += gpart[(size_t)(b + 1) * HD + t];
      a2 += gpart[(size_t)(b + 2) * HD + t];
      a3 += gpart[(size_t)(b + 3) * HD + t];
    }
    gvec[t] = ((a0 + a1) + (a2 + a3)) / (float)(*gcnt);
    return;
  }

  if (t < KS) sidx[t] = sheet_idx[s * KS + t];
  if (t >= 240) xf[t - 240] = sheet_feat[s * FI + (t - 240)];
  __syncthreads();

  float pa[8] = {};
#pragma unroll 2
  for (int r = 0; r < KS; r += 8) {
#pragma unroll
    for (int u = 0; u < 8; ++u)
      pa[u] += (float)h16[(size_t)sidx[r + u] * HD + t];
  }
  float shv = ((pa[0] + pa[1]) + (pa[2] + pa[3]) + (pa[4] + pa[5]) + (pa[6] + pa[7])) * (1.f / KS);
  sh16[(size_t)s * HD + t] = (_Float16)shv;

  float a = geo_b1[t];
#pragma unroll
  for (int k = 0; k < FI; ++k) a += xf[k] * geo_W1[k * HD + t];
  float g1 = ln_fast(a, t, 256, red16, geo_g1, geo_be1, true);
  g116[(size_t)s * HD + t] = (_Float16)g1;
}

// ---------------- MFMA tail stage with LN (NW waves, 16 rows/block) ----------------
template <int KD, int NW>
__global__ __launch_bounds__(NW * 64) void k_stageLN(
    const _Float16* __restrict__ X, const _Float16* __restrict__ WT,
    const float* __restrict__ b, const float* __restrict__ G,
    const float* __restrict__ Be, _Float16* __restrict__ Y,
    const float* __restrict__ W3, const float* __restrict__ b3,
    float* __restrict__ outq,
    const float* __restrict__ gvec,
    const float* __restrict__ dW1, const float* __restrict__ db1,
    const float* __restrict__ dg1, const float* __restrict__ dbe1,
    const float* __restrict__ dW2, const float* __restrict__ db2,
    float* __restrict__ outd)
{
  __shared__ float ps[NW * 16], ps2[NW * 16], pq[NW * 16];
  const int NCOL = NW * 64;
  int t = threadIdx.x;

  if (outd != nullptr && blockIdx.x == 16) {
    int w2 = t >> 6;
    float acc2 = db1[t];
    for (int k = 0; k < 256; ++k) acc2 += gvec[k] * dW1[(size_t)k * 128 + t];
    float s = wsum(acc2), s2v = wsum(acc2 * acc2);
    if ((t & 63) == 0) { ps[w2] = s; ps2[w2] = s2v; }
    __syncthreads();
    float S = ps[0] + ps[1], S2 = ps2[0] + ps2[1];
    float mu = S * (1.f / 128.f), var = S2 * (1.f / 128.f) - mu * mu;
    float hdv = fmaxf((acc2 - mu) * rsqrtf(var + 1e-5f) * dg1[t] + dbe1[t], 0.f);
    float o = wsum(hdv * dW2[t]);
    if ((t & 63) == 0) pq[w2] = o;
    __syncthreads();
    if (t == 0) outd[0] = pq[0] + pq[1] + db2[0];
    return;
  }

  int w = t >> 6, lane = t & 63;
  int arow = lane & 15, kg = lane >> 4;
  int m0 = blockIdx.x * 16;
  int col0 = w * 64;

  f32x4 acc[4] = {};
#pragma unroll
  for (int ks = 0; ks < KD / 32; ++ks) {
    half8 af = *(const half8*)(X + (size_t)(m0 + arow) * KD + ks * 32 + kg * 8);
#pragma unroll
    for (int n = 0; n < 4; ++n) {
      half8 bf = *(const half8*)(WT + (size_t)(col0 + n * 16 + arow) * KD + ks * 32 + kg * 8);
      acc[n] = __builtin_amdgcn_mfma_f32_16x16x32_f16(af, bf, acc[n], 0, 0, 0);
    }
  }
#pragma unroll
  for (int n = 0; n < 4; ++n) {
    float bv = b[col0 + n * 16 + arow];
#pragma unroll
    for (int r = 0; r < 4; ++r) acc[n][r] += bv;
  }
  float s[4] = {}, s2[4] = {};
#pragma unroll
  for (int n = 0; n < 4; ++n)
#pragma unroll
    for (int r = 0; r < 4; ++r) { float v = acc[n][r]; s[r] += v; s2[r] += v * v; }
#pragma unroll
  for (int d = 1; d < 16; d <<= 1)
#pragma unroll
    for (int r = 0; r < 4; ++r) { s[r] += __shfl_xor(s[r], d); s2[r] += __shfl_xor(s2[r], d); }
  if (arow == 0) {
#pragma unroll
    for (int r = 0; r < 4; ++r) {
      ps[w * 16 + kg * 4 + r] = s[r];
      ps2[w * 16 + kg * 4 + r] = s2[r];
    }
  }
  __syncthreads();
  float mu[4], rs[4];
#pragma unroll
  for (int r = 0; r < 4; ++r) {
    float S = 0.f, S2 = 0.f;
#pragma unroll
    for (int w2 = 0; w2 < NW; ++w2) { S += ps[w2 * 16 + kg * 4 + r]; S2 += ps2[w2 * 16 + kg * 4 + r]; }
    float m = S / NCOL;
    float var = S2 / NCOL - m * m;
    mu[r] = m; rs[r] = rsqrtf(var + 1e-5f);
  }
#pragma unroll
  for (int n = 0; n < 4; ++n) {
    int col = col0 + n * 16 + arow;
    float gv = G[col], bev = Be[col];
#pragma unroll
    for (int r = 0; r < 4; ++r)
      acc[n][r] = fmaxf((acc[n][r] - mu[r]) * rs[r] * gv + bev, 0.f);
  }
  if (Y) {
#pragma unroll
    for (int n = 0; n < 4; ++n) {
      int col = col0 + n * 16 + arow;
#pragma unroll
      for (int r = 0; r < 4; ++r)
        Y[(size_t)(m0 + kg * 4 + r) * NCOL + col] = (_Float16)acc[n][r];
    }
  }
  if (outq) {
    float p[4] = {};
#pragma unroll
    for (int n = 0; n < 4; ++n) {
      float w3 = W3[col0 + n * 16 + arow];
#pragma unroll
      for (int r = 0; r < 4; ++r) p[r] += acc[n][r] * w3;
    }
#pragma unroll
    for (int d = 1; d < 16; d <<= 1)
#pragma unroll
      for (int r = 0; r < 4; ++r) p[r] += __shfl_xor(p[r], d);
    if (arow == 0)
#pragma unroll
      for (int r = 0; r < 4; ++r) pq[w * 16 + kg * 4 + r] = p[r];
    __syncthreads();
    if (w == 0 && arow == 0) {
#pragma unroll
      for (int r = 0; r < 4; ++r) {
        float o = b3[0];
#pragma unroll
        for (int w2 = 0; w2 < NW; ++w2) o += pq[w2 * 16 + kg * 4 + r];
        outq[m0 + kg * 4 + r] = o;
      }
    }
  }
}

// ---------------- q/k/v stage (no LN): grid (16, 4, 3) ----------------
__global__ __launch_bounds__(64) void k_qkv(
    const _Float16* __restrict__ sh16, const _Float16* __restrict__ g216,
    const _Float16* __restrict__ Tq, const _Float16* __restrict__ Tk,
    const _Float16* __restrict__ Tv,
    const float* __restrict__ bq, const float* __restrict__ bk,
    const float* __restrict__ bv,
    _Float16* __restrict__ qb, _Float16* __restrict__ kb, _Float16* __restrict__ vb)
{
  int lane = threadIdx.x;
  int arow = lane & 15, kg = lane >> 4;
  int m0 = blockIdx.x * 16;
  int col0 = blockIdx.y * 64;
  int mat = blockIdx.z;
  const _Float16* X = (mat == 0) ? sh16 : g216;
  const _Float16* WT = (mat == 0) ? Tq : (mat == 1) ? Tk : Tv;
  const float* b = (mat == 0) ? bq : (mat == 1) ? bk : bv;
  _Float16* Y = (mat == 0) ? qb : (mat == 1) ? kb : vb;

  f32x4 acc[4] = {};
#pragma unroll
  for (int ks = 0; ks < 8; ++ks) {
    half8 af = *(const half8*)(X + (size_t)(m0 + arow) * 256 + ks * 32 + kg * 8);
#pragma unroll
    for (int n = 0; n < 4; ++n) {
      half8 bf = *(const half8*)(WT + (size_t)(col0 + n * 16 + arow) * 256 + ks * 32 + kg * 8);
      acc[n] = __builtin_amdgcn_mfma_f32_16x16x32_f16(af, bf, acc[n], 0, 0, 0);
    }
  }
#pragma unroll
  for (int n = 0; n < 4; ++n) {
    int col = col0 + n * 16 + arow;
    float bv2 = b[col];
#pragma unroll
    for (int r = 0; r < 4; ++r)
      Y[(size_t)(m0 + kg * 4 + r) * 256 + col] = (_Float16)(acc[n][r] + bv2);
  }
}

// ---------------- Wo stage + gv concat: grid (16, 4) ----------------
__global__ __launch_bounds__(64) void k_wo(
    const _Float16* __restrict__ pv16, const _Float16* __restrict__ To,
    const float* __restrict__ bo, const float* __restrict__ gvec,
    _Float16* __restrict__ hqin)
{
  int lane = threadIdx.x;
  int arow = lane & 15, kg = lane >> 4;
  int m0 = blockIdx.x * 16;
  int col0 = blockIdx.y * 64;

  f32x4 acc[4] = {};
#pragma unroll
  for (int ks = 0; ks < 8; ++ks) {
    half8 af = *(const half8*)(pv16 + (size_t)(m0 + arow) * 256 + ks * 32 + kg * 8);
#pragma unroll
    for (int n = 0; n < 4; ++n) {
      half8 bf = *(const half8*)(To + (size_t)(col0 + n * 16 + arow) * 256 + ks * 32 + kg * 8);
      acc[n] = __builtin_amdgcn_mfma_f32_16x16x32_f16(af, bf, acc[n], 0, 0, 0);
    }
  }
#pragma unroll
  for (int n = 0; n < 4; ++n) {
    int col = col0 + n * 16 + arow;
    float bv = bo[col];
    _Float16 gg = (_Float16)gvec[col];
#pragma unroll
    for (int r = 0; r < 4; ++r) {
      hqin[(size_t)(m0 + kg * 4 + r) * 512 + col] = (_Float16)(acc[n][r] + bv);
      hqin[(size_t)(m0 + kg * 4 + r) * 512 + 256 + col] = gg;
    }
  }
}

// ---------------- cross-attention per query row (1024 thr) ----------------
__global__ __launch_bounds__(1024) void k_attn(const _Float16* __restrict__ qb,
    const _Float16* __restrict__ kb, const _Float16* __restrict__ vb,
    _Float16* __restrict__ pv16)
{
  __shared__ float qv[HD];
  __shared__ float att[1024];
  __shared__ float red4[1024];
  __shared__ float redm[16];
  __shared__ float reds[16];
  int row = blockIdx.x, t = threadIdx.x;
  int w = t >> 6;

  if (t < 256) qv[t] = (float)qb[(size_t)row * HD + t];
  __syncthreads();

  int h = t >> 8, key = t & 255;
  float e = 0.f;
  {
    const half8* kr = (const half8*)(kb + (size_t)key * HD + h * HC);
    const float* qh = qv + h * HC;
#pragma unroll
    for (int d = 0; d < 8; ++d) {
      half8 kk = kr[d];
#pragma unroll
      for (int u = 0; u < 8; ++u) e += qh[d * 8 + u] * (float)kk[u];
    }
    e *= 0.125f;
  }
  float wm = e;
#pragma unroll
  for (int d = 1; d < 64; d <<= 1) wm = fmaxf(wm, __shfl_xor(wm, d));
  if ((t & 63) == 0) redm[w] = wm;
  __syncthreads();
  float mx = fmaxf(fmaxf(redm[4 * h], redm[4 * h + 1]), fmaxf(redm[4 * h + 2], redm[4 * h + 3]));
  float pw = __expf(e - mx);
  float ws = wsum(pw);
  if ((t & 63) == 0) reds[w] = ws;
  att[t] = pw;
  __syncthreads();

  int kq = t >> 8, j = t & 255;
  int hj = j >> 6;
  float p = 0.f;
  const float* arow = att + hj * 256 + kq * 64;
  const _Float16* vcol = vb + (size_t)(kq * 64) * HD + j;
  for (int k = 0; k < 64; ++k)
    p += arow[k] * (float)vcol[(size_t)k * HD];
  red4[t] = p;
  __syncthreads();
  if (t < 256) {
    int hh = t >> 6;
    float dsum = reds[4 * hh] + reds[4 * hh + 1] + reds[4 * hh + 2] + reds[4 * hh + 3];
    float pv = (red4[t] + red4[256 + t] + red4[512 + t] + red4[768 + t]) / dsum;
    pv16[(size_t)row * HD + t] = (_Float16)pv;
  }
}

// =====================================================================
extern "C" void kernel_launch(void* const* d_in, const int* in_sizes, int n_in,
                              void* d_out, int out_size, void* d_ws, size_t ws_size,
                              hipStream_t stream) {
  const float* x      = (const float*)d_in[0];
  const int*   ei     = (const int*)d_in[1];
  const int*   batch  = (const int*)d_in[2];
  const int*   sheet_idx = (const int*)d_in[3];
  const float* sheet_feat = (const float*)d_in[4];
  const float* pre_W  = (const float*)d_in[5];
  const float* pre_b  = (const float*)d_in[6];
  const float* gat_Wl = (const float*)d_in[7];
  const float* gat_Wr = (const float*)d_in[8];
  const float* gat_att = (const float*)d_in[9];
  const float* gat_b  = (const float*)d_in[10];
  const float* geo_W1 = (const float*)d_in[11];
  const float* geo_b1 = (const float*)d_in[12];
  const float* geo_g1 = (const float*)d_in[13];
  const float* geo_be1 = (const float*)d_in[14];
  const float* geo_W2 = (const float*)d_in[15];
  const float* geo_b2 = (const float*)d_in[16];
  const float* geo_g2 = (const float*)d_in[17];
  const float* geo_be2 = (const float*)d_in[18];
  const float* ca_Wq = (const float*)d_in[19];
  const float* ca_bq = (const float*)d_in[20];
  const float* ca_Wk = (const float*)d_in[21];
  const float* ca_bk = (const float*)d_in[22];
  const float* ca_Wv = (const float*)d_in[23];
  const float* ca_bv = (const float*)d_in[24];
  const float* ca_Wo = (const float*)d_in[25];
  const float* ca_bo = (const float*)d_in[26];
  const float* q_W1 = (const float*)d_in[27];
  const float* q_b1 = (const float*)d_in[28];
  const float* q_g1 = (const float*)d_in[29];
  const float* q_be1 = (const float*)d_in[30];
  const float* q_W2 = (const float*)d_in[31];
  const float* q_b2 = (const float*)d_in[32];
  const float* q_g2 = (const float*)d_in[33];
  const float* q_be2 = (const float*)d_in[34];
  const float* q_W3 = (const float*)d_in[35];
  const float* q_b3 = (const float*)d_in[36];
  const float* d_W1 = (const float*)d_in[37];
  const float* d_b1 = (const float*)d_in[38];
  const float* d_g1 = (const float*)d_in[39];
  const float* d_be1 = (const float*)d_in[40];
  const float* d_W2 = (const float*)d_in[41];
  const float* d_b2 = (const float*)d_in[42];

  char* wsb = (char*)d_ws;
  auto alloc = [&](size_t bytes) { char* p = wsb; wsb += (bytes + 255) & ~(size_t)255; return p; };

  _Float16* h16  = (_Float16*)alloc((size_t)MPAD * HD * 2);
  _Float16* Xl16 = (_Float16*)alloc((size_t)MPAD * HD * 2);
  _Float16* Xr16 = (_Float16*)alloc((size_t)MPAD * HD * 2);
  _Float16* WT   = (_Float16*)alloc((size_t)6 * HD * HD * 2);
  _Float16* Tgeo2 = (_Float16*)alloc((size_t)HD * HD * 2);
  _Float16* Tq   = (_Float16*)alloc((size_t)HD * HD * 2);
  _Float16* Tk   = (_Float16*)alloc((size_t)HD * HD * 2);
  _Float16* Tv   = (_Float16*)alloc((size_t)HD * HD * 2);
  _Float16* To   = (_Float16*)alloc((size_t)HD * HD * 2);
  _Float16* Tq1  = (_Float16*)alloc((size_t)HD * 512 * 2);
  _Float16* Tq2  = (_Float16*)alloc((size_t)128 * HD * 2);
  _Float16* sh16 = (_Float16*)alloc((size_t)SS * HD * 2);
  _Float16* g116 = (_Float16*)alloc((size_t)SS * HD * 2);
  _Float16* g216 = (_Float16*)alloc((size_t)SS * HD * 2);
  _Float16* qb16 = (_Float16*)alloc((size_t)SS * HD * 2);
  _Float16* kb16 = (_Float16*)alloc((size_t)SS * HD * 2);
  _Float16* vb16 = (_Float16*)alloc((size_t)SS * HD * 2);
  _Float16* pv16 = (_Float16*)alloc((size_t)SS * HD * 2);
  _Float16* hqin16 = (_Float16*)alloc((size_t)SS * 512 * 2);
  _Float16* hq116 = (_Float16*)alloc((size_t)SS * HD * 2);
  float* gpart   = (float*)alloc((size_t)GSB * HD * 4);
  float* gvec    = (float*)alloc(256 * 4);
  int* cnt       = (int*)alloc((size_t)NN * 4);
  int* rowptr    = (int*)alloc((size_t)(NN + 1) * 4);
  int* wptr      = (int*)alloc((size_t)NN * 4);
  int* csr_src   = (int*)alloc((size_t)(ETOT + 8) * 4);
  int* btot      = (int*)alloc((size_t)SCB * 4);
  int* boff      = (int*)alloc((size_t)SCB * 4);
  int* gcnt      = (int*)alloc(4);

  float* out_q = (float*)d_out;        // [256]
  float* out_d = out_q + SS;           // [1]

  // weights + init (blocks 3200+)
  k_wconvAll<<<3318, 256, 0, stream>>>(gat_Wl, gat_Wr, geo_W2, ca_Wq, ca_Wk, ca_Wv,
                                       ca_Wo, q_W1, q_W2,
                                       WT, Tgeo2, Tq, Tk, Tv, To, Tq1, Tq2,
                                       cnt, gcnt, h16 + (size_t)NN * HD, csr_src + ETOT);

  // CSR build
  k_count<<<(ETOT + 255) / 256, 256, 0, stream>>>(ei, cnt);
  k_scanA<<<SCB, 256, 0, stream>>>(cnt, rowptr, btot);
  k_scanB<<<1, 128, 0, stream>>>(btot, boff, rowptr);
  k_scanC<<<SCB, 256, 0, stream>>>(rowptr, boff, wptr);
  k_scatter<<<(ETOT + 255) / 256, 256, 0, stream>>>(ei, wptr, csr_src);

  // pre-transform
  k_pre<<<NN / 8, 256, 0, stream>>>(x, pre_W, pre_b, h16);

  // GAT layers
  for (int l = 0; l < NL; ++l) {
    k_gemm16<<<MPAD / 64, 512, 0, stream>>>(h16, WT + (size_t)l * 2 * HD * HD, Xl16, Xr16);
    k_edgeagg<<<(NN + 3) / 4, 256, 0, stream>>>(Xl16, Xr16, gat_att + l * NH * CH,
                                                gat_b + l * HD, rowptr, csr_src, h16);
  }

  // global mean partials
  k_gsum<<<GSB, 256, 0, stream>>>(h16, batch, gpart, gcnt);

  // tail (+gfin folded into block SS)
  k_tail1<<<SS + 1, 256, 0, stream>>>(h16, sheet_idx, sheet_feat,
      geo_W1, geo_b1, geo_g1, geo_be1, gpart, gcnt, gvec, sh16, g116);
  k_stageLN<256, 4><<<16, 256, 0, stream>>>(g116, Tgeo2, geo_b2, geo_g2, geo_be2,
      g216, nullptr, nullptr, nullptr,
      nullptr, nullptr, nullptr, nullptr, nullptr, nullptr, nullptr, nullptr);
  dim3 qkvg(16, 4, 3);
  k_qkv<<<qkvg, 64, 0, stream>>>(sh16, g216, Tq, Tk, Tv, ca_bq, ca_bk, ca_bv,
                                 qb16, kb16, vb16);
  k_attn<<<SS, 1024, 0, stream>>>(qb16, kb16, vb16, pv16);
  dim3 wog(16, 4);
  k_wo<<<wog, 64, 0, stream>>>(pv16, To, ca_bo, gvec, hqin16);
  k_stageLN<512, 4><<<16, 256, 0, stream>>>(hqin16, Tq1, q_b1, q_g1, q_be1,
      hq116, nullptr, nullptr, nullptr,
      nullptr, nullptr, nullptr, nullptr, nullptr, nullptr, nullptr, nullptr);
  // hq2 + qval (blocks 0..15) + done head (block 16)
  k_stageLN<256, 2><<<17, 128, 0, stream>>>(hq116, Tq2, q_b2, q_g2, q_be2,
      nullptr, q_W3, q_b3, out_q,
      gvec, d_W1, d_b1, d_g1, d_be1, d_W2, d_b2, out_d);
}

// Round 13
// 275.771 us; speedup vs baseline: 1.4904x; 1.0375x over previous
//
#include <hip/hip_runtime.h>
#include <hip/hip_bf16.h>
#include <stdint.h>

#define NN 30000
#define MPAD 30080
#define FI 16
#define EE 300000
#define ETOT (EE + NN)
#define HD 256
#define NH 8
#define CH 32
#define NL 3
#define SS 256
#define KS 128
#define NHC 4
#define HC 64
#define GSB 256
#define RPB 118
#define SCB 118

typedef _Float16 half8 __attribute__((ext_vector_type(8)));
typedef _Float16 half4v __attribute__((ext_vector_type(4)));
typedef _Float16 half2v __attribute__((ext_vector_type(2)));
typedef float f32x4 __attribute__((ext_vector_type(4)));

// ---------------- wave helpers ----------------
__device__ __forceinline__ float wsum(float v) {
#pragma unroll
  for (int d = 1; d < 64; d <<= 1) v += __shfl_xor(v, d);
  return v;
}

__device__ __forceinline__ half2v mk2(_Float16 a, _Float16 b) {
  half2v r; r[0] = a; r[1] = b; return r;
}

__device__ __forceinline__ half2v h2max(half2v a, half2v b) {
#if __has_builtin(__builtin_elementwise_max)
  return __builtin_elementwise_max(a, b);
#else
  half2v r; r[0] = a[0] > b[0] ? a[0] : b[0]; r[1] = a[1] > b[1] ? a[1] : b[1];
  return r;
#endif
}

__device__ __forceinline__ float h2dot(half2v a, half2v b, float c) {
#if __has_builtin(__builtin_amdgcn_fdot2)
  return __builtin_amdgcn_fdot2(a, b, c, false);
#else
  return c + (float)a[0] * (float)b[0] + (float)a[1] * (float)b[1];
#endif
}

// LN over n channels, 256 threads, t<n holds a. 2 barriers.
__device__ __forceinline__ float ln_fast(float a, int t, int n, float* red16,
    const float* __restrict__ G, const float* __restrict__ Be, bool relu)
{
  float av = (t < n) ? a : 0.f;
  float s = wsum(av), s2 = wsum(av * av);
  if ((t & 63) == 0) { red16[t >> 6] = s; red16[8 + (t >> 6)] = s2; }
  __syncthreads();
  float sum = red16[0] + red16[1] + red16[2] + red16[3];
  float sq  = red16[8] + red16[9] + red16[10] + red16[11];
  float mu = sum / n;
  float var = sq / n - mu * mu;
  float o = 0.f;
  if (t < n) {
    o = (a - mu) * rsqrtf(var + 1e-5f) * G[t] + Be[t];
    if (relu) o = fmaxf(o, 0.f);
  }
  __syncthreads();
  return o;
}

// ---------------- weights transpose+convert + init (blocks 3200+) ----------------
__global__ __launch_bounds__(256) void k_wconvAll(
    const float* __restrict__ Wl, const float* __restrict__ Wr,
    const float* __restrict__ geo_W2, const float* __restrict__ ca_Wq,
    const float* __restrict__ ca_Wk, const float* __restrict__ ca_Wv,
    const float* __restrict__ ca_Wo, const float* __restrict__ q_W1,
    const float* __restrict__ q_W2,
    _Float16* __restrict__ WT,
    _Float16* __restrict__ Tgeo2, _Float16* __restrict__ Tq,
    _Float16* __restrict__ Tk, _Float16* __restrict__ Tv,
    _Float16* __restrict__ To, _Float16* __restrict__ Tq1,
    _Float16* __restrict__ Tq2,
    int* __restrict__ cnt, int* __restrict__ gcnt,
    _Float16* __restrict__ h16pad, int* __restrict__ csr_pad)
{
  int b = blockIdx.x, t = threadIdx.x;
  if (b >= 3200) {
    int i = (b - 3200) * 256 + t;
    if (i < NN) cnt[i] = 0;
    if (i == 0) gcnt[0] = 0;
    if (i < 16) csr_pad[i] = 0;
    if (i < (MPAD - NN) * HD) h16pad[i] = (_Float16)0.f;
    return;
  }
  if (b < 1536) {
    int m = b >> 8;
    int n = b & 255;
    int l = m >> 1;
    const float* W = (m & 1) ? (Wr + (size_t)l * HD * HD) : (Wl + (size_t)l * HD * HD);
    WT[((size_t)m * HD + n) * HD + t] = (_Float16)W[t * HD + n];
    return;
  }
  b -= 1536;
  if (b < 1280) {
    int seg = b >> 8;
    int n = b & 255;
    const float* src = (seg == 0) ? geo_W2 : (seg == 1) ? ca_Wq : (seg == 2) ? ca_Wk
                     : (seg == 3) ? ca_Wv : ca_Wo;
    _Float16* dst = (seg == 0) ? Tgeo2 : (seg == 1) ? Tq : (seg == 2) ? Tk
                  : (seg == 3) ? Tv : To;
    dst[(size_t)n * 256 + t] = (_Float16)src[(size_t)t * 256 + n];
  } else if (b < 1536) {
    int n = b - 1280;
    Tq1[(size_t)n * 512 + t]       = (_Float16)q_W1[(size_t)t * 256 + n];
    Tq1[(size_t)n * 512 + 256 + t] = (_Float16)q_W1[(size_t)(256 + t) * 256 + n];
  } else {
    int n = b - 1536;
    Tq2[(size_t)n * 256 + t] = (_Float16)q_W2[(size_t)t * 128 + n];
  }
}

// ---------------- pre-transform ----------------
__global__ __launch_bounds__(256) void k_pre(const float* __restrict__ x,
    const float* __restrict__ W, const float* __restrict__ b,
    _Float16* __restrict__ H16)
{
  __shared__ float Ws[FI][HD];
  __shared__ float xs[8][FI];
  int r0 = blockIdx.x * 8;
  int t = threadIdx.x;
  for (int i = t; i < FI * HD; i += 256) Ws[i >> 8][i & 255] = W[i];
  if (t < 8 * FI) xs[t >> 4][t & 15] = x[(size_t)(r0 + (t >> 4)) * FI + (t & 15)];
  __syncthreads();
  float bj = b[t];
  for (int r = 0; r < 8; ++r) {
    float acc = bj;
#pragma unroll
    for (int k = 0; k < FI; ++k) acc += xs[r][k] * Ws[k][t];
    H16[(size_t)(r0 + r) * HD + t] = (_Float16)acc;
  }
}

// ---------------- CSR build ----------------
__global__ __launch_bounds__(256) void k_count(const int* __restrict__ ei, int* __restrict__ cnt)
{
  int i = blockIdx.x * 256 + threadIdx.x;
  if (i >= ETOT) return;
  int dst = (i < EE) ? ei[EE + i] : (i - EE);
  atomicAdd(&cnt[dst], 1);
}

__global__ __launch_bounds__(256) void k_scanA(const int* __restrict__ cnt,
    int* __restrict__ rowptr, int* __restrict__ btot)
{
  __shared__ int wt[4];
  int b = blockIdx.x, t = threadIdx.x;
  int i = b * 256 + t;
  int v = (i < NN) ? cnt[i] : 0;
  int lane = t & 63, w = t >> 6;
  int s = v;
#pragma unroll
  for (int d = 1; d < 64; d <<= 1) {
    int u = __shfl_up(s, d);
    if (lane >= d) s += u;
  }
  if (lane == 63) wt[w] = s;
  __syncthreads();
  int off = 0;
  for (int k = 0; k < w; ++k) off += wt[k];
  if (i < NN) rowptr[i] = off + s - v;
  if (t == 255) btot[b] = off + s;
}

__global__ __launch_bounds__(128) void k_scanB(const int* __restrict__ btot,
    int* __restrict__ boff, int* __restrict__ rowptr)
{
  __shared__ int wt[2];
  int t = threadIdx.x;
  int v = (t < SCB) ? btot[t] : 0;
  int lane = t & 63, w = t >> 6;
  int s = v;
#pragma unroll
  for (int d = 1; d < 64; d <<= 1) {
    int u = __shfl_up(s, d);
    if (lane >= d) s += u;
  }
  if (lane == 63) wt[w] = s;
  __syncthreads();
  int off = (w == 1) ? wt[0] : 0;
  if (t < SCB) boff[t] = off + s - v;
  if (t == 127) rowptr[NN] = wt[0] + wt[1];
}

__global__ __launch_bounds__(256) void k_scanC(int* __restrict__ rowptr,
    const int* __restrict__ boff, int* __restrict__ wptr)
{
  int b = blockIdx.x, t = threadIdx.x;
  int i = b * 256 + t;
  if (i < NN) {
    int r = rowptr[i] + boff[b];
    rowptr[i] = r;
    wptr[i] = r;
  }
}

// csr_src stores src*HD (pre-scaled element offset)
__global__ __launch_bounds__(256) void k_scatter(const int* __restrict__ ei,
    int* __restrict__ wptr, int* __restrict__ csr_src)
{
  int i = blockIdx.x * 256 + threadIdx.x;
  if (i >= ETOT) return;
  int src = (i < EE) ? ei[i] : (i - EE);
  int dst = (i < EE) ? ei[EE + i] : (i - EE);
  int pos = atomicAdd(&wptr[dst], 1);
  csr_src[pos] = src * HD;
}

// ---------------- fp16 MFMA GEMM: 64x512 tile (both mats), 8 waves ----------------
#define BKG 64
__global__ __launch_bounds__(512) void k_gemm16(const _Float16* __restrict__ A,
    const _Float16* __restrict__ WT,
    _Float16* __restrict__ Xl, _Float16* __restrict__ Xr)
{
  __shared__ __align__(16) _Float16 As[64 * BKG];    // 8KB
  __shared__ __align__(16) _Float16 Bs[512 * BKG];   // 64KB
  int t = threadIdx.x;
  int w = t >> 6, lane = t & 63;
  int row0 = blockIdx.x * 64;

  f32x4 acc[4][4] = {};

  for (int k0 = 0; k0 < HD; k0 += BKG) {
    {
      int row = t >> 3, s = t & 7;
      int g = s ^ (row & 7);
      __builtin_amdgcn_global_load_lds(
        (const __attribute__((address_space(1))) void*)(A + (size_t)(row0 + row) * HD + k0 + g * 8),
        (__attribute__((address_space(3))) void*)((char*)As + w * 1024),
        16, 0, 0);
    }
#pragma unroll
    for (int i = 0; i < 8; ++i) {
      int p = i * 512 + t;
      int row = p >> 3, s = p & 7;
      int g = s ^ (row & 7);
      __builtin_amdgcn_global_load_lds(
        (const __attribute__((address_space(1))) void*)(WT + (size_t)row * HD + k0 + g * 8),
        (__attribute__((address_space(3))) void*)((char*)Bs + (i * 8 + w) * 1024),
        16, 0, 0);
    }
    __syncthreads();
#pragma unroll
    for (int ks = 0; ks < 2; ++ks) {
      half8 af[4], bfr[4];
      int kslot = ks * 4 + (lane >> 4);
#pragma unroll
      for (int mi = 0; mi < 4; ++mi) {
        int rl = mi * 16 + (lane & 15);
        int ps = kslot ^ (rl & 7);
        af[mi] = *(const half8*)((const char*)As + rl * 128 + ps * 16);
      }
#pragma unroll
      for (int ni = 0; ni < 4; ++ni) {
        int nl = w * 64 + ni * 16 + (lane & 15);
        int ps = kslot ^ (nl & 7);
        bfr[ni] = *(const half8*)((const char*)Bs + nl * 128 + ps * 16);
      }
#pragma unroll
      for (int mi = 0; mi < 4; ++mi)
#pragma unroll
        for (int ni = 0; ni < 4; ++ni)
          acc[mi][ni] = __builtin_amdgcn_mfma_f32_16x16x32_f16(af[mi], bfr[ni], acc[mi][ni], 0, 0, 0);
    }
    __syncthreads();
  }
  int crow = (lane >> 4) * 4;
  int ccol = lane & 15;
  _Float16* Out = (w < 4) ? Xl : Xr;
  int cbase = (w < 4) ? (w * 64) : ((w - 4) * 64);
#pragma unroll
  for (int mi = 0; mi < 4; ++mi)
#pragma unroll
    for (int ni = 0; ni < 4; ++ni) {
      size_t base_r = row0 + mi * 16 + crow;
      int c = cbase + ni * 16 + ccol;
#pragma unroll
      for (int r = 0; r < 4; ++r)
        Out[(base_r + r) * HD + c] = (_Float16)acc[mi][ni][r];
    }
}

// ---------------- fused edge + online-softmax agg (4-edge batched) ----------------
// one wave per node; lanes 0-31/32-63 = interleaved edge streams, independent
// online softmax merged at end. 8 ch/lane, 4 edges per trip, fp16 pk accum.
// csr_src holds src*HD; 16-entry pad covers lookahead over-reads.
__global__ __launch_bounds__(256) void k_edgeagg(const _Float16* __restrict__ Xl,
    const _Float16* __restrict__ Xr, const float* __restrict__ attw,
    const float* __restrict__ bias, const int* __restrict__ rowptr,
    const int* __restrict__ csr_src, _Float16* __restrict__ H16)
{
  int node = blockIdx.x * 4 + (threadIdx.x >> 6);
  int lane = threadIdx.x & 63;
  if (node >= NN) return;
  int st = rowptr[node], en = rowptr[node + 1];
  int n = en - st;
  int hf = lane >> 5, sl = lane & 31;
  int c = sl * 8;
  half8 xrv = *(const half8*)(Xr + (size_t)node * HD + c);
  float4 wa = *(const float4*)(attw + c);
  float4 wb = *(const float4*)(attw + c + 4);
  half2v w0 = mk2((_Float16)wa.x, (_Float16)wa.y);
  half2v w1 = mk2((_Float16)wa.z, (_Float16)wa.w);
  half2v w2 = mk2((_Float16)wb.x, (_Float16)wb.y);
  half2v w3 = mk2((_Float16)wb.z, (_Float16)wb.w);
  half2v r0 = mk2(xrv[0], xrv[1]), r1 = mk2(xrv[2], xrv[3]);
  half2v r2 = mk2(xrv[4], xrv[5]), r3 = mk2(xrv[6], xrv[7]);
  half2v c02 = mk2((_Float16)0.2f, (_Float16)0.2f);

  float mh = -1e30f, dsum = 0.f;
  half2v acch0 = {}, acch1 = {}, acch2 = {}, acch3 = {};
  int trips = (n + 1) >> 1;          // per-half slot count (max of the two)
  int trips4 = (trips + 3) >> 2;     // 4 slots per trip
  int base = st + hf;

  // current batch (slots 0..3)
  half8 cur0 = *(const half8*)(Xl + (size_t)csr_src[base + 0] + c);
  half8 cur1 = *(const half8*)(Xl + (size_t)csr_src[base + 2] + c);
  half8 cur2 = *(const half8*)(Xl + (size_t)csr_src[base + 4] + c);
  half8 cur3 = *(const half8*)(Xl + (size_t)csr_src[base + 6] + c);

  for (int it = 0; it < trips4; ++it) {
    // prefetch next batch (pad-safe)
    int nb = base + 8 * (it + 1);
    half8 nxt0 = *(const half8*)(Xl + (size_t)csr_src[nb + 0] + c);
    half8 nxt1 = *(const half8*)(Xl + (size_t)csr_src[nb + 2] + c);
    half8 nxt2 = *(const half8*)(Xl + (size_t)csr_src[nb + 4] + c);
    half8 nxt3 = *(const half8*)(Xl + (size_t)csr_src[nb + 6] + c);

    int s0i = 8 * it + hf;           // edge number of slot j is s0i + 2j
    float e0, e1, e2, e3;
    {
      half2v x0 = mk2(cur0[0], cur0[1]), x1 = mk2(cur0[2], cur0[3]);
      half2v x2 = mk2(cur0[4], cur0[5]), x3 = mk2(cur0[6], cur0[7]);
      half2v s0 = x0 + r0, s1 = x1 + r1, s2 = x2 + r2, s3 = x3 + r3;
      half2v m0 = h2max(s0, s0 * c02), m1 = h2max(s1, s1 * c02);
      half2v m2 = h2max(s2, s2 * c02), m3 = h2max(s3, s3 * c02);
      e0 = h2dot(m1, w1, h2dot(m0, w0, 0.f)) + h2dot(m3, w3, h2dot(m2, w2, 0.f));
    }
    {
      half2v x0 = mk2(cur1[0], cur1[1]), x1 = mk2(cur1[2], cur1[3]);
      half2v x2 = mk2(cur1[4], cur1[5]), x3 = mk2(cur1[6], cur1[7]);
      half2v s0 = x0 + r0, s1 = x1 + r1, s2 = x2 + r2, s3 = x3 + r3;
      half2v m0 = h2max(s0, s0 * c02), m1 = h2max(s1, s1 * c02);
      half2v m2 = h2max(s2, s2 * c02), m3 = h2max(s3, s3 * c02);
      e1 = h2dot(m1, w1, h2dot(m0, w0, 0.f)) + h2dot(m3, w3, h2dot(m2, w2, 0.f));
    }
    {
      half2v x0 = mk2(cur2[0], cur2[1]), x1 = mk2(cur2[2], cur2[3]);
      half2v x2 = mk2(cur2[4], cur2[5]), x3 = mk2(cur2[6], cur2[7]);
      half2v s0 = x0 + r0, s1 = x1 + r1, s2 = x2 + r2, s3 = x3 + r3;
      half2v m0 = h2max(s0, s0 * c02), m1 = h2max(s1, s1 * c02);
      half2v m2 = h2max(s2, s2 * c02), m3 = h2max(s3, s3 * c02);
      e2 = h2dot(m1, w1, h2dot(m0, w0, 0.f)) + h2dot(m3, w3, h2dot(m2, w2, 0.f));
    }
    {
      half2v x0 = mk2(cur3[0], cur3[1]), x1 = mk2(cur3[2], cur3[3]);
      half2v x2 = mk2(cur3[4], cur3[5]), x3 = mk2(cur3[6], cur3[7]);
      half2v s0 = x0 + r0, s1 = x1 + r1, s2 = x2 + r2, s3 = x3 + r3;
      half2v m0 = h2max(s0, s0 * c02), m1 = h2max(s1, s1 * c02);
      half2v m2 = h2max(s2, s2 * c02), m3 = h2max(s3, s3 * c02);
      e3 = h2dot(m1, w1, h2dot(m0, w0, 0.f)) + h2dot(m3, w3, h2dot(m2, w2, 0.f));
    }
    e0 += __shfl_xor(e0, 1); e1 += __shfl_xor(e1, 1);
    e2 += __shfl_xor(e2, 1); e3 += __shfl_xor(e3, 1);
    e0 += __shfl_xor(e0, 2); e1 += __shfl_xor(e1, 2);
    e2 += __shfl_xor(e2, 2); e3 += __shfl_xor(e3, 2);
    e0 = (s0i + 0 < n) ? e0 : -1e30f;
    e1 = (s0i + 2 < n) ? e1 : -1e30f;
    e2 = (s0i + 4 < n) ? e2 : -1e30f;
    e3 = (s0i + 6 < n) ? e3 : -1e30f;

    float pmax = fmaxf(fmaxf(e0, e1), fmaxf(e2, e3));
    // defer-max THR=4 so deferred weights <= e^4 (fp16 accum overflow-safe)
    if (__any(pmax > mh + 4.f)) {
      float nm = fmaxf(mh, pmax);
      float sc = __expf(mh - nm);
      _Float16 sch16 = (_Float16)sc;
      half2v sch = mk2(sch16, sch16);
      acch0 *= sch; acch1 *= sch; acch2 *= sch; acch3 *= sch;
      dsum *= sc;
      mh = nm;
    }
    float pw0 = __expf(e0 - mh);
    float pw1 = __expf(e1 - mh);
    float pw2 = __expf(e2 - mh);
    float pw3 = __expf(e3 - mh);
    {
      _Float16 p16 = (_Float16)pw0; half2v p = mk2(p16, p16);
      acch0 += p * mk2(cur0[0], cur0[1]); acch1 += p * mk2(cur0[2], cur0[3]);
      acch2 += p * mk2(cur0[4], cur0[5]); acch3 += p * mk2(cur0[6], cur0[7]);
    }
    {
      _Float16 p16 = (_Float16)pw1; half2v p = mk2(p16, p16);
      acch0 += p * mk2(cur1[0], cur1[1]); acch1 += p * mk2(cur1[2], cur1[3]);
      acch2 += p * mk2(cur1[4], cur1[5]); acch3 += p * mk2(cur1[6], cur1[7]);
    }
    {
      _Float16 p16 = (_Float16)pw2; half2v p = mk2(p16, p16);
      acch0 += p * mk2(cur2[0], cur2[1]); acch1 += p * mk2(cur2[2], cur2[3]);
      acch2 += p * mk2(cur2[4], cur2[5]); acch3 += p * mk2(cur2[6], cur2[7]);
    }
    {
      _Float16 p16 = (_Float16)pw3; half2v p = mk2(p16, p16);
      acch0 += p * mk2(cur3[0], cur3[1]); acch1 += p * mk2(cur3[2], cur3[3]);
      acch2 += p * mk2(cur3[4], cur3[5]); acch3 += p * mk2(cur3[6], cur3[7]);
    }
    dsum += (pw0 + pw1) + (pw2 + pw3);
    cur0 = nxt0; cur1 = nxt1; cur2 = nxt2; cur3 = nxt3;
  }
  // to fp32, then exact cross-half merge
  float a[8];
  a[0] = (float)acch0[0]; a[1] = (float)acch0[1];
  a[2] = (float)acch1[0]; a[3] = (float)acch1[1];
  a[4] = (float)acch2[0]; a[5] = (float)acch2[1];
  a[6] = (float)acch3[0]; a[7] = (float)acch3[1];
  float om = __shfl_xor(mh, 32);
  float od = __shfl_xor(dsum, 32);
  float nm = fmaxf(mh, om);
  float scs = __expf(mh - nm);
  float sco = __expf(om - nm);
  float d = dsum * scs + od * sco;
#pragma unroll
  for (int j = 0; j < 8; ++j) {
    float oa = __shfl_xor(a[j], 32);
    a[j] = a[j] * scs + oa * sco;
  }
  if (hf == 0) {
    float inv = 1.f / (d + 1e-16f);
    float4 ba = *(const float4*)(bias + c);
    float4 bb = *(const float4*)(bias + c + 4);
    float ob[8] = {ba.x, ba.y, ba.z, ba.w, bb.x, bb.y, bb.z, bb.w};
    half8 h8;
#pragma unroll
    for (int j = 0; j < 8; ++j) {
      float o = a[j] * inv + ob[j];
      o = (o > 0.f) ? o : (__expf(o) - 1.f);   // fast ELU
      h8[j] = (_Float16)o;
    }
    *(half8*)(H16 + (size_t)node * HD + c) = h8;
  }
}

// ---------------- global sum: per-block partials ----------------
__global__ __launch_bounds__(256) void k_gsum(const _Float16* __restrict__ H,
    const int* __restrict__ batch, float* __restrict__ gpart, int* __restrict__ gcnt)
{
  __shared__ float flagf[RPB];
  __shared__ int scount;
  int b = blockIdx.x, t = threadIdx.x;
  int r0 = b * RPB;
  int nr = NN - r0; if (nr > RPB) nr = RPB; if (nr < 0) nr = 0;
  if (t == 0) scount = 0;
  __syncthreads();
  if (t < nr) {
    int ok = (batch[r0 + t] == 0) ? 1 : 0;
    flagf[t] = (float)ok;
    if (ok) atomicAdd(&scount, 1);
  }
  __syncthreads();
  float a0 = 0.f, a1 = 0.f, a2 = 0.f, a3 = 0.f;
  const _Float16* Hp = H + (size_t)r0 * HD + t;
  int r = 0;
  for (; r + 4 <= nr; r += 4) {
    float v0 = (float)Hp[(size_t)(r + 0) * HD];
    float v1 = (float)Hp[(size_t)(r + 1) * HD];
    float v2 = (float)Hp[(size_t)(r + 2) * HD];
    float v3 = (float)Hp[(size_t)(r + 3) * HD];
    a0 += v0 * flagf[r + 0]; a1 += v1 * flagf[r + 1];
    a2 += v2 * flagf[r + 2]; a3 += v3 * flagf[r + 3];
  }
  for (; r < nr; ++r) a0 += (float)Hp[(size_t)r * HD] * flagf[r];
  gpart[(size_t)b * HD + t] = (a0 + a1) + (a2 + a3);
  if (t == 0 && scount) atomicAdd(gcnt, scount);
}

// ---------------- tail head: sheet pool + geo1 (+gfin at blk SS) ----------------
__global__ __launch_bounds__(256) void k_tail1(const _Float16* __restrict__ h16,
    const int* __restrict__ sheet_idx, const float* __restrict__ sheet_feat,
    const float* __restrict__ geo_W1, const float* __restrict__ geo_b1,
    const float* __restrict__ geo_g1, const float* __restrict__ geo_be1,
    const float* __restrict__ gpart, const int* __restrict__ gcnt,
    float* __restrict__ gvec,
    _Float16* __restrict__ sh16, _Float16* __restrict__ g116)
{
  __shared__ float xf[FI];
  __shared__ int sidx[KS];
  __shared__ float red16[16];
  int s = blockIdx.x, t = threadIdx.x;

  if (s == SS) {
    float a0 = 0.f, a1 = 0.f, a2 = 0.f, a3 = 0.f;
    for (int b = 0; b < GSB; b += 4) {
      a0 += gpart[(size_t)b * HD + t];
      a1 += gpart[(size_t)(b + 1) * HD + t];
      a2 += gpart[(size_t)(b + 2) * HD + t];
      a3 += gpart[(size_t)(b + 3) * HD + t];
    }
    gvec[t] = ((a0 + a1) + (a2 + a3)) / (float)(*gcnt);
    return;
  }

  if (t < KS) sidx[t] = sheet_idx[s * KS + t];
  if (t >= 240) xf[t - 240] = sheet_feat[s * FI + (t - 240)];
  __syncthreads();

  float pa[8] = {};
#pragma unroll 2
  for (int r = 0; r < KS; r += 8) {
#pragma unroll
    for (int u = 0; u < 8; ++u)
      pa[u] += (float)h16[(size_t)sidx[r + u] * HD + t];
  }
  float shv = ((pa[0] + pa[1]) + (pa[2] + pa[3]) + (pa[4] + pa[5]) + (pa[6] + pa[7])) * (1.f / KS);
  sh16[(size_t)s * HD + t] = (_Float16)shv;

  float a = geo_b1[t];
#pragma unroll
  for (int k = 0; k < FI; ++k) a += xf[k] * geo_W1[k * HD + t];
  float g1 = ln_fast(a, t, 256, red16, geo_g1, geo_be1, true);
  g116[(size_t)s * HD + t] = (_Float16)g1;
}

// ---------------- MFMA tail stage with LN (NW waves, 16 rows/block) ----------------
template <int KD, int NW>
__global__ __launch_bounds__(NW * 64) void k_stageLN(
    const _Float16* __restrict__ X, const _Float16* __restrict__ WT,
    const float* __restrict__ b, const float* __restrict__ G,
    const float* __restrict__ Be, _Float16* __restrict__ Y,
    const float* __restrict__ W3, const float* __restrict__ b3,
    float* __restrict__ outq,
    const float* __restrict__ gvec,
    const float* __restrict__ dW1, const float* __restrict__ db1,
    const float* __restrict__ dg1, const float* __restrict__ dbe1,
    const float* __restrict__ dW2, const float* __restrict__ db2,
    float* __restrict__ outd)
{
  __shared__ float ps[NW * 16], ps2[NW * 16], pq[NW * 16];
  const int NCOL = NW * 64;
  int t = threadIdx.x;

  if (outd != nullptr && blockIdx.x == 16) {
    int w2 = t >> 6;
    float acc2 = db1[t];
    for (int k = 0; k < 256; ++k) acc2 += gvec[k] * dW1[(size_t)k * 128 + t];
    float s = wsum(acc2), s2v = wsum(acc2 * acc2);
    if ((t & 63) == 0) { ps[w2] = s; ps2[w2] = s2v; }
    __syncthreads();
    float S = ps[0] + ps[1], S2 = ps2[0] + ps2[1];
    float mu = S * (1.f / 128.f), var = S2 * (1.f / 128.f) - mu * mu;
    float hdv = fmaxf((acc2 - mu) * rsqrtf(var + 1e-5f) * dg1[t] + dbe1[t], 0.f);
    float o = wsum(hdv * dW2[t]);
    if ((t & 63) == 0) pq[w2] = o;
    __syncthreads();
    if (t == 0) outd[0] = pq[0] + pq[1] + db2[0];
    return;
  }

  int w = t >> 6, lane = t & 63;
  int arow = lane & 15, kg = lane >> 4;
  int m0 = blockIdx.x * 16;
  int col0 = w * 64;

  f32x4 acc[4] = {};
#pragma unroll
  for (int ks = 0; ks < KD / 32; ++ks) {
    half8 af = *(const half8*)(X + (size_t)(m0 + arow) * KD + ks * 32 + kg * 8);
#pragma unroll
    for (int n = 0; n < 4; ++n) {
      half8 bf = *(const half8*)(WT + (size_t)(col0 + n * 16 + arow) * KD + ks * 32 + kg * 8);
      acc[n] = __builtin_amdgcn_mfma_f32_16x16x32_f16(af, bf, acc[n], 0, 0, 0);
    }
  }
#pragma unroll
  for (int n = 0; n < 4; ++n) {
    float bv = b[col0 + n * 16 + arow];
#pragma unroll
    for (int r = 0; r < 4; ++r) acc[n][r] += bv;
  }
  float s[4] = {}, s2[4] = {};
#pragma unroll
  for (int n = 0; n < 4; ++n)
#pragma unroll
    for (int r = 0; r < 4; ++r) { float v = acc[n][r]; s[r] += v; s2[r] += v * v; }
#pragma unroll
  for (int d = 1; d < 16; d <<= 1)
#pragma unroll
    for (int r = 0; r < 4; ++r) { s[r] += __shfl_xor(s[r], d); s2[r] += __shfl_xor(s2[r], d); }
  if (arow == 0) {
#pragma unroll
    for (int r = 0; r < 4; ++r) {
      ps[w * 16 + kg * 4 + r] = s[r];
      ps2[w * 16 + kg * 4 + r] = s2[r];
    }
  }
  __syncthreads();
  float mu[4], rs[4];
#pragma unroll
  for (int r = 0; r < 4; ++r) {
    float S = 0.f, S2 = 0.f;
#pragma unroll
    for (int w2 = 0; w2 < NW; ++w2) { S += ps[w2 * 16 + kg * 4 + r]; S2 += ps2[w2 * 16 + kg * 4 + r]; }
    float m = S / NCOL;
    float var = S2 / NCOL - m * m;
    mu[r] = m; rs[r] = rsqrtf(var + 1e-5f);
  }
#pragma unroll
  for (int n = 0; n < 4; ++n) {
    int col = col0 + n * 16 + arow;
    float gv = G[col], bev = Be[col];
#pragma unroll
    for (int r = 0; r < 4; ++r)
      acc[n][r] = fmaxf((acc[n][r] - mu[r]) * rs[r] * gv + bev, 0.f);
  }
  if (Y) {
#pragma unroll
    for (int n = 0; n < 4; ++n) {
      int col = col0 + n * 16 + arow;
#pragma unroll
      for (int r = 0; r < 4; ++r)
        Y[(size_t)(m0 + kg * 4 + r) * NCOL + col] = (_Float16)acc[n][r];
    }
  }
  if (outq) {
    float p[4] = {};
#pragma unroll
    for (int n = 0; n < 4; ++n) {
      float w3 = W3[col0 + n * 16 + arow];
#pragma unroll
      for (int r = 0; r < 4; ++r) p[r] += acc[n][r] * w3;
    }
#pragma unroll
    for (int d = 1; d < 16; d <<= 1)
#pragma unroll
      for (int r = 0; r < 4; ++r) p[r] += __shfl_xor(p[r], d);
    if (arow == 0)
#pragma unroll
      for (int r = 0; r < 4; ++r) pq[w * 16 + kg * 4 + r] = p[r];
    __syncthreads();
    if (w == 0 && arow == 0) {
#pragma unroll
      for (int r = 0; r < 4; ++r) {
        float o = b3[0];
#pragma unroll
        for (int w2 = 0; w2 < NW; ++w2) o += pq[w2 * 16 + kg * 4 + r];
        outq[m0 + kg * 4 + r] = o;
      }
    }
  }
}

// ---------------- q/k/v stage (no LN): grid (16, 4, 3) ----------------
__global__ __launch_bounds__(64) void k_qkv(
    const _Float16* __restrict__ sh16, const _Float16* __restrict__ g216,
    const _Float16* __restrict__ Tq, const _Float16* __restrict__ Tk,
    const _Float16* __restrict__ Tv,
    const float* __restrict__ bq, const float* __restrict__ bk,
    const float* __restrict__ bv,
    _Float16* __restrict__ qb, _Float16* __restrict__ kb, _Float16* __restrict__ vb)
{
  int lane = threadIdx.x;
  int arow = lane & 15, kg = lane >> 4;
  int m0 = blockIdx.x * 16;
  int col0 = blockIdx.y * 64;
  int mat = blockIdx.z;
  const _Float16* X = (mat == 0) ? sh16 : g216;
  const _Float16* WT = (mat == 0) ? Tq : (mat == 1) ? Tk : Tv;
  const float* b = (mat == 0) ? bq : (mat == 1) ? bk : bv;
  _Float16* Y = (mat == 0) ? qb : (mat == 1) ? kb : vb;

  f32x4 acc[4] = {};
#pragma unroll
  for (int ks = 0; ks < 8; ++ks) {
    half8 af = *(const half8*)(X + (size_t)(m0 + arow) * 256 + ks * 32 + kg * 8);
#pragma unroll
    for (int n = 0; n < 4; ++n) {
      half8 bf = *(const half8*)(WT + (size_t)(col0 + n * 16 + arow) * 256 + ks * 32 + kg * 8);
      acc[n] = __builtin_amdgcn_mfma_f32_16x16x32_f16(af, bf, acc[n], 0, 0, 0);
    }
  }
#pragma unroll
  for (int n = 0; n < 4; ++n) {
    int col = col0 + n * 16 + arow;
    float bv2 = b[col];
#pragma unroll
    for (int r = 0; r < 4; ++r)
      Y[(size_t)(m0 + kg * 4 + r) * 256 + col] = (_Float16)(acc[n][r] + bv2);
  }
}

// ---------------- Wo stage + gv concat: grid (16, 4) ----------------
__global__ __launch_bounds__(64) void k_wo(
    const _Float16* __restrict__ pv16, const _Float16* __restrict__ To,
    const float* __restrict__ bo, const float* __restrict__ gvec,
    _Float16* __restrict__ hqin)
{
  int lane = threadIdx.x;
  int arow = lane & 15, kg = lane >> 4;
  int m0 = blockIdx.x * 16;
  int col0 = blockIdx.y * 64;

  f32x4 acc[4] = {};
#pragma unroll
  for (int ks = 0; ks < 8; ++ks) {
    half8 af = *(const half8*)(pv16 + (size_t)(m0 + arow) * 256 + ks * 32 + kg * 8);
#pragma unroll
    for (int n = 0; n < 4; ++n) {
      half8 bf = *(const half8*)(To + (size_t)(col0 + n * 16 + arow) * 256 + ks * 32 + kg * 8);
      acc[n] = __builtin_amdgcn_mfma_f32_16x16x32_f16(af, bf, acc[n], 0, 0, 0);
    }
  }
#pragma unroll
  for (int n = 0; n < 4; ++n) {
    int col = col0 + n * 16 + arow;
    float bv = bo[col];
    _Float16 gg = (_Float16)gvec[col];
#pragma unroll
    for (int r = 0; r < 4; ++r) {
      hqin[(size_t)(m0 + kg * 4 + r) * 512 + col] = (_Float16)(acc[n][r] + bv);
      hqin[(size_t)(m0 + kg * 4 + r) * 512 + 256 + col] = gg;
    }
  }
}

// ---------------- cross-attention per query row (1024 thr) ----------------
__global__ __launch_bounds__(1024) void k_attn(const _Float16* __restrict__ qb,
    const _Float16* __restrict__ kb, const _Float16* __restrict__ vb,
    _Float16* __restrict__ pv16)
{
  __shared__ float qv[HD];
  __shared__ float att[1024];
  __shared__ float red4[1024];
  __shared__ float redm[16];
  __shared__ float reds[16];
  int row = blockIdx.x, t = threadIdx.x;
  int w = t >> 6;

  if (t < 256) qv[t] = (float)qb[(size_t)row * HD + t];
  __syncthreads();

  int h = t >> 8, key = t & 255;
  float e = 0.f;
  {
    const half8* kr = (const half8*)(kb + (size_t)key * HD + h * HC);
    const float* qh = qv + h * HC;
#pragma unroll
    for (int d = 0; d < 8; ++d) {
      half8 kk = kr[d];
#pragma unroll
      for (int u = 0; u < 8; ++u) e += qh[d * 8 + u] * (float)kk[u];
    }
    e *= 0.125f;
  }
  float wm = e;
#pragma unroll
  for (int d = 1; d < 64; d <<= 1) wm = fmaxf(wm, __shfl_xor(wm, d));
  if ((t & 63) == 0) redm[w] = wm;
  __syncthreads();
  float mx = fmaxf(fmaxf(redm[4 * h], redm[4 * h + 1]), fmaxf(redm[4 * h + 2], redm[4 * h + 3]));
  float pw = __expf(e - mx);
  float ws = wsum(pw);
  if ((t & 63) == 0) reds[w] = ws;
  att[t] = pw;
  __syncthreads();

  int kq = t >> 8, j = t & 255;
  int hj = j >> 6;
  float p = 0.f;
  const float* arow = att + hj * 256 + kq * 64;
  const _Float16* vcol = vb + (size_t)(kq * 64) * HD + j;
  for (int k = 0; k < 64; ++k)
    p += arow[k] * (float)vcol[(size_t)k * HD];
  red4[t] = p;
  __syncthreads();
  if (t < 256) {
    int hh = t >> 6;
    float dsum = reds[4 * hh] + reds[4 * hh + 1] + reds[4 * hh + 2] + reds[4 * hh + 3];
    float pv = (red4[t] + red4[256 + t] + red4[512 + t] + red4[768 + t]) / dsum;
    pv16[(size_t)row * HD + t] = (_Float16)pv;
  }
}

// =====================================================================
extern "C" void kernel_launch(void* const* d_in, const int* in_sizes, int n_in,
                              void* d_out, int out_size, void* d_ws, size_t ws_size,
                              hipStream_t stream) {
  const float* x      = (const float*)d_in[0];
  const int*   ei     = (const int*)d_in[1];
  const int*   batch  = (const int*)d_in[2];
  const int*   sheet_idx = (const int*)d_in[3];
  const float* sheet_feat = (const float*)d_in[4];
  const float* pre_W  = (const float*)d_in[5];
  const float* pre_b  = (const float*)d_in[6];
  const float* gat_Wl = (const float*)d_in[7];
  const float* gat_Wr = (const float*)d_in[8];
  const float* gat_att = (const float*)d_in[9];
  const float* gat_b  = (const float*)d_in[10];
  const float* geo_W1 = (const float*)d_in[11];
  const float* geo_b1 = (const float*)d_in[12];
  const float* geo_g1 = (const float*)d_in[13];
  const float* geo_be1 = (const float*)d_in[14];
  const float* geo_W2 = (const float*)d_in[15];
  const float* geo_b2 = (const float*)d_in[16];
  const float* geo_g2 = (const float*)d_in[17];
  const float* geo_be2 = (const float*)d_in[18];
  const float* ca_Wq = (const float*)d_in[19];
  const float* ca_bq = (const float*)d_in[20];
  const float* ca_Wk = (const float*)d_in[21];
  const float* ca_bk = (const float*)d_in[22];
  const float* ca_Wv = (const float*)d_in[23];
  const float* ca_bv = (const float*)d_in[24];
  const float* ca_Wo = (const float*)d_in[25];
  const float* ca_bo = (const float*)d_in[26];
  const float* q_W1 = (const float*)d_in[27];
  const float* q_b1 = (const float*)d_in[28];
  const float* q_g1 = (const float*)d_in[29];
  const float* q_be1 = (const float*)d_in[30];
  const float* q_W2 = (const float*)d_in[31];
  const float* q_b2 = (const float*)d_in[32];
  const float* q_g2 = (const float*)d_in[33];
  const float* q_be2 = (const float*)d_in[34];
  const float* q_W3 = (const float*)d_in[35];
  const float* q_b3 = (const float*)d_in[36];
  const float* d_W1 = (const float*)d_in[37];
  const float* d_b1 = (const float*)d_in[38];
  const float* d_g1 = (const float*)d_in[39];
  const float* d_be1 = (const float*)d_in[40];
  const float* d_W2 = (const float*)d_in[41];
  const float* d_b2 = (const float*)d_in[42];

  char* wsb = (char*)d_ws;
  auto alloc = [&](size_t bytes) { char* p = wsb; wsb += (bytes + 255) & ~(size_t)255; return p; };

  _Float16* h16  = (_Float16*)alloc((size_t)MPAD * HD * 2);
  _Float16* Xl16 = (_Float16*)alloc((size_t)MPAD * HD * 2);
  _Float16* Xr16 = (_Float16*)alloc((size_t)MPAD * HD * 2);
  _Float16* WT   = (_Float16*)alloc((size_t)6 * HD * HD * 2);
  _Float16* Tgeo2 = (_Float16*)alloc((size_t)HD * HD * 2);
  _Float16* Tq   = (_Float16*)alloc((size_t)HD * HD * 2);
  _Float16* Tk   = (_Float16*)alloc((size_t)HD * HD * 2);
  _Float16* Tv   = (_Float16*)alloc((size_t)HD * HD * 2);
  _Float16* To   = (_Float16*)alloc((size_t)HD * HD * 2);
  _Float16* Tq1  = (_Float16*)alloc((size_t)HD * 512 * 2);
  _Float16* Tq2  = (_Float16*)alloc((size_t)128 * HD * 2);
  _Float16* sh16 = (_Float16*)alloc((size_t)SS * HD * 2);
  _Float16* g116 = (_Float16*)alloc((size_t)SS * HD * 2);
  _Float16* g216 = (_Float16*)alloc((size_t)SS * HD * 2);
  _Float16* qb16 = (_Float16*)alloc((size_t)SS * HD * 2);
  _Float16* kb16 = (_Float16*)alloc((size_t)SS * HD * 2);
  _Float16* vb16 = (_Float16*)alloc((size_t)SS * HD * 2);
  _Float16* pv16 = (_Float16*)alloc((size_t)SS * HD * 2);
  _Float16* hqin16 = (_Float16*)alloc((size_t)SS * 512 * 2);
  _Float16* hq116 = (_Float16*)alloc((size_t)SS * HD * 2);
  float* gpart   = (float*)alloc((size_t)GSB * HD * 4);
  float* gvec    = (float*)alloc(256 * 4);
  int* cnt       = (int*)alloc((size_t)NN * 4);
  int* rowptr    = (int*)alloc((size_t)(NN + 1) * 4);
  int* wptr      = (int*)alloc((size_t)NN * 4);
  int* csr_src   = (int*)alloc((size_t)(ETOT + 16) * 4);
  int* btot      = (int*)alloc((size_t)SCB * 4);
  int* boff      = (int*)alloc((size_t)SCB * 4);
  int* gcnt      = (int*)alloc(4);

  float* out_q = (float*)d_out;        // [256]
  float* out_d = out_q + SS;           // [1]

  // weights + init (blocks 3200+)
  k_wconvAll<<<3318, 256, 0, stream>>>(gat_Wl, gat_Wr, geo_W2, ca_Wq, ca_Wk, ca_Wv,
                                       ca_Wo, q_W1, q_W2,
                                       WT, Tgeo2, Tq, Tk, Tv, To, Tq1, Tq2,
                                       cnt, gcnt, h16 + (size_t)NN * HD, csr_src + ETOT);

  // CSR build
  k_count<<<(ETOT + 255) / 256, 256, 0, stream>>>(ei, cnt);
  k_scanA<<<SCB, 256, 0, stream>>>(cnt, rowptr, btot);
  k_scanB<<<1, 128, 0, stream>>>(btot, boff, rowptr);
  k_scanC<<<SCB, 256, 0, stream>>>(rowptr, boff, wptr);
  k_scatter<<<(ETOT + 255) / 256, 256, 0, stream>>>(ei, wptr, csr_src);

  // pre-transform
  k_pre<<<NN / 8, 256, 0, stream>>>(x, pre_W, pre_b, h16);

  // GAT layers
  for (int l = 0; l < NL; ++l) {
    k_gemm16<<<MPAD / 64, 512, 0, stream>>>(h16, WT + (size_t)l * 2 * HD * HD, Xl16, Xr16);
    k_edgeagg<<<(NN + 3) / 4, 256, 0, stream>>>(Xl16, Xr16, gat_att + l * NH * CH,
                                                gat_b + l * HD, rowptr, csr_src, h16);
  }

  // global mean partials
  k_gsum<<<GSB, 256, 0, stream>>>(h16, batch, gpart, gcnt);

  // tail (+gfin folded into block SS)
  k_tail1<<<SS + 1, 256, 0, stream>>>(h16, sheet_idx, sheet_feat,
      geo_W1, geo_b1, geo_g1, geo_be1, gpart, gcnt, gvec, sh16, g116);
  k_stageLN<256, 4><<<16, 256, 0, stream>>>(g116, Tgeo2, geo_b2, geo_g2, geo_be2,
      g216, nullptr, nullptr, nullptr,
      nullptr, nullptr, nullptr, nullptr, nullptr, nullptr, nullptr, nullptr);
  dim3 qkvg(16, 4, 3);
  k_qkv<<<qkvg, 64, 0, stream>>>(sh16, g216, Tq, Tk, Tv, ca_bq, ca_bk, ca_bv,
                                 qb16, kb16, vb16);
  k_attn<<<SS, 1024, 0, stream>>>(qb16, kb16, vb16, pv16);
  dim3 wog(16, 4);
  k_wo<<<wog, 64, 0, stream>>>(pv16, To, ca_bo, gvec, hqin16);
  k_stageLN<512, 4><<<16, 256, 0, stream>>>(hqin16, Tq1, q_b1, q_g1, q_be1,
      hq116, nullptr, nullptr, nullptr,
      nullptr, nullptr, nullptr, nullptr, nullptr, nullptr, nullptr, nullptr);
  // hq2 + qval (blocks 0..15) + done head (block 16)
  k_stageLN<256, 2><<<17, 128, 0, stream>>>(hq116, Tq2, q_b2, q_g2, q_be2,
      nullptr, q_W3, q_b3, out_q,
      gvec, d_W1, d_b1, d_g1, d_be1, d_W2, d_b2, out_d);
}